// Round 2
// baseline (724.090 us; speedup 1.0000x reference)
//
#include <hip/hip_runtime.h>
#include <math.h>

// ---------------------------------------------------------------------------
// GAT (3-layer, PyG GATConv semantics) on MI355X.
// CSR-by-dst built on device (no atomics in hot aggregation), tiled fp32
// GEMMs (128x64 tile, 8x4 micro-tile), wave-per-(node,head) online-softmax
// aggregation. fp32 everywhere: correctness-first baseline.
// ---------------------------------------------------------------------------

#define N_FEAT 256
#define HID 512

// ---------------- CSR construction ----------------

__global__ void init_counts(int* cursor, int N) {
    int i = blockIdx.x * blockDim.x + threadIdx.x;
    if (i < N) cursor[i] = 1;  // self loop contributes 1
}

__global__ void count_edges(const int* __restrict__ ei, int E, int* cursor) {
    int e = blockIdx.x * blockDim.x + threadIdx.x;
    if (e < E) atomicAdd(&cursor[ei[E + e]], 1);
}

// single-block scan, thread-serial chunks: counts (in cursor) ->
// row_off[0..N] inclusive offsets, cursor reset to row start.
__global__ __launch_bounds__(1024) void scan_offsets(int* cursor, int* row_off, int N) {
    __shared__ int sdata[1024];
    int tid = threadIdx.x;
    int chunk = (N + 1023) >> 10;
    int base = tid * chunk;
    int lsum = 0;
    for (int i = 0; i < chunk; i++) {
        int idx = base + i;
        if (idx < N) lsum += cursor[idx];
    }
    sdata[tid] = lsum;
    __syncthreads();
    for (int off = 1; off < 1024; off <<= 1) {
        int t = (tid >= off) ? sdata[tid - off] : 0;
        __syncthreads();
        sdata[tid] += t;
        __syncthreads();
    }
    int run = sdata[tid] - lsum;           // exclusive prefix for this thread
    if (tid == 0) row_off[0] = 0;
    for (int i = 0; i < chunk; i++) {
        int idx = base + i;
        if (idx < N) {
            int c = cursor[idx];
            cursor[idx] = run;             // row start
            run += c;
            row_off[idx + 1] = run;
        }
    }
}

__global__ void fill_csr(const int* __restrict__ ei, int E, int N,
                         int* cursor, int* __restrict__ col) {
    int i = blockIdx.x * blockDim.x + threadIdx.x;
    int tot = E + N;
    if (i >= tot) return;
    int s, d;
    if (i < E) { s = ei[i]; d = ei[E + i]; }
    else       { s = i - E; d = s; }
    int pos = atomicAdd(&cursor[d], 1);
    col[pos] = s;
}

// ---------------- fp32 tiled GEMM: C[M,N] = A[M,K] @ B[K,N] ----------------
// 128x64 tile, 256 threads, 8x4 micro-tile, K-tile 16. K must be mult of 16.

__global__ __launch_bounds__(256) void sgemm128(const float* __restrict__ A,
                                                const float* __restrict__ B,
                                                float* __restrict__ C,
                                                int M, int N, int K) {
    __shared__ float As[16][132];
    __shared__ float Bs[16][68];
    int tid = threadIdx.x;
    int bm = blockIdx.x * 128, bn = blockIdx.y * 64;
    int ty = tid >> 4, tx = tid & 15;       // 16x16 thread grid

    float acc[8][4] = {};

    int arow = tid >> 1;                    // 0..127
    int acol8 = (tid & 1) * 8;              // 0 or 8
    int brow = tid >> 4;                    // 0..15
    int bcol4 = (tid & 15) * 4;             // 0..60

    for (int k0 = 0; k0 < K; k0 += 16) {
        int ar = bm + arow;
        float4 av0 = make_float4(0.f, 0.f, 0.f, 0.f);
        float4 av1 = make_float4(0.f, 0.f, 0.f, 0.f);
        if (ar < M) {
            const float* ap = &A[(size_t)ar * K + k0 + acol8];
            av0 = *reinterpret_cast<const float4*>(ap);
            av1 = *reinterpret_cast<const float4*>(ap + 4);
        }
        As[acol8 + 0][arow] = av0.x;
        As[acol8 + 1][arow] = av0.y;
        As[acol8 + 2][arow] = av0.z;
        As[acol8 + 3][arow] = av0.w;
        As[acol8 + 4][arow] = av1.x;
        As[acol8 + 5][arow] = av1.y;
        As[acol8 + 6][arow] = av1.z;
        As[acol8 + 7][arow] = av1.w;

        float4 bv;
        int bc = bn + bcol4;
        int br = k0 + brow;
        if (bc + 3 < N) {
            bv = *reinterpret_cast<const float4*>(&B[(size_t)br * N + bc]);
        } else {
            float t0 = (bc + 0 < N) ? B[(size_t)br * N + bc + 0] : 0.f;
            float t1 = (bc + 1 < N) ? B[(size_t)br * N + bc + 1] : 0.f;
            float t2 = (bc + 2 < N) ? B[(size_t)br * N + bc + 2] : 0.f;
            float t3 = (bc + 3 < N) ? B[(size_t)br * N + bc + 3] : 0.f;
            bv = make_float4(t0, t1, t2, t3);
        }
        *reinterpret_cast<float4*>(&Bs[brow][bcol4]) = bv;
        __syncthreads();

        #pragma unroll
        for (int k = 0; k < 16; k++) {
            float4 a0 = *reinterpret_cast<const float4*>(&As[k][ty * 8]);
            float4 a1 = *reinterpret_cast<const float4*>(&As[k][ty * 8 + 4]);
            float4 b4 = *reinterpret_cast<const float4*>(&Bs[k][tx * 4]);
            float a[8] = {a0.x, a0.y, a0.z, a0.w, a1.x, a1.y, a1.z, a1.w};
            float b[4] = {b4.x, b4.y, b4.z, b4.w};
            #pragma unroll
            for (int i = 0; i < 8; i++)
                #pragma unroll
                for (int j = 0; j < 4; j++)
                    acc[i][j] = fmaf(a[i], b[j], acc[i][j]);
        }
        __syncthreads();
    }

    #pragma unroll
    for (int i = 0; i < 8; i++) {
        int r = bm + ty * 8 + i;
        if (r >= M) continue;
        #pragma unroll
        for (int j = 0; j < 4; j++) {
            int c = bn + tx * 4 + j;
            if (c < N) C[(size_t)r * N + c] = acc[i][j];
        }
    }
}

// ---------------- attention scores: a_src/a_dst [N,H] ----------------
// one wave per (n,h)

__global__ __launch_bounds__(256) void att_scores(const float* __restrict__ xw,
                                                  const float* __restrict__ att_s,
                                                  const float* __restrict__ att_d,
                                                  float* __restrict__ asrc,
                                                  float* __restrict__ adst,
                                                  int N, int H, int C) {
    int w = (blockIdx.x * blockDim.x + threadIdx.x) >> 6;
    int lane = threadIdx.x & 63;
    if (w >= N * H) return;
    int n = w / H, h = w - n * H;
    const float* xp = &xw[((size_t)n * H + h) * C];
    float vs = 0.f, vd = 0.f;
    for (int c = lane; c < C; c += 64) {
        float v = xp[c];
        vs = fmaf(v, att_s[h * C + c], vs);
        vd = fmaf(v, att_d[h * C + c], vd);
    }
    #pragma unroll
    for (int off = 32; off; off >>= 1) {
        vs += __shfl_xor(vs, off);
        vd += __shfl_xor(vd, off);
    }
    if (lane == 0) { asrc[n * H + h] = vs; adst[n * H + h] = vd; }
}

// ---------------- softmax + aggregation, wave per (n,h), online softmax ----

template <int CMAX>   // C <= 64*CMAX
__global__ __launch_bounds__(256) void gat_agg(const float* __restrict__ xw,
                                               const float* __restrict__ asrc,
                                               const float* __restrict__ adst,
                                               const int* __restrict__ row_off,
                                               const int* __restrict__ col,
                                               float* __restrict__ out,
                                               int N, int H, int C) {
    int w = (blockIdx.x * blockDim.x + threadIdx.x) >> 6;
    int lane = threadIdx.x & 63;
    if (w >= N * H) return;
    int n = w / H, h = w - n * H;
    float adn = adst[n * H + h];
    float m = -INFINITY, denom = 0.f;
    float acc[CMAX];
    #pragma unroll
    for (int i = 0; i < CMAX; i++) acc[i] = 0.f;

    int jb = row_off[n], je = row_off[n + 1];
    for (int j = jb; j < je; j++) {
        int s = col[j];
        float e = asrc[s * H + h] + adn;
        e = e > 0.f ? e : 0.2f * e;              // leaky_relu(0.2)
        float nm = fmaxf(m, e);
        float scale = __expf(m - nm);            // 0 when m == -inf
        float p = __expf(e - nm);
        const float* srcp = &xw[((size_t)s * H + h) * C];
        #pragma unroll
        for (int i = 0; i < CMAX; i++) {
            int c = lane + i * 64;
            float v = (c < C) ? srcp[c] : 0.f;
            acc[i] = acc[i] * scale + p * v;
        }
        denom = denom * scale + p;
        m = nm;
    }
    float inv = 1.f / (denom + 1e-16f);
    float* dst = &out[((size_t)n * H + h) * C];
    #pragma unroll
    for (int i = 0; i < CMAX; i++) {
        int c = lane + i * 64;
        if (c < C) dst[c] = acc[i] * inv;
    }
}

// ---------------- epilogues ----------------

__global__ void elu_bias_add(const float* __restrict__ agg,
                             const float* __restrict__ bias,
                             const float* __restrict__ skip,
                             float* __restrict__ out, int total, int D) {
    int i = blockIdx.x * blockDim.x + threadIdx.x;
    if (i >= total) return;
    float v = agg[i] + bias[i % D] + skip[i];
    out[i] = v > 0.f ? v : expm1f(v);            // elu
}

__global__ void final_out(const float* __restrict__ agg,   // [N,6,40]
                          const float* __restrict__ b2,    // [40]
                          const float* __restrict__ skip,  // [N,40]
                          float* __restrict__ out, int N) {
    int i = blockIdx.x * blockDim.x + threadIdx.x;
    if (i >= N * 40) return;
    int n = i / 40, c = i - n * 40;
    float s = 0.f;
    #pragma unroll
    for (int h = 0; h < 6; h++) s += agg[((size_t)n * 6 + h) * 40 + c];
    out[i] = s * (1.f / 6.f) + b2[c] + skip[i];
}

// ---------------- orchestration ----------------

extern "C" void kernel_launch(void* const* d_in, const int* in_sizes, int n_in,
                              void* d_out, int out_size, void* d_ws, size_t ws_size,
                              hipStream_t stream) {
    const float* x        = (const float*)d_in[0];
    const int*   ei       = (const int*)  d_in[1];
    const float* W0       = (const float*)d_in[2];
    const float* a_src0   = (const float*)d_in[3];
    const float* a_dst0   = (const float*)d_in[4];
    const float* b0       = (const float*)d_in[5];
    const float* Wskip_in = (const float*)d_in[6];
    const float* W1       = (const float*)d_in[7];
    const float* a_src1   = (const float*)d_in[8];
    const float* a_dst1   = (const float*)d_in[9];
    const float* b1       = (const float*)d_in[10];
    const float* W2       = (const float*)d_in[11];
    const float* a_src2   = (const float*)d_in[12];
    const float* a_dst2   = (const float*)d_in[13];
    const float* b2       = (const float*)d_in[14];
    const float* Wskip_out= (const float*)d_in[15];

    const int N = in_sizes[0] / N_FEAT;     // 10000
    const int E = in_sizes[1] / 2;          // 160000
    float* out = (float*)d_out;

    float* ws = (float*)d_ws;
    size_t o = 0;
    float* xw   = ws + o; o += (size_t)N * HID;
    float* agg  = ws + o; o += (size_t)N * HID;
    float* x1   = ws + o; o += (size_t)N * HID;
    float* tmpD = ws + o; o += (size_t)N * HID;   // skip_in (L0), then x2 (L1+)
    float* asrc = ws + o; o += (size_t)N * 8;
    float* adst = ws + o; o += (size_t)N * 8;
    float* skipo= ws + o; o += (size_t)N * 40;
    int* row_off = (int*)(ws + o);
    int* cursor  = row_off + (N + 1);
    int* col     = cursor + (N + 1);

    // ---- CSR by destination (includes self loops) ----
    init_counts<<<(N + 255) / 256, 256, 0, stream>>>(cursor, N);
    count_edges<<<(E + 255) / 256, 256, 0, stream>>>(ei, E, cursor);
    scan_offsets<<<1, 1024, 0, stream>>>(cursor, row_off, N);
    fill_csr<<<(E + N + 255) / 256, 256, 0, stream>>>(ei, E, N, cursor, col);

    dim3 gemm_blk(256);
    int mtiles = (N + 127) / 128;

    // ---- Layer 0: in 256 -> 4x128 concat ----
    {
        dim3 g(mtiles, (HID + 63) / 64);
        sgemm128<<<g, gemm_blk, 0, stream>>>(x, W0, xw, N, HID, N_FEAT);
        sgemm128<<<g, gemm_blk, 0, stream>>>(x, Wskip_in, tmpD, N, HID, N_FEAT);
        int waves = N * 4;
        att_scores<<<(waves * 64 + 255) / 256, 256, 0, stream>>>(
            xw, a_src0, a_dst0, asrc, adst, N, 4, 128);
        gat_agg<2><<<(waves * 64 + 255) / 256, 256, 0, stream>>>(
            xw, asrc, adst, row_off, col, agg, N, 4, 128);
        elu_bias_add<<<(N * HID + 255) / 256, 256, 0, stream>>>(
            agg, b0, tmpD, x1, N * HID, HID);
    }

    // ---- Layer 1: 512 -> 4x128 concat, residual x1 ----
    {
        dim3 g(mtiles, (HID + 63) / 64);
        sgemm128<<<g, gemm_blk, 0, stream>>>(x1, W1, xw, N, HID, HID);
        int waves = N * 4;
        att_scores<<<(waves * 64 + 255) / 256, 256, 0, stream>>>(
            xw, a_src1, a_dst1, asrc, adst, N, 4, 128);
        gat_agg<2><<<(waves * 64 + 255) / 256, 256, 0, stream>>>(
            xw, asrc, adst, row_off, col, agg, N, 4, 128);
        elu_bias_add<<<(N * HID + 255) / 256, 256, 0, stream>>>(
            agg, b1, x1, tmpD, N * HID, HID);   // tmpD = x2
    }

    // ---- Layer 2: 512 -> 6x40 mean, + x2@Wskip_out ----
    {
        dim3 g2(mtiles, (240 + 63) / 64);
        sgemm128<<<g2, gemm_blk, 0, stream>>>(tmpD, W2, xw, N, 240, HID);
        dim3 gs(mtiles, 1);
        sgemm128<<<gs, gemm_blk, 0, stream>>>(tmpD, Wskip_out, skipo, N, 40, HID);
        int waves = N * 6;
        att_scores<<<(waves * 64 + 255) / 256, 256, 0, stream>>>(
            xw, a_src2, a_dst2, asrc, adst, N, 6, 40);
        gat_agg<1><<<(waves * 64 + 255) / 256, 256, 0, stream>>>(
            xw, asrc, adst, row_off, col, agg, N, 6, 40);
        final_out<<<(N * 40 + 255) / 256, 256, 0, stream>>>(agg, b2, skipo, out, N);
    }
}

// Round 3
// 643.642 us; speedup vs baseline: 1.1250x; 1.1250x over previous
//
#include <hip/hip_runtime.h>
#include <math.h>

// ---------------------------------------------------------------------------
// GAT (3-layer, PyG GATConv semantics) on MI355X.
// Round 3 structure:
//   - CSR-by-dst on device (unchanged, validated)
//   - fp32 tiled GEMMs (unchanged, validated)
//   - NEW: two-phase edge softmax:
//       edge_alpha     : lane-parallel normalized attention per edge
//       agg_fused512   : wave-per-node, all-4-heads aggregation + fused
//                        elu(bias+skip) epilogue
//       agg_final240   : wave-per-node layer-2 aggregation + fused head-mean
//                        + bias + out-skip, writes d_out
// ---------------------------------------------------------------------------

#define N_FEAT 256
#define HID 512

// ---------------- CSR construction ----------------

__global__ void init_counts(int* cursor, int N) {
    int i = blockIdx.x * blockDim.x + threadIdx.x;
    if (i < N) cursor[i] = 1;  // self loop contributes 1
}

__global__ void count_edges(const int* __restrict__ ei, int E, int* cursor) {
    int e = blockIdx.x * blockDim.x + threadIdx.x;
    if (e < E) atomicAdd(&cursor[ei[E + e]], 1);
}

// single-block scan, thread-serial chunks: counts (in cursor) ->
// row_off[0..N], cursor reset to row start.
__global__ __launch_bounds__(1024) void scan_offsets(int* cursor, int* row_off, int N) {
    __shared__ int sdata[1024];
    int tid = threadIdx.x;
    int chunk = (N + 1023) >> 10;
    int base = tid * chunk;
    int lsum = 0;
    for (int i = 0; i < chunk; i++) {
        int idx = base + i;
        if (idx < N) lsum += cursor[idx];
    }
    sdata[tid] = lsum;
    __syncthreads();
    for (int off = 1; off < 1024; off <<= 1) {
        int t = (tid >= off) ? sdata[tid - off] : 0;
        __syncthreads();
        sdata[tid] += t;
        __syncthreads();
    }
    int run = sdata[tid] - lsum;           // exclusive prefix for this thread
    if (tid == 0) row_off[0] = 0;
    for (int i = 0; i < chunk; i++) {
        int idx = base + i;
        if (idx < N) {
            int c = cursor[idx];
            cursor[idx] = run;             // row start
            run += c;
            row_off[idx + 1] = run;
        }
    }
}

__global__ void fill_csr(const int* __restrict__ ei, int E, int N,
                         int* cursor, int* __restrict__ col) {
    int i = blockIdx.x * blockDim.x + threadIdx.x;
    int tot = E + N;
    if (i >= tot) return;
    int s, d;
    if (i < E) { s = ei[i]; d = ei[E + i]; }
    else       { s = i - E; d = s; }
    int pos = atomicAdd(&cursor[d], 1);
    col[pos] = s;
}

// ---------------- fp32 tiled GEMM: C[M,N] = A[M,K] @ B[K,N] ----------------
// 128x64 tile, 256 threads, 8x4 micro-tile, K-tile 16. K must be mult of 16.

__global__ __launch_bounds__(256) void sgemm128(const float* __restrict__ A,
                                                const float* __restrict__ B,
                                                float* __restrict__ C,
                                                int M, int N, int K) {
    __shared__ float As[16][132];
    __shared__ float Bs[16][68];
    int tid = threadIdx.x;
    int bm = blockIdx.x * 128, bn = blockIdx.y * 64;
    int ty = tid >> 4, tx = tid & 15;       // 16x16 thread grid

    float acc[8][4] = {};

    int arow = tid >> 1;                    // 0..127
    int acol8 = (tid & 1) * 8;              // 0 or 8
    int brow = tid >> 4;                    // 0..15
    int bcol4 = (tid & 15) * 4;             // 0..60

    for (int k0 = 0; k0 < K; k0 += 16) {
        int ar = bm + arow;
        float4 av0 = make_float4(0.f, 0.f, 0.f, 0.f);
        float4 av1 = make_float4(0.f, 0.f, 0.f, 0.f);
        if (ar < M) {
            const float* ap = &A[(size_t)ar * K + k0 + acol8];
            av0 = *reinterpret_cast<const float4*>(ap);
            av1 = *reinterpret_cast<const float4*>(ap + 4);
        }
        As[acol8 + 0][arow] = av0.x;
        As[acol8 + 1][arow] = av0.y;
        As[acol8 + 2][arow] = av0.z;
        As[acol8 + 3][arow] = av0.w;
        As[acol8 + 4][arow] = av1.x;
        As[acol8 + 5][arow] = av1.y;
        As[acol8 + 6][arow] = av1.z;
        As[acol8 + 7][arow] = av1.w;

        float4 bv;
        int bc = bn + bcol4;
        int br = k0 + brow;
        if (bc + 3 < N) {
            bv = *reinterpret_cast<const float4*>(&B[(size_t)br * N + bc]);
        } else {
            float t0 = (bc + 0 < N) ? B[(size_t)br * N + bc + 0] : 0.f;
            float t1 = (bc + 1 < N) ? B[(size_t)br * N + bc + 1] : 0.f;
            float t2 = (bc + 2 < N) ? B[(size_t)br * N + bc + 2] : 0.f;
            float t3 = (bc + 3 < N) ? B[(size_t)br * N + bc + 3] : 0.f;
            bv = make_float4(t0, t1, t2, t3);
        }
        *reinterpret_cast<float4*>(&Bs[brow][bcol4]) = bv;
        __syncthreads();

        #pragma unroll
        for (int k = 0; k < 16; k++) {
            float4 a0 = *reinterpret_cast<const float4*>(&As[k][ty * 8]);
            float4 a1 = *reinterpret_cast<const float4*>(&As[k][ty * 8 + 4]);
            float4 b4 = *reinterpret_cast<const float4*>(&Bs[k][tx * 4]);
            float a[8] = {a0.x, a0.y, a0.z, a0.w, a1.x, a1.y, a1.z, a1.w};
            float b[4] = {b4.x, b4.y, b4.z, b4.w};
            #pragma unroll
            for (int i = 0; i < 8; i++)
                #pragma unroll
                for (int j = 0; j < 4; j++)
                    acc[i][j] = fmaf(a[i], b[j], acc[i][j]);
        }
        __syncthreads();
    }

    #pragma unroll
    for (int i = 0; i < 8; i++) {
        int r = bm + ty * 8 + i;
        if (r >= M) continue;
        #pragma unroll
        for (int j = 0; j < 4; j++) {
            int c = bn + tx * 4 + j;
            if (c < N) C[(size_t)r * N + c] = acc[i][j];
        }
    }
}

// ---------------- attention scores: a_src/a_dst [N,H] ----------------
// one wave per (n,h)

__global__ __launch_bounds__(256) void att_scores(const float* __restrict__ xw,
                                                  const float* __restrict__ att_s,
                                                  const float* __restrict__ att_d,
                                                  float* __restrict__ asrc,
                                                  float* __restrict__ adst,
                                                  int N, int H, int C) {
    int w = (blockIdx.x * blockDim.x + threadIdx.x) >> 6;
    int lane = threadIdx.x & 63;
    if (w >= N * H) return;
    int n = w / H, h = w - n * H;
    const float* xp = &xw[((size_t)n * H + h) * C];
    float vs = 0.f, vd = 0.f;
    for (int c = lane; c < C; c += 64) {
        float v = xp[c];
        vs = fmaf(v, att_s[h * C + c], vs);
        vd = fmaf(v, att_d[h * C + c], vd);
    }
    #pragma unroll
    for (int off = 32; off; off >>= 1) {
        vs += __shfl_xor(vs, off);
        vd += __shfl_xor(vd, off);
    }
    if (lane == 0) { asrc[n * H + h] = vs; adst[n * H + h] = vd; }
}

// ---------------- phase 1: normalized edge attention ----------------
// one wave per (n,h); edges of the row are lane-parallel.

__global__ __launch_bounds__(256) void edge_alpha(const float* __restrict__ asrc,
                                                  const float* __restrict__ adst,
                                                  const int* __restrict__ row_off,
                                                  const int* __restrict__ col,
                                                  float* __restrict__ alpha,
                                                  int N, int H) {
    int w = (blockIdx.x * blockDim.x + threadIdx.x) >> 6;
    int lane = threadIdx.x & 63;
    if (w >= N * H) return;
    int n = w / H, h = w - n * H;
    int jb = row_off[n], je = row_off[n + 1];
    float adn = adst[n * H + h];

    float m = -INFINITY;
    for (int j = jb + lane; j < je; j += 64) {
        float e = asrc[col[j] * H + h] + adn;
        e = e > 0.f ? e : 0.2f * e;
        m = fmaxf(m, e);
    }
    #pragma unroll
    for (int off = 32; off; off >>= 1) m = fmaxf(m, __shfl_xor(m, off));

    float ssum = 0.f;
    for (int j = jb + lane; j < je; j += 64) {
        float e = asrc[col[j] * H + h] + adn;
        e = e > 0.f ? e : 0.2f * e;
        ssum += __expf(e - m);
    }
    #pragma unroll
    for (int off = 32; off; off >>= 1) ssum += __shfl_xor(ssum, off);
    float inv = 1.f / (ssum + 1e-16f);

    for (int j = jb + lane; j < je; j += 64) {
        float e = asrc[col[j] * H + h] + adn;
        e = e > 0.f ? e : 0.2f * e;
        alpha[(size_t)j * H + h] = __expf(e - m) * inv;
    }
}

// ---------------- phase 2: aggregation, wave per node, H=4, C=128 --------
// lane owns 8 contiguous floats (head = lane>>4); fused elu(agg+bias+skip).

__global__ __launch_bounds__(256) void agg_fused512(const float* __restrict__ xw,
                                                    const float* __restrict__ alpha,
                                                    const int* __restrict__ row_off,
                                                    const int* __restrict__ col,
                                                    const float* __restrict__ bias,
                                                    const float* __restrict__ skip,
                                                    float* __restrict__ out,
                                                    int N) {
    int w = (blockIdx.x * blockDim.x + threadIdx.x) >> 6;  // node
    int lane = threadIdx.x & 63;
    if (w >= N) return;
    int base = lane * 8;
    int hme = lane >> 4;

    float acc[8] = {};
    int jb = row_off[w], je = row_off[w + 1];
    int s = (jb < je) ? col[jb] : 0;
    for (int j = jb; j < je; ++j) {
        int snext = (j + 1 < je) ? col[j + 1] : 0;
        float a = alpha[(size_t)j * 4 + hme];
        const float* sp = &xw[(size_t)s * 512 + base];
        float4 v0 = *reinterpret_cast<const float4*>(sp);
        float4 v1 = *reinterpret_cast<const float4*>(sp + 4);
        acc[0] = fmaf(a, v0.x, acc[0]);
        acc[1] = fmaf(a, v0.y, acc[1]);
        acc[2] = fmaf(a, v0.z, acc[2]);
        acc[3] = fmaf(a, v0.w, acc[3]);
        acc[4] = fmaf(a, v1.x, acc[4]);
        acc[5] = fmaf(a, v1.y, acc[5]);
        acc[6] = fmaf(a, v1.z, acc[6]);
        acc[7] = fmaf(a, v1.w, acc[7]);
        s = snext;
    }

    const float* bp = &bias[base];
    const float* kp = &skip[(size_t)w * 512 + base];
    float r[8];
    #pragma unroll
    for (int i = 0; i < 8; i++) {
        float v = acc[i] + bp[i] + kp[i];
        r[i] = v > 0.f ? v : expm1f(v);          // elu
    }
    float* op = &out[(size_t)w * 512 + base];
    *reinterpret_cast<float4*>(op)     = make_float4(r[0], r[1], r[2], r[3]);
    *reinterpret_cast<float4*>(op + 4) = make_float4(r[4], r[5], r[6], r[7]);
}

// ---------------- phase 2 (layer 2): H=6, C=40, head-mean + skip ---------
// lanes 0..39 each own output column c; sum over 6 heads in registers.

__global__ __launch_bounds__(256) void agg_final240(const float* __restrict__ xw,
                                                    const float* __restrict__ alpha,
                                                    const int* __restrict__ row_off,
                                                    const int* __restrict__ col,
                                                    const float* __restrict__ b2,
                                                    const float* __restrict__ skip,
                                                    float* __restrict__ out,
                                                    int N) {
    int w = (blockIdx.x * blockDim.x + threadIdx.x) >> 6;  // node
    int lane = threadIdx.x & 63;
    if (w >= N) return;
    bool active = lane < 40;

    float acc[6] = {};
    int jb = row_off[w], je = row_off[w + 1];
    int s = (jb < je) ? col[jb] : 0;
    for (int j = jb; j < je; ++j) {
        int snext = (j + 1 < je) ? col[j + 1] : 0;
        const float* ap = &alpha[(size_t)j * 6];
        if (active) {
            const float* sp = &xw[(size_t)s * 240 + lane];
            #pragma unroll
            for (int h = 0; h < 6; h++)
                acc[h] = fmaf(ap[h], sp[h * 40], acc[h]);
        }
        s = snext;
    }
    if (active) {
        float v = (acc[0] + acc[1] + acc[2] + acc[3] + acc[4] + acc[5]) * (1.f / 6.f)
                  + b2[lane] + skip[(size_t)w * 40 + lane];
        out[(size_t)w * 40 + lane] = v;
    }
}

// ---------------- orchestration ----------------

extern "C" void kernel_launch(void* const* d_in, const int* in_sizes, int n_in,
                              void* d_out, int out_size, void* d_ws, size_t ws_size,
                              hipStream_t stream) {
    const float* x        = (const float*)d_in[0];
    const int*   ei       = (const int*)  d_in[1];
    const float* W0       = (const float*)d_in[2];
    const float* a_src0   = (const float*)d_in[3];
    const float* a_dst0   = (const float*)d_in[4];
    const float* b0       = (const float*)d_in[5];
    const float* Wskip_in = (const float*)d_in[6];
    const float* W1       = (const float*)d_in[7];
    const float* a_src1   = (const float*)d_in[8];
    const float* a_dst1   = (const float*)d_in[9];
    const float* b1       = (const float*)d_in[10];
    const float* W2       = (const float*)d_in[11];
    const float* a_src2   = (const float*)d_in[12];
    const float* a_dst2   = (const float*)d_in[13];
    const float* b2       = (const float*)d_in[14];
    const float* Wskip_out= (const float*)d_in[15];

    const int N = in_sizes[0] / N_FEAT;     // 10000
    const int E = in_sizes[1] / 2;          // 160000
    float* out = (float*)d_out;

    float* ws = (float*)d_ws;
    size_t o = 0;
    float* xw    = ws + o; o += (size_t)N * HID;
    float* x1    = ws + o; o += (size_t)N * HID;
    float* tmpD  = ws + o; o += (size_t)N * HID;   // skip_in (L0), then x2
    float* asrc  = ws + o; o += (size_t)N * 8;
    float* adst  = ws + o; o += (size_t)N * 8;
    float* skipo = ws + o; o += (size_t)N * 40;
    float* alpha = ws + o; o += (size_t)(E + N) * 6;
    int* row_off = (int*)(ws + o);
    int* cursor  = row_off + (N + 1);
    int* col     = cursor + (N + 1);

    // ---- CSR by destination (includes self loops) ----
    init_counts<<<(N + 255) / 256, 256, 0, stream>>>(cursor, N);
    count_edges<<<(E + 255) / 256, 256, 0, stream>>>(ei, E, cursor);
    scan_offsets<<<1, 1024, 0, stream>>>(cursor, row_off, N);
    fill_csr<<<(E + N + 255) / 256, 256, 0, stream>>>(ei, E, N, cursor, col);

    dim3 gemm_blk(256);
    int mtiles = (N + 127) / 128;
    int nodeBlocks = (N * 64 + 255) / 256;

    // ---- Layer 0: in 256 -> 4x128 concat ----
    {
        dim3 g(mtiles, (HID + 63) / 64);
        sgemm128<<<g, gemm_blk, 0, stream>>>(x, W0, xw, N, HID, N_FEAT);
        sgemm128<<<g, gemm_blk, 0, stream>>>(x, Wskip_in, tmpD, N, HID, N_FEAT);
        int waves = N * 4;
        att_scores<<<(waves * 64 + 255) / 256, 256, 0, stream>>>(
            xw, a_src0, a_dst0, asrc, adst, N, 4, 128);
        edge_alpha<<<(waves * 64 + 255) / 256, 256, 0, stream>>>(
            asrc, adst, row_off, col, alpha, N, 4);
        agg_fused512<<<nodeBlocks, 256, 0, stream>>>(
            xw, alpha, row_off, col, b0, tmpD, x1, N);
    }

    // ---- Layer 1: 512 -> 4x128 concat, residual x1 ----
    {
        dim3 g(mtiles, (HID + 63) / 64);
        sgemm128<<<g, gemm_blk, 0, stream>>>(x1, W1, xw, N, HID, HID);
        int waves = N * 4;
        att_scores<<<(waves * 64 + 255) / 256, 256, 0, stream>>>(
            xw, a_src1, a_dst1, asrc, adst, N, 4, 128);
        edge_alpha<<<(waves * 64 + 255) / 256, 256, 0, stream>>>(
            asrc, adst, row_off, col, alpha, N, 4);
        agg_fused512<<<nodeBlocks, 256, 0, stream>>>(
            xw, alpha, row_off, col, b1, x1, tmpD, N);   // tmpD = x2
    }

    // ---- Layer 2: 512 -> 6x40 mean, + x2@Wskip_out ----
    {
        dim3 g2(mtiles, (240 + 63) / 64);
        sgemm128<<<g2, gemm_blk, 0, stream>>>(tmpD, W2, xw, N, 240, HID);
        dim3 gs(mtiles, 1);
        sgemm128<<<gs, gemm_blk, 0, stream>>>(tmpD, Wskip_out, skipo, N, 40, HID);
        int waves = N * 6;
        att_scores<<<(waves * 64 + 255) / 256, 256, 0, stream>>>(
            xw, a_src2, a_dst2, asrc, adst, N, 6, 40);
        edge_alpha<<<(waves * 64 + 255) / 256, 256, 0, stream>>>(
            asrc, adst, row_off, col, alpha, N, 6);
        agg_final240<<<nodeBlocks, 256, 0, stream>>>(
            xw, alpha, row_off, col, b2, skipo, out, N);
    }
}

// Round 4
// 637.190 us; speedup vs baseline: 1.1364x; 1.0101x over previous
//
#include <hip/hip_runtime.h>
#include <math.h>

// ---------------------------------------------------------------------------
// GAT (3-layer, PyG GATConv semantics) on MI355X.
// Round 4: identical to round 3 except the GEMM grid — 1D launch with
// bijective XCD-aware swizzle (m204) and N-tile-fastest ordering inside each
// XCD, so each XCD keeps its A-panel + all of B hot in its private L2.
// ---------------------------------------------------------------------------

#define N_FEAT 256
#define HID 512

// ---------------- CSR construction ----------------

__global__ void init_counts(int* cursor, int N) {
    int i = blockIdx.x * blockDim.x + threadIdx.x;
    if (i < N) cursor[i] = 1;  // self loop contributes 1
}

__global__ void count_edges(const int* __restrict__ ei, int E, int* cursor) {
    int e = blockIdx.x * blockDim.x + threadIdx.x;
    if (e < E) atomicAdd(&cursor[ei[E + e]], 1);
}

// single-block scan, thread-serial chunks: counts (in cursor) ->
// row_off[0..N], cursor reset to row start.
__global__ __launch_bounds__(1024) void scan_offsets(int* cursor, int* row_off, int N) {
    __shared__ int sdata[1024];
    int tid = threadIdx.x;
    int chunk = (N + 1023) >> 10;
    int base = tid * chunk;
    int lsum = 0;
    for (int i = 0; i < chunk; i++) {
        int idx = base + i;
        if (idx < N) lsum += cursor[idx];
    }
    sdata[tid] = lsum;
    __syncthreads();
    for (int off = 1; off < 1024; off <<= 1) {
        int t = (tid >= off) ? sdata[tid - off] : 0;
        __syncthreads();
        sdata[tid] += t;
        __syncthreads();
    }
    int run = sdata[tid] - lsum;           // exclusive prefix for this thread
    if (tid == 0) row_off[0] = 0;
    for (int i = 0; i < chunk; i++) {
        int idx = base + i;
        if (idx < N) {
            int c = cursor[idx];
            cursor[idx] = run;             // row start
            run += c;
            row_off[idx + 1] = run;
        }
    }
}

__global__ void fill_csr(const int* __restrict__ ei, int E, int N,
                         int* cursor, int* __restrict__ col) {
    int i = blockIdx.x * blockDim.x + threadIdx.x;
    int tot = E + N;
    if (i >= tot) return;
    int s, d;
    if (i < E) { s = ei[i]; d = ei[E + i]; }
    else       { s = i - E; d = s; }
    int pos = atomicAdd(&cursor[d], 1);
    col[pos] = s;
}

// ---------------- fp32 tiled GEMM: C[M,N] = A[M,K] @ B[K,N] ----------------
// 128x64 tile, 256 threads, 8x4 micro-tile, K-tile 16. K must be mult of 16.
// 1D grid; bijective XCD swizzle (hw: xcd = blockIdx % 8), N-tile fastest
// inside each XCD so the A-panel + B stay hot in the XCD's private L2.

__global__ __launch_bounds__(256) void sgemm128(const float* __restrict__ A,
                                                const float* __restrict__ B,
                                                float* __restrict__ C,
                                                int M, int N, int K, int ntiles) {
    int nwg = gridDim.x;
    int b = blockIdx.x;
    int q = nwg >> 3, r = nwg & 7;
    int xcd = b & 7, i = b >> 3;
    int t = (xcd < r) ? (xcd * (q + 1) + i) : (r * (q + 1) + (xcd - r) * q + i);
    int bm = (t / ntiles) * 128;
    int bn = (t - (t / ntiles) * ntiles) * 64;

    __shared__ float As[16][132];
    __shared__ float Bs[16][68];
    int tid = threadIdx.x;
    int ty = tid >> 4, tx = tid & 15;       // 16x16 thread grid

    float acc[8][4] = {};

    int arow = tid >> 1;                    // 0..127
    int acol8 = (tid & 1) * 8;              // 0 or 8
    int brow = tid >> 4;                    // 0..15
    int bcol4 = (tid & 15) * 4;             // 0..60

    for (int k0 = 0; k0 < K; k0 += 16) {
        int ar = bm + arow;
        float4 av0 = make_float4(0.f, 0.f, 0.f, 0.f);
        float4 av1 = make_float4(0.f, 0.f, 0.f, 0.f);
        if (ar < M) {
            const float* ap = &A[(size_t)ar * K + k0 + acol8];
            av0 = *reinterpret_cast<const float4*>(ap);
            av1 = *reinterpret_cast<const float4*>(ap + 4);
        }
        As[acol8 + 0][arow] = av0.x;
        As[acol8 + 1][arow] = av0.y;
        As[acol8 + 2][arow] = av0.z;
        As[acol8 + 3][arow] = av0.w;
        As[acol8 + 4][arow] = av1.x;
        As[acol8 + 5][arow] = av1.y;
        As[acol8 + 6][arow] = av1.z;
        As[acol8 + 7][arow] = av1.w;

        float4 bv;
        int bc = bn + bcol4;
        int br = k0 + brow;
        if (bc + 3 < N) {
            bv = *reinterpret_cast<const float4*>(&B[(size_t)br * N + bc]);
        } else {
            float t0 = (bc + 0 < N) ? B[(size_t)br * N + bc + 0] : 0.f;
            float t1 = (bc + 1 < N) ? B[(size_t)br * N + bc + 1] : 0.f;
            float t2 = (bc + 2 < N) ? B[(size_t)br * N + bc + 2] : 0.f;
            float t3 = (bc + 3 < N) ? B[(size_t)br * N + bc + 3] : 0.f;
            bv = make_float4(t0, t1, t2, t3);
        }
        *reinterpret_cast<float4*>(&Bs[brow][bcol4]) = bv;
        __syncthreads();

        #pragma unroll
        for (int k = 0; k < 16; k++) {
            float4 a0 = *reinterpret_cast<const float4*>(&As[k][ty * 8]);
            float4 a1 = *reinterpret_cast<const float4*>(&As[k][ty * 8 + 4]);
            float4 b4 = *reinterpret_cast<const float4*>(&Bs[k][tx * 4]);
            float a[8] = {a0.x, a0.y, a0.z, a0.w, a1.x, a1.y, a1.z, a1.w};
            float bb[4] = {b4.x, b4.y, b4.z, b4.w};
            #pragma unroll
            for (int ii = 0; ii < 8; ii++)
                #pragma unroll
                for (int jj = 0; jj < 4; jj++)
                    acc[ii][jj] = fmaf(a[ii], bb[jj], acc[ii][jj]);
        }
        __syncthreads();
    }

    #pragma unroll
    for (int ii = 0; ii < 8; ii++) {
        int rr = bm + ty * 8 + ii;
        if (rr >= M) continue;
        #pragma unroll
        for (int jj = 0; jj < 4; jj++) {
            int cc = bn + tx * 4 + jj;
            if (cc < N) C[(size_t)rr * N + cc] = acc[ii][jj];
        }
    }
}

// ---------------- attention scores: a_src/a_dst [N,H] ----------------
// one wave per (n,h)

__global__ __launch_bounds__(256) void att_scores(const float* __restrict__ xw,
                                                  const float* __restrict__ att_s,
                                                  const float* __restrict__ att_d,
                                                  float* __restrict__ asrc,
                                                  float* __restrict__ adst,
                                                  int N, int H, int C) {
    int w = (blockIdx.x * blockDim.x + threadIdx.x) >> 6;
    int lane = threadIdx.x & 63;
    if (w >= N * H) return;
    int n = w / H, h = w - n * H;
    const float* xp = &xw[((size_t)n * H + h) * C];
    float vs = 0.f, vd = 0.f;
    for (int c = lane; c < C; c += 64) {
        float v = xp[c];
        vs = fmaf(v, att_s[h * C + c], vs);
        vd = fmaf(v, att_d[h * C + c], vd);
    }
    #pragma unroll
    for (int off = 32; off; off >>= 1) {
        vs += __shfl_xor(vs, off);
        vd += __shfl_xor(vd, off);
    }
    if (lane == 0) { asrc[n * H + h] = vs; adst[n * H + h] = vd; }
}

// ---------------- phase 1: normalized edge attention ----------------
// one wave per (n,h); edges of the row are lane-parallel.

__global__ __launch_bounds__(256) void edge_alpha(const float* __restrict__ asrc,
                                                  const float* __restrict__ adst,
                                                  const int* __restrict__ row_off,
                                                  const int* __restrict__ col,
                                                  float* __restrict__ alpha,
                                                  int N, int H) {
    int w = (blockIdx.x * blockDim.x + threadIdx.x) >> 6;
    int lane = threadIdx.x & 63;
    if (w >= N * H) return;
    int n = w / H, h = w - n * H;
    int jb = row_off[n], je = row_off[n + 1];
    float adn = adst[n * H + h];

    float m = -INFINITY;
    for (int j = jb + lane; j < je; j += 64) {
        float e = asrc[col[j] * H + h] + adn;
        e = e > 0.f ? e : 0.2f * e;
        m = fmaxf(m, e);
    }
    #pragma unroll
    for (int off = 32; off; off >>= 1) m = fmaxf(m, __shfl_xor(m, off));

    float ssum = 0.f;
    for (int j = jb + lane; j < je; j += 64) {
        float e = asrc[col[j] * H + h] + adn;
        e = e > 0.f ? e : 0.2f * e;
        ssum += __expf(e - m);
    }
    #pragma unroll
    for (int off = 32; off; off >>= 1) ssum += __shfl_xor(ssum, off);
    float inv = 1.f / (ssum + 1e-16f);

    for (int j = jb + lane; j < je; j += 64) {
        float e = asrc[col[j] * H + h] + adn;
        e = e > 0.f ? e : 0.2f * e;
        alpha[(size_t)j * H + h] = __expf(e - m) * inv;
    }
}

// ---------------- phase 2: aggregation, wave per node, H=4, C=128 --------
// lane owns 8 contiguous floats (head = lane>>4); fused elu(agg+bias+skip).

__global__ __launch_bounds__(256) void agg_fused512(const float* __restrict__ xw,
                                                    const float* __restrict__ alpha,
                                                    const int* __restrict__ row_off,
                                                    const int* __restrict__ col,
                                                    const float* __restrict__ bias,
                                                    const float* __restrict__ skip,
                                                    float* __restrict__ out,
                                                    int N) {
    int w = (blockIdx.x * blockDim.x + threadIdx.x) >> 6;  // node
    int lane = threadIdx.x & 63;
    if (w >= N) return;
    int base = lane * 8;
    int hme = lane >> 4;

    float acc[8] = {};
    int jb = row_off[w], je = row_off[w + 1];
    int s = (jb < je) ? col[jb] : 0;
    for (int j = jb; j < je; ++j) {
        int snext = (j + 1 < je) ? col[j + 1] : 0;
        float a = alpha[(size_t)j * 4 + hme];
        const float* sp = &xw[(size_t)s * 512 + base];
        float4 v0 = *reinterpret_cast<const float4*>(sp);
        float4 v1 = *reinterpret_cast<const float4*>(sp + 4);
        acc[0] = fmaf(a, v0.x, acc[0]);
        acc[1] = fmaf(a, v0.y, acc[1]);
        acc[2] = fmaf(a, v0.z, acc[2]);
        acc[3] = fmaf(a, v0.w, acc[3]);
        acc[4] = fmaf(a, v1.x, acc[4]);
        acc[5] = fmaf(a, v1.y, acc[5]);
        acc[6] = fmaf(a, v1.z, acc[6]);
        acc[7] = fmaf(a, v1.w, acc[7]);
        s = snext;
    }

    const float* bp = &bias[base];
    const float* kp = &skip[(size_t)w * 512 + base];
    float r[8];
    #pragma unroll
    for (int i = 0; i < 8; i++) {
        float v = acc[i] + bp[i] + kp[i];
        r[i] = v > 0.f ? v : expm1f(v);          // elu
    }
    float* op = &out[(size_t)w * 512 + base];
    *reinterpret_cast<float4*>(op)     = make_float4(r[0], r[1], r[2], r[3]);
    *reinterpret_cast<float4*>(op + 4) = make_float4(r[4], r[5], r[6], r[7]);
}

// ---------------- phase 2 (layer 2): H=6, C=40, head-mean + skip ---------
// lanes 0..39 each own output column c; sum over 6 heads in registers.

__global__ __launch_bounds__(256) void agg_final240(const float* __restrict__ xw,
                                                    const float* __restrict__ alpha,
                                                    const int* __restrict__ row_off,
                                                    const int* __restrict__ col,
                                                    const float* __restrict__ b2,
                                                    const float* __restrict__ skip,
                                                    float* __restrict__ out,
                                                    int N) {
    int w = (blockIdx.x * blockDim.x + threadIdx.x) >> 6;  // node
    int lane = threadIdx.x & 63;
    if (w >= N) return;
    bool active = lane < 40;

    float acc[6] = {};
    int jb = row_off[w], je = row_off[w + 1];
    int s = (jb < je) ? col[jb] : 0;
    for (int j = jb; j < je; ++j) {
        int snext = (j + 1 < je) ? col[j + 1] : 0;
        const float* ap = &alpha[(size_t)j * 6];
        if (active) {
            const float* sp = &xw[(size_t)s * 240 + lane];
            #pragma unroll
            for (int h = 0; h < 6; h++)
                acc[h] = fmaf(ap[h], sp[h * 40], acc[h]);
        }
        s = snext;
    }
    if (active) {
        float v = (acc[0] + acc[1] + acc[2] + acc[3] + acc[4] + acc[5]) * (1.f / 6.f)
                  + b2[lane] + skip[(size_t)w * 40 + lane];
        out[(size_t)w * 40 + lane] = v;
    }
}

// ---------------- orchestration ----------------

static inline void launch_sgemm(const float* A, const float* B, float* C,
                                int M, int N, int K, hipStream_t stream) {
    int mtiles = (M + 127) / 128;
    int ntiles = (N + 63) / 64;
    sgemm128<<<mtiles * ntiles, 256, 0, stream>>>(A, B, C, M, N, K, ntiles);
}

extern "C" void kernel_launch(void* const* d_in, const int* in_sizes, int n_in,
                              void* d_out, int out_size, void* d_ws, size_t ws_size,
                              hipStream_t stream) {
    const float* x        = (const float*)d_in[0];
    const int*   ei       = (const int*)  d_in[1];
    const float* W0       = (const float*)d_in[2];
    const float* a_src0   = (const float*)d_in[3];
    const float* a_dst0   = (const float*)d_in[4];
    const float* b0       = (const float*)d_in[5];
    const float* Wskip_in = (const float*)d_in[6];
    const float* W1       = (const float*)d_in[7];
    const float* a_src1   = (const float*)d_in[8];
    const float* a_dst1   = (const float*)d_in[9];
    const float* b1       = (const float*)d_in[10];
    const float* W2       = (const float*)d_in[11];
    const float* a_src2   = (const float*)d_in[12];
    const float* a_dst2   = (const float*)d_in[13];
    const float* b2       = (const float*)d_in[14];
    const float* Wskip_out= (const float*)d_in[15];

    const int N = in_sizes[0] / N_FEAT;     // 10000
    const int E = in_sizes[1] / 2;          // 160000
    float* out = (float*)d_out;

    float* ws = (float*)d_ws;
    size_t o = 0;
    float* xw    = ws + o; o += (size_t)N * HID;
    float* x1    = ws + o; o += (size_t)N * HID;
    float* tmpD  = ws + o; o += (size_t)N * HID;   // skip_in (L0), then x2
    float* asrc  = ws + o; o += (size_t)N * 8;
    float* adst  = ws + o; o += (size_t)N * 8;
    float* skipo = ws + o; o += (size_t)N * 40;
    float* alpha = ws + o; o += (size_t)(E + N) * 6;
    int* row_off = (int*)(ws + o);
    int* cursor  = row_off + (N + 1);
    int* col     = cursor + (N + 1);

    // ---- CSR by destination (includes self loops) ----
    init_counts<<<(N + 255) / 256, 256, 0, stream>>>(cursor, N);
    count_edges<<<(E + 255) / 256, 256, 0, stream>>>(ei, E, cursor);
    scan_offsets<<<1, 1024, 0, stream>>>(cursor, row_off, N);
    fill_csr<<<(E + N + 255) / 256, 256, 0, stream>>>(ei, E, N, cursor, col);

    int nodeBlocks = (N * 64 + 255) / 256;

    // ---- Layer 0: in 256 -> 4x128 concat ----
    {
        launch_sgemm(x, W0, xw, N, HID, N_FEAT, stream);
        launch_sgemm(x, Wskip_in, tmpD, N, HID, N_FEAT, stream);
        int waves = N * 4;
        att_scores<<<(waves * 64 + 255) / 256, 256, 0, stream>>>(
            xw, a_src0, a_dst0, asrc, adst, N, 4, 128);
        edge_alpha<<<(waves * 64 + 255) / 256, 256, 0, stream>>>(
            asrc, adst, row_off, col, alpha, N, 4);
        agg_fused512<<<nodeBlocks, 256, 0, stream>>>(
            xw, alpha, row_off, col, b0, tmpD, x1, N);
    }

    // ---- Layer 1: 512 -> 4x128 concat, residual x1 ----
    {
        launch_sgemm(x1, W1, xw, N, HID, HID, stream);
        int waves = N * 4;
        att_scores<<<(waves * 64 + 255) / 256, 256, 0, stream>>>(
            xw, a_src1, a_dst1, asrc, adst, N, 4, 128);
        edge_alpha<<<(waves * 64 + 255) / 256, 256, 0, stream>>>(
            asrc, adst, row_off, col, alpha, N, 4);
        agg_fused512<<<nodeBlocks, 256, 0, stream>>>(
            xw, alpha, row_off, col, b1, x1, tmpD, N);   // tmpD = x2
    }

    // ---- Layer 2: 512 -> 6x40 mean, + x2@Wskip_out ----
    {
        launch_sgemm(tmpD, W2, xw, N, 240, HID, stream);
        launch_sgemm(tmpD, Wskip_out, skipo, N, 40, HID, stream);
        int waves = N * 6;
        att_scores<<<(waves * 64 + 255) / 256, 256, 0, stream>>>(
            xw, a_src2, a_dst2, asrc, adst, N, 6, 40);
        edge_alpha<<<(waves * 64 + 255) / 256, 256, 0, stream>>>(
            asrc, adst, row_off, col, alpha, N, 6);
        agg_final240<<<nodeBlocks, 256, 0, stream>>>(
            xw, alpha, row_off, col, b2, skipo, out, N);
    }
}

// Round 6
// 510.928 us; speedup vs baseline: 1.4172x; 1.2471x over previous
//
#include <hip/hip_runtime.h>
#include <math.h>

// ---------------------------------------------------------------------------
// GAT (3-layer, PyG GATConv semantics) on MI355X.
// Round 6: split-bf16 MFMA GEMM path (round 5) made memory-safe:
//   - exact ws footprint computed at launch; if ws_size is too small we fall
//     back to the validated round-4 fp32 sgemm path (never OOB).
//   - alpha aliases the Ah pack region (disjoint live ranges, stream-ordered).
// ---------------------------------------------------------------------------

#define N_FEAT 256
#define HID 512

using u16 = unsigned short;
using bf16x8 = __attribute__((ext_vector_type(8))) __bf16;
using f32x16 = __attribute__((ext_vector_type(16))) float;

__device__ inline u16 bf16_rne(float f) {
    unsigned u = __float_as_uint(f);
    return (u16)((u + 0x7fffu + ((u >> 16) & 1u)) >> 16);
}

__device__ inline bf16x8 ldb8(const u16* p) {
    return *reinterpret_cast<const bf16x8*>(p);
}

// ---------------- CSR construction ----------------

__global__ void init_counts(int* cursor, int N) {
    int i = blockIdx.x * blockDim.x + threadIdx.x;
    if (i < N) cursor[i] = 1;  // self loop contributes 1
}

__global__ void count_edges(const int* __restrict__ ei, int E, int* cursor) {
    int e = blockIdx.x * blockDim.x + threadIdx.x;
    if (e < E) atomicAdd(&cursor[ei[E + e]], 1);
}

__global__ __launch_bounds__(1024) void scan_offsets(int* cursor, int* row_off, int N) {
    __shared__ int sdata[1024];
    int tid = threadIdx.x;
    int chunk = (N + 1023) >> 10;
    int base = tid * chunk;
    int lsum = 0;
    for (int i = 0; i < chunk; i++) {
        int idx = base + i;
        if (idx < N) lsum += cursor[idx];
    }
    sdata[tid] = lsum;
    __syncthreads();
    for (int off = 1; off < 1024; off <<= 1) {
        int t = (tid >= off) ? sdata[tid - off] : 0;
        __syncthreads();
        sdata[tid] += t;
        __syncthreads();
    }
    int run = sdata[tid] - lsum;
    if (tid == 0) row_off[0] = 0;
    for (int i = 0; i < chunk; i++) {
        int idx = base + i;
        if (idx < N) {
            int c = cursor[idx];
            cursor[idx] = run;
            run += c;
            row_off[idx + 1] = run;
        }
    }
}

__global__ void fill_csr(const int* __restrict__ ei, int E, int N,
                         int* cursor, int* __restrict__ col) {
    int i = blockIdx.x * blockDim.x + threadIdx.x;
    int tot = E + N;
    if (i >= tot) return;
    int s, d;
    if (i < E) { s = ei[i]; d = ei[E + i]; }
    else       { s = i - E; d = s; }
    int pos = atomicAdd(&cursor[d], 1);
    col[pos] = s;
}

// ---------------- split-bf16 packing ----------------
// Packed fragment layout (32-row/col blocks, 16-k chunks):
//   slot index = ((blk * (K/16) + c) * 64 + lane) * 8
//   lane&31 -> row(col) within block ; lane>>5 -> k-subgroup (8 consecutive k)

__global__ __launch_bounds__(256) void cvtA_pack(const float* __restrict__ X,
                                                 u16* __restrict__ hi, u16* __restrict__ lo,
                                                 int M, int K, int Rblocks) {
    int gid = blockIdx.x * blockDim.x + threadIdx.x;
    int lane = gid & 63;
    int rest = gid >> 6;                 // R * KC + c
    int KC = K >> 4;
    int R = rest / KC;
    int c = rest - R * KC;
    if (R >= Rblocks) return;
    int row = R * 32 + (lane & 31);
    if (row >= M) row = M - 1;           // clamp: clamped rows never stored
    const float* src = X + (size_t)row * K + c * 16 + (lane >> 5) * 8;
    float4 v0 = *reinterpret_cast<const float4*>(src);
    float4 v1 = *reinterpret_cast<const float4*>(src + 4);
    float vv[8] = {v0.x, v0.y, v0.z, v0.w, v1.x, v1.y, v1.z, v1.w};
    unsigned hp[4], lp[4];
    #pragma unroll
    for (int j = 0; j < 4; j++) {
        u16 h0 = bf16_rne(vv[2 * j]);
        u16 h1 = bf16_rne(vv[2 * j + 1]);
        float r0 = vv[2 * j]     - __uint_as_float((unsigned)h0 << 16);
        float r1 = vv[2 * j + 1] - __uint_as_float((unsigned)h1 << 16);
        u16 l0 = bf16_rne(r0);
        u16 l1 = bf16_rne(r1);
        hp[j] = (unsigned)h0 | ((unsigned)h1 << 16);
        lp[j] = (unsigned)l0 | ((unsigned)l1 << 16);
    }
    size_t dst = ((size_t)rest * 64 + lane) * 8;
    *reinterpret_cast<int4*>(hi + dst) = make_int4(hp[0], hp[1], hp[2], hp[3]);
    *reinterpret_cast<int4*>(lo + dst) = make_int4(lp[0], lp[1], lp[2], lp[3]);
}

// B [K][N] -> packed B^T fragments (col blocks of 32), cols >= N zero-filled.
__global__ __launch_bounds__(256) void cvtB_pack(const float* __restrict__ B,
                                                 u16* __restrict__ hi, u16* __restrict__ lo,
                                                 int K, int N, int Cblocks) {
    int gid = blockIdx.x * blockDim.x + threadIdx.x;
    int lane = gid & 63;
    int rest = gid >> 6;                 // Cb * KC + c
    int KC = K >> 4;
    int Cb = rest / KC;
    int c = rest - Cb * KC;
    if (Cb >= Cblocks) return;
    int n = Cb * 32 + (lane & 31);
    int kbase = c * 16 + (lane >> 5) * 8;
    float vv[8];
    #pragma unroll
    for (int j = 0; j < 8; j++)
        vv[j] = (n < N) ? B[(size_t)(kbase + j) * N + n] : 0.f;
    unsigned hp[4], lp[4];
    #pragma unroll
    for (int j = 0; j < 4; j++) {
        u16 h0 = bf16_rne(vv[2 * j]);
        u16 h1 = bf16_rne(vv[2 * j + 1]);
        float r0 = vv[2 * j]     - __uint_as_float((unsigned)h0 << 16);
        float r1 = vv[2 * j + 1] - __uint_as_float((unsigned)h1 << 16);
        u16 l0 = bf16_rne(r0);
        u16 l1 = bf16_rne(r1);
        hp[j] = (unsigned)h0 | ((unsigned)h1 << 16);
        lp[j] = (unsigned)l0 | ((unsigned)l1 << 16);
    }
    size_t dst = ((size_t)rest * 64 + lane) * 8;
    *reinterpret_cast<int4*>(hi + dst) = make_int4(hp[0], hp[1], hp[2], hp[3]);
    *reinterpret_cast<int4*>(lo + dst) = make_int4(lp[0], lp[1], lp[2], lp[3]);
}

// ---------------- MFMA GEMM: C[M,N] = A[M,K] @ B[K,N] ----------------
// 128x64 block, 4 waves (2x2), wave tile 64x32 = 2 m-frags of 32x32.
// 3-term split-bf16; packed operands; XCD-swizzled 1D grid.

__global__ __launch_bounds__(256) void gemm_mfma(const u16* __restrict__ Ahi,
                                                 const u16* __restrict__ Alo,
                                                 const u16* __restrict__ Bhi,
                                                 const u16* __restrict__ Blo,
                                                 float* __restrict__ C,
                                                 int M, int N, int K,
                                                 int ntiles, int Rblocks) {
    int nwg = gridDim.x, b = blockIdx.x;
    int q = nwg >> 3, r = nwg & 7;
    int xcd = b & 7, idx = b >> 3;
    int t = (xcd < r) ? (xcd * (q + 1) + idx)
                      : (r * (q + 1) + (xcd - r) * q + idx);
    int bm = (t / ntiles) * 128;
    int bn = (t - (t / ntiles) * ntiles) * 64;

    int lane = threadIdx.x & 63, w = threadIdx.x >> 6;
    int wr = w >> 1, wc = w & 1;
    int l31 = lane & 31, lg = lane >> 5;
    int KC = K >> 4;

    int R0 = (bm + wr * 64) >> 5;               // m-frag0 row-block
    int R1 = R0 + 1;
    if (R0 >= Rblocks) R0 = Rblocks - 1;        // OOB tiles: load garbage, no store
    if (R1 >= Rblocks) R1 = Rblocks - 1;
    int Cb = (bn + wc * 32) >> 5;

    const u16* pa0h = Ahi + (((size_t)R0 * KC) * 64 + lane) * 8;
    const u16* pa0l = Alo + (((size_t)R0 * KC) * 64 + lane) * 8;
    const u16* pa1h = Ahi + (((size_t)R1 * KC) * 64 + lane) * 8;
    const u16* pa1l = Alo + (((size_t)R1 * KC) * 64 + lane) * 8;
    const u16* pbh  = Bhi + (((size_t)Cb * KC) * 64 + lane) * 8;
    const u16* pbl  = Blo + (((size_t)Cb * KC) * 64 + lane) * 8;

    f32x16 acc0, acc1;
    #pragma unroll
    for (int i2 = 0; i2 < 16; i2++) { acc0[i2] = 0.f; acc1[i2] = 0.f; }

    bf16x8 a0h = ldb8(pa0h), a0l = ldb8(pa0l);
    bf16x8 a1h = ldb8(pa1h), a1l = ldb8(pa1l);
    bf16x8 bh  = ldb8(pbh),  bl  = ldb8(pbl);

    for (int c = 1; c <= KC; c++) {
        size_t off = (size_t)c * 512;           // 64 lanes * 8 u16
        bf16x8 na0h = ldb8(pa0h + off), na0l = ldb8(pa0l + off);
        bf16x8 na1h = ldb8(pa1h + off), na1l = ldb8(pa1l + off);
        bf16x8 nbh  = ldb8(pbh + off),  nbl  = ldb8(pbl + off);
        acc0 = __builtin_amdgcn_mfma_f32_32x32x16_bf16(a0h, bh, acc0, 0, 0, 0);
        acc1 = __builtin_amdgcn_mfma_f32_32x32x16_bf16(a1h, bh, acc1, 0, 0, 0);
        acc0 = __builtin_amdgcn_mfma_f32_32x32x16_bf16(a0h, bl, acc0, 0, 0, 0);
        acc1 = __builtin_amdgcn_mfma_f32_32x32x16_bf16(a1h, bl, acc1, 0, 0, 0);
        acc0 = __builtin_amdgcn_mfma_f32_32x32x16_bf16(a0l, bh, acc0, 0, 0, 0);
        acc1 = __builtin_amdgcn_mfma_f32_32x32x16_bf16(a1l, bh, acc1, 0, 0, 0);
        a0h = na0h; a0l = na0l; a1h = na1h; a1l = na1l; bh = nbh; bl = nbl;
    }

    int n = bn + wc * 32 + l31;
    int base_m = bm + wr * 64;
    if (n < N) {
        #pragma unroll
        for (int rg = 0; rg < 16; rg++) {
            int mrow = (rg & 3) + 8 * (rg >> 2) + 4 * lg;
            int m0 = base_m + mrow;
            int m1 = m0 + 32;
            if (m0 < M) C[(size_t)m0 * N + n] = acc0[rg];
            if (m1 < M) C[(size_t)m1 * N + n] = acc1[rg];
        }
    }
}

// ---------------- fp32 fallback GEMM (round-4 validated) ----------------

__global__ __launch_bounds__(256) void sgemm128(const float* __restrict__ A,
                                                const float* __restrict__ B,
                                                float* __restrict__ C,
                                                int M, int N, int K, int ntiles) {
    int nwg = gridDim.x;
    int b = blockIdx.x;
    int q = nwg >> 3, r = nwg & 7;
    int xcd = b & 7, i = b >> 3;
    int t = (xcd < r) ? (xcd * (q + 1) + i) : (r * (q + 1) + (xcd - r) * q + i);
    int bm = (t / ntiles) * 128;
    int bn = (t - (t / ntiles) * ntiles) * 64;

    __shared__ float As[16][132];
    __shared__ float Bs[16][68];
    int tid = threadIdx.x;
    int ty = tid >> 4, tx = tid & 15;

    float acc[8][4] = {};

    int arow = tid >> 1;
    int acol8 = (tid & 1) * 8;
    int brow = tid >> 4;
    int bcol4 = (tid & 15) * 4;

    for (int k0 = 0; k0 < K; k0 += 16) {
        int ar = bm + arow;
        float4 av0 = make_float4(0.f, 0.f, 0.f, 0.f);
        float4 av1 = make_float4(0.f, 0.f, 0.f, 0.f);
        if (ar < M) {
            const float* ap = &A[(size_t)ar * K + k0 + acol8];
            av0 = *reinterpret_cast<const float4*>(ap);
            av1 = *reinterpret_cast<const float4*>(ap + 4);
        }
        As[acol8 + 0][arow] = av0.x;
        As[acol8 + 1][arow] = av0.y;
        As[acol8 + 2][arow] = av0.z;
        As[acol8 + 3][arow] = av0.w;
        As[acol8 + 4][arow] = av1.x;
        As[acol8 + 5][arow] = av1.y;
        As[acol8 + 6][arow] = av1.z;
        As[acol8 + 7][arow] = av1.w;

        float4 bv;
        int bc = bn + bcol4;
        int br = k0 + brow;
        if (bc + 3 < N) {
            bv = *reinterpret_cast<const float4*>(&B[(size_t)br * N + bc]);
        } else {
            float t0 = (bc + 0 < N) ? B[(size_t)br * N + bc + 0] : 0.f;
            float t1 = (bc + 1 < N) ? B[(size_t)br * N + bc + 1] : 0.f;
            float t2 = (bc + 2 < N) ? B[(size_t)br * N + bc + 2] : 0.f;
            float t3 = (bc + 3 < N) ? B[(size_t)br * N + bc + 3] : 0.f;
            bv = make_float4(t0, t1, t2, t3);
        }
        *reinterpret_cast<float4*>(&Bs[brow][bcol4]) = bv;
        __syncthreads();

        #pragma unroll
        for (int k = 0; k < 16; k++) {
            float4 a0 = *reinterpret_cast<const float4*>(&As[k][ty * 8]);
            float4 a1 = *reinterpret_cast<const float4*>(&As[k][ty * 8 + 4]);
            float4 b4 = *reinterpret_cast<const float4*>(&Bs[k][tx * 4]);
            float a[8] = {a0.x, a0.y, a0.z, a0.w, a1.x, a1.y, a1.z, a1.w};
            float bb[4] = {b4.x, b4.y, b4.z, b4.w};
            #pragma unroll
            for (int ii = 0; ii < 8; ii++)
                #pragma unroll
                for (int jj = 0; jj < 4; jj++)
                    acc[ii][jj] = fmaf(a[ii], bb[jj], acc[ii][jj]);
        }
        __syncthreads();
    }

    #pragma unroll
    for (int ii = 0; ii < 8; ii++) {
        int rr = bm + ty * 8 + ii;
        if (rr >= M) continue;
        #pragma unroll
        for (int jj = 0; jj < 4; jj++) {
            int cc = bn + tx * 4 + jj;
            if (cc < N) C[(size_t)rr * N + cc] = acc[ii][jj];
        }
    }
}

// ---------------- attention scores: a_src/a_dst [N,H] ----------------

__global__ __launch_bounds__(256) void att_scores(const float* __restrict__ xw,
                                                  const float* __restrict__ att_s,
                                                  const float* __restrict__ att_d,
                                                  float* __restrict__ asrc,
                                                  float* __restrict__ adst,
                                                  int N, int H, int C) {
    int w = (blockIdx.x * blockDim.x + threadIdx.x) >> 6;
    int lane = threadIdx.x & 63;
    if (w >= N * H) return;
    int n = w / H, h = w - n * H;
    const float* xp = &xw[((size_t)n * H + h) * C];
    float vs = 0.f, vd = 0.f;
    for (int c = lane; c < C; c += 64) {
        float v = xp[c];
        vs = fmaf(v, att_s[h * C + c], vs);
        vd = fmaf(v, att_d[h * C + c], vd);
    }
    #pragma unroll
    for (int off = 32; off; off >>= 1) {
        vs += __shfl_xor(vs, off);
        vd += __shfl_xor(vd, off);
    }
    if (lane == 0) { asrc[n * H + h] = vs; adst[n * H + h] = vd; }
}

// ---------------- phase 1: normalized edge attention ----------------

__global__ __launch_bounds__(256) void edge_alpha(const float* __restrict__ asrc,
                                                  const float* __restrict__ adst,
                                                  const int* __restrict__ row_off,
                                                  const int* __restrict__ col,
                                                  float* __restrict__ alpha,
                                                  int N, int H) {
    int w = (blockIdx.x * blockDim.x + threadIdx.x) >> 6;
    int lane = threadIdx.x & 63;
    if (w >= N * H) return;
    int n = w / H, h = w - n * H;
    int jb = row_off[n], je = row_off[n + 1];
    float adn = adst[n * H + h];

    float m = -INFINITY;
    for (int j = jb + lane; j < je; j += 64) {
        float e = asrc[col[j] * H + h] + adn;
        e = e > 0.f ? e : 0.2f * e;
        m = fmaxf(m, e);
    }
    #pragma unroll
    for (int off = 32; off; off >>= 1) m = fmaxf(m, __shfl_xor(m, off));

    float ssum = 0.f;
    for (int j = jb + lane; j < je; j += 64) {
        float e = asrc[col[j] * H + h] + adn;
        e = e > 0.f ? e : 0.2f * e;
        ssum += __expf(e - m);
    }
    #pragma unroll
    for (int off = 32; off; off >>= 1) ssum += __shfl_xor(ssum, off);
    float inv = 1.f / (ssum + 1e-16f);

    for (int j = jb + lane; j < je; j += 64) {
        float e = asrc[col[j] * H + h] + adn;
        e = e > 0.f ? e : 0.2f * e;
        alpha[(size_t)j * H + h] = __expf(e - m) * inv;
    }
}

// ---------------- phase 2: aggregation, wave per node, H=4, C=128 --------

__global__ __launch_bounds__(256) void agg_fused512(const float* __restrict__ xw,
                                                    const float* __restrict__ alpha,
                                                    const int* __restrict__ row_off,
                                                    const int* __restrict__ col,
                                                    const float* __restrict__ bias,
                                                    const float* __restrict__ skip,
                                                    float* __restrict__ out,
                                                    int N) {
    int w = (blockIdx.x * blockDim.x + threadIdx.x) >> 6;  // node
    int lane = threadIdx.x & 63;
    if (w >= N) return;
    int base = lane * 8;
    int hme = lane >> 4;

    float acc[8] = {};
    int jb = row_off[w], je = row_off[w + 1];
    int s = (jb < je) ? col[jb] : 0;
    for (int j = jb; j < je; ++j) {
        int snext = (j + 1 < je) ? col[j + 1] : 0;
        float a = alpha[(size_t)j * 4 + hme];
        const float* sp = &xw[(size_t)s * 512 + base];
        float4 v0 = *reinterpret_cast<const float4*>(sp);
        float4 v1 = *reinterpret_cast<const float4*>(sp + 4);
        acc[0] = fmaf(a, v0.x, acc[0]);
        acc[1] = fmaf(a, v0.y, acc[1]);
        acc[2] = fmaf(a, v0.z, acc[2]);
        acc[3] = fmaf(a, v0.w, acc[3]);
        acc[4] = fmaf(a, v1.x, acc[4]);
        acc[5] = fmaf(a, v1.y, acc[5]);
        acc[6] = fmaf(a, v1.z, acc[6]);
        acc[7] = fmaf(a, v1.w, acc[7]);
        s = snext;
    }

    const float* bp = &bias[base];
    const float* kp = &skip[(size_t)w * 512 + base];
    float r[8];
    #pragma unroll
    for (int i = 0; i < 8; i++) {
        float v = acc[i] + bp[i] + kp[i];
        r[i] = v > 0.f ? v : expm1f(v);          // elu
    }
    float* op = &out[(size_t)w * 512 + base];
    *reinterpret_cast<float4*>(op)     = make_float4(r[0], r[1], r[2], r[3]);
    *reinterpret_cast<float4*>(op + 4) = make_float4(r[4], r[5], r[6], r[7]);
}

// ---------------- phase 2 (layer 2): H=6, C=40, head-mean + skip ---------

__global__ __launch_bounds__(256) void agg_final240(const float* __restrict__ xw,
                                                    const float* __restrict__ alpha,
                                                    const int* __restrict__ row_off,
                                                    const int* __restrict__ col,
                                                    const float* __restrict__ b2,
                                                    const float* __restrict__ skip,
                                                    float* __restrict__ out,
                                                    int N) {
    int w = (blockIdx.x * blockDim.x + threadIdx.x) >> 6;  // node
    int lane = threadIdx.x & 63;
    if (w >= N) return;
    bool active = lane < 40;

    float acc[6] = {};
    int jb = row_off[w], je = row_off[w + 1];
    int s = (jb < je) ? col[jb] : 0;
    for (int j = jb; j < je; ++j) {
        int snext = (j + 1 < je) ? col[j + 1] : 0;
        const float* ap = &alpha[(size_t)j * 6];
        if (active) {
            const float* sp = &xw[(size_t)s * 240 + lane];
            #pragma unroll
            for (int h = 0; h < 6; h++)
                acc[h] = fmaf(ap[h], sp[h * 40], acc[h]);
        }
        s = snext;
    }
    if (active) {
        float v = (acc[0] + acc[1] + acc[2] + acc[3] + acc[4] + acc[5]) * (1.f / 6.f)
                  + b2[lane] + skip[(size_t)w * 40 + lane];
        out[(size_t)w * 40 + lane] = v;
    }
}

// ---------------- orchestration ----------------

static inline void launch_gemm(const u16* Ah, const u16* Al,
                               const u16* Bh, const u16* Bl, float* C,
                               int M, int N, int K, int Rblocks, hipStream_t stream) {
    int mtiles = (M + 127) / 128;
    int ntiles = (N + 63) / 64;
    gemm_mfma<<<mtiles * ntiles, 256, 0, stream>>>(Ah, Al, Bh, Bl, C, M, N, K,
                                                   ntiles, Rblocks);
}

static inline void launch_sgemm(const float* A, const float* B, float* C,
                                int M, int N, int K, hipStream_t stream) {
    int mtiles = (M + 127) / 128;
    int ntiles = (N + 63) / 64;
    sgemm128<<<mtiles * ntiles, 256, 0, stream>>>(A, B, C, M, N, K, ntiles);
}

extern "C" void kernel_launch(void* const* d_in, const int* in_sizes, int n_in,
                              void* d_out, int out_size, void* d_ws, size_t ws_size,
                              hipStream_t stream) {
    const float* x        = (const float*)d_in[0];
    const int*   ei       = (const int*)  d_in[1];
    const float* W0       = (const float*)d_in[2];
    const float* a_src0   = (const float*)d_in[3];
    const float* a_dst0   = (const float*)d_in[4];
    const float* b0       = (const float*)d_in[5];
    const float* Wskip_in = (const float*)d_in[6];
    const float* W1       = (const float*)d_in[7];
    const float* a_src1   = (const float*)d_in[8];
    const float* a_dst1   = (const float*)d_in[9];
    const float* b1       = (const float*)d_in[10];
    const float* W2       = (const float*)d_in[11];
    const float* a_src2   = (const float*)d_in[12];
    const float* a_dst2   = (const float*)d_in[13];
    const float* b2       = (const float*)d_in[14];
    const float* Wskip_out= (const float*)d_in[15];

    const int N = in_sizes[0] / N_FEAT;     // 10000
    const int E = in_sizes[1] / 2;          // 160000
    float* out = (float*)d_out;

    const int Rblocks = (N + 31) / 32;      // 313

    // ---------- common float buffers ----------
    float* ws = (float*)d_ws;
    size_t o = 0;
    float* xw    = ws + o; o += (size_t)N * HID;
    float* x1    = ws + o; o += (size_t)N * HID;
    float* tmpD  = ws + o; o += (size_t)N * HID;   // skip_in (L0), then x2
    float* asrc  = ws + o; o += (size_t)N * 8;
    float* adst  = ws + o; o += (size_t)N * 8;
    float* skipo = ws + o; o += (size_t)N * 40;

    // ---------- MFMA-path layout (u16 pack region + CSR) ----------
    u16* up = (u16*)(ws + o);
    size_t uo = 0;
    const size_t aPack = (size_t)Rblocks * 32 * 512 + 512;  // K=512 worst case
    u16* Ah  = up + uo; uo += aPack;
    u16* Al  = up + uo; uo += aPack;
    const size_t w0sz = (size_t)16 * 16 * 512 + 512;   // Cb=16, KC=16
    u16* W0h = up + uo; uo += w0sz;  u16* W0l = up + uo; uo += w0sz;
    u16* Wih = up + uo; uo += w0sz;  u16* Wil = up + uo; uo += w0sz;
    const size_t w1sz = (size_t)16 * 32 * 512 + 512;   // Cb=16, KC=32
    u16* W1h = up + uo; uo += w1sz;  u16* W1l = up + uo; uo += w1sz;
    const size_t w2sz = (size_t)8 * 32 * 512 + 512;    // Cb=8, KC=32
    u16* W2h = up + uo; uo += w2sz;  u16* W2l = up + uo; uo += w2sz;
    const size_t wssz = (size_t)2 * 32 * 512 + 512;    // Cb=2, KC=32
    u16* Wsh = up + uo; uo += wssz;  u16* Wsl = up + uo; uo += wssz;
    int* row_off_m = (int*)(up + uo);
    int* cursor_m  = row_off_m + (N + 1);
    int* col_m     = cursor_m + (N + 1);
    // alpha aliases Ah: Ah is dead after each layer's GEMMs; alpha is dead
    // before the next layer's cvtA_pack (stream-ordered, no overlap).
    float* alpha_m = (float*)Ah;
    size_t need_mfma = (size_t)((char*)(col_m + (E + N)) - (char*)d_ws);

    // ---------- fp32-fallback layout (round 4, ~68.5 MB, proven) ----------
    size_t of = o;
    float* alpha_f = ws + of; of += (size_t)(E + N) * 6;
    int* row_off_f = (int*)(ws + of);
    int* cursor_f  = row_off_f + (N + 1);
    int* col_f     = cursor_f + (N + 1);

    const bool use_mfma = ws_size >= need_mfma;
    int* row_off = use_mfma ? row_off_m : row_off_f;
    int* cursor  = use_mfma ? cursor_m  : cursor_f;
    int* col     = use_mfma ? col_m     : col_f;
    float* alpha = use_mfma ? alpha_m   : alpha_f;

    // ---- CSR by destination (includes self loops) ----
    init_counts<<<(N + 255) / 256, 256, 0, stream>>>(cursor, N);
    count_edges<<<(E + 255) / 256, 256, 0, stream>>>(ei, E, cursor);
    scan_offsets<<<1, 1024, 0, stream>>>(cursor, row_off, N);
    fill_csr<<<(E + N + 255) / 256, 256, 0, stream>>>(ei, E, N, cursor, col);

    if (use_mfma) {
        // ---- weight packing (B^T fragment layout, hi/lo split) ----
        cvtB_pack<<<16 * 16 * 64 / 256, 256, 0, stream>>>(W0,        W0h, W0l, 256, 512, 16);
        cvtB_pack<<<16 * 16 * 64 / 256, 256, 0, stream>>>(Wskip_in,  Wih, Wil, 256, 512, 16);
        cvtB_pack<<<16 * 32 * 64 / 256, 256, 0, stream>>>(W1,        W1h, W1l, 512, 512, 16);
        cvtB_pack<<< 8 * 32 * 64 / 256, 256, 0, stream>>>(W2,        W2h, W2l, 512, 240, 8);
        cvtB_pack<<< 2 * 32 * 64 / 256, 256, 0, stream>>>(Wskip_out, Wsh, Wsl, 512, 40, 2);
    }

    int nodeBlocks = (N * 64 + 255) / 256;

    // ---- Layer 0: in 256 -> 4x128 concat ----
    {
        if (use_mfma) {
            cvtA_pack<<<Rblocks * 16 * 64 / 256 + 1, 256, 0, stream>>>(x, Ah, Al, N, 256, Rblocks);
            launch_gemm(Ah, Al, W0h, W0l, xw,   N, HID, 256, Rblocks, stream);
            launch_gemm(Ah, Al, Wih, Wil, tmpD, N, HID, 256, Rblocks, stream);
        } else {
            launch_sgemm(x, W0, xw, N, HID, N_FEAT, stream);
            launch_sgemm(x, Wskip_in, tmpD, N, HID, N_FEAT, stream);
        }
        int waves = N * 4;
        att_scores<<<(waves * 64 + 255) / 256, 256, 0, stream>>>(
            xw, a_src0, a_dst0, asrc, adst, N, 4, 128);
        edge_alpha<<<(waves * 64 + 255) / 256, 256, 0, stream>>>(
            asrc, adst, row_off, col, alpha, N, 4);
        agg_fused512<<<nodeBlocks, 256, 0, stream>>>(
            xw, alpha, row_off, col, b0, tmpD, x1, N);
    }

    // ---- Layer 1: 512 -> 4x128 concat, residual x1 ----
    {
        if (use_mfma) {
            cvtA_pack<<<Rblocks * 32 * 64 / 256 + 1, 256, 0, stream>>>(x1, Ah, Al, N, 512, Rblocks);
            launch_gemm(Ah, Al, W1h, W1l, xw, N, HID, 512, Rblocks, stream);
        } else {
            launch_sgemm(x1, W1, xw, N, HID, HID, stream);
        }
        int waves = N * 4;
        att_scores<<<(waves * 64 + 255) / 256, 256, 0, stream>>>(
            xw, a_src1, a_dst1, asrc, adst, N, 4, 128);
        edge_alpha<<<(waves * 64 + 255) / 256, 256, 0, stream>>>(
            asrc, adst, row_off, col, alpha, N, 4);
        agg_fused512<<<nodeBlocks, 256, 0, stream>>>(
            xw, alpha, row_off, col, b1, x1, tmpD, N);   // tmpD = x2
    }

    // ---- Layer 2: 512 -> 6x40 mean, + x2@Wskip_out ----
    {
        if (use_mfma) {
            cvtA_pack<<<Rblocks * 32 * 64 / 256 + 1, 256, 0, stream>>>(tmpD, Ah, Al, N, 512, Rblocks);
            launch_gemm(Ah, Al, W2h, W2l, xw,    N, 240, 512, Rblocks, stream);
            launch_gemm(Ah, Al, Wsh, Wsl, skipo, N, 40,  512, Rblocks, stream);
        } else {
            launch_sgemm(tmpD, W2, xw, N, 240, HID, stream);
            launch_sgemm(tmpD, Wskip_out, skipo, N, 40, HID, stream);
        }
        int waves = N * 6;
        att_scores<<<(waves * 64 + 255) / 256, 256, 0, stream>>>(
            xw, a_src2, a_dst2, asrc, adst, N, 6, 40);
        edge_alpha<<<(waves * 64 + 255) / 256, 256, 0, stream>>>(
            asrc, adst, row_off, col, alpha, N, 6);
        agg_final240<<<nodeBlocks, 256, 0, stream>>>(
            xw, alpha, row_off, col, b2, skipo, out, N);
    }
}

// Round 7
// 475.292 us; speedup vs baseline: 1.5235x; 1.0750x over previous
//
#include <hip/hip_runtime.h>
#include <math.h>

// ---------------------------------------------------------------------------
// GAT (3-layer, PyG GATConv semantics) on MI355X.
// Round 7: xw (the per-layer projected features, the gather table of the
// aggregation phase) is stored as bf16 — GEMM epilogue writes bf16 directly,
// halving the dominant gather traffic (155 MB -> ~80 MB HBM per agg).
// Accumulation everywhere stays fp32. Skip-path GEMMs stay fp32.
// ---------------------------------------------------------------------------

#define N_FEAT 256
#define HID 512

using u16 = unsigned short;
using bf16x8 = __attribute__((ext_vector_type(8))) __bf16;
using f32x16 = __attribute__((ext_vector_type(16))) float;

__device__ inline u16 bf16_rne(float f) {
    unsigned u = __float_as_uint(f);
    return (u16)((u + 0x7fffu + ((u >> 16) & 1u)) >> 16);
}
__device__ inline float bf16_to_f32(u16 h) {
    return __uint_as_float((unsigned)h << 16);
}
__device__ inline bf16x8 ldb8(const u16* p) {
    return *reinterpret_cast<const bf16x8*>(p);
}

// ---------------- CSR construction ----------------

__global__ void init_counts(int* cursor, int N) {
    int i = blockIdx.x * blockDim.x + threadIdx.x;
    if (i < N) cursor[i] = 1;  // self loop contributes 1
}

__global__ void count_edges(const int* __restrict__ ei, int E, int* cursor) {
    int e = blockIdx.x * blockDim.x + threadIdx.x;
    if (e < E) atomicAdd(&cursor[ei[E + e]], 1);
}

__global__ __launch_bounds__(1024) void scan_offsets(int* cursor, int* row_off, int N) {
    __shared__ int sdata[1024];
    int tid = threadIdx.x;
    int chunk = (N + 1023) >> 10;
    int base = tid * chunk;
    int lsum = 0;
    for (int i = 0; i < chunk; i++) {
        int idx = base + i;
        if (idx < N) lsum += cursor[idx];
    }
    sdata[tid] = lsum;
    __syncthreads();
    for (int off = 1; off < 1024; off <<= 1) {
        int t = (tid >= off) ? sdata[tid - off] : 0;
        __syncthreads();
        sdata[tid] += t;
        __syncthreads();
    }
    int run = sdata[tid] - lsum;
    if (tid == 0) row_off[0] = 0;
    for (int i = 0; i < chunk; i++) {
        int idx = base + i;
        if (idx < N) {
            int c = cursor[idx];
            cursor[idx] = run;
            run += c;
            row_off[idx + 1] = run;
        }
    }
}

__global__ void fill_csr(const int* __restrict__ ei, int E, int N,
                         int* cursor, int* __restrict__ col) {
    int i = blockIdx.x * blockDim.x + threadIdx.x;
    int tot = E + N;
    if (i >= tot) return;
    int s, d;
    if (i < E) { s = ei[i]; d = ei[E + i]; }
    else       { s = i - E; d = s; }
    int pos = atomicAdd(&cursor[d], 1);
    col[pos] = s;
}

// ---------------- split-bf16 packing ----------------
// Packed fragment layout (32-row/col blocks, 16-k chunks):
//   slot index = ((blk * (K/16) + c) * 64 + lane) * 8
//   lane&31 -> row(col) within block ; lane>>5 -> k-subgroup (8 consecutive k)

__global__ __launch_bounds__(256) void cvtA_pack(const float* __restrict__ X,
                                                 u16* __restrict__ hi, u16* __restrict__ lo,
                                                 int M, int K, int Rblocks) {
    int gid = blockIdx.x * blockDim.x + threadIdx.x;
    int lane = gid & 63;
    int rest = gid >> 6;                 // R * KC + c
    int KC = K >> 4;
    int R = rest / KC;
    int c = rest - R * KC;
    if (R >= Rblocks) return;
    int row = R * 32 + (lane & 31);
    if (row >= M) row = M - 1;           // clamp: clamped rows never stored
    const float* src = X + (size_t)row * K + c * 16 + (lane >> 5) * 8;
    float4 v0 = *reinterpret_cast<const float4*>(src);
    float4 v1 = *reinterpret_cast<const float4*>(src + 4);
    float vv[8] = {v0.x, v0.y, v0.z, v0.w, v1.x, v1.y, v1.z, v1.w};
    unsigned hp[4], lp[4];
    #pragma unroll
    for (int j = 0; j < 4; j++) {
        u16 h0 = bf16_rne(vv[2 * j]);
        u16 h1 = bf16_rne(vv[2 * j + 1]);
        float r0 = vv[2 * j]     - __uint_as_float((unsigned)h0 << 16);
        float r1 = vv[2 * j + 1] - __uint_as_float((unsigned)h1 << 16);
        u16 l0 = bf16_rne(r0);
        u16 l1 = bf16_rne(r1);
        hp[j] = (unsigned)h0 | ((unsigned)h1 << 16);
        lp[j] = (unsigned)l0 | ((unsigned)l1 << 16);
    }
    size_t dst = ((size_t)rest * 64 + lane) * 8;
    *reinterpret_cast<int4*>(hi + dst) = make_int4(hp[0], hp[1], hp[2], hp[3]);
    *reinterpret_cast<int4*>(lo + dst) = make_int4(lp[0], lp[1], lp[2], lp[3]);
}

// B [K][N] -> packed B^T fragments (col blocks of 32), cols >= N zero-filled.
__global__ __launch_bounds__(256) void cvtB_pack(const float* __restrict__ B,
                                                 u16* __restrict__ hi, u16* __restrict__ lo,
                                                 int K, int N, int Cblocks) {
    int gid = blockIdx.x * blockDim.x + threadIdx.x;
    int lane = gid & 63;
    int rest = gid >> 6;                 // Cb * KC + c
    int KC = K >> 4;
    int Cb = rest / KC;
    int c = rest - Cb * KC;
    if (Cb >= Cblocks) return;
    int n = Cb * 32 + (lane & 31);
    int kbase = c * 16 + (lane >> 5) * 8;
    float vv[8];
    #pragma unroll
    for (int j = 0; j < 8; j++)
        vv[j] = (n < N) ? B[(size_t)(kbase + j) * N + n] : 0.f;
    unsigned hp[4], lp[4];
    #pragma unroll
    for (int j = 0; j < 4; j++) {
        u16 h0 = bf16_rne(vv[2 * j]);
        u16 h1 = bf16_rne(vv[2 * j + 1]);
        float r0 = vv[2 * j]     - __uint_as_float((unsigned)h0 << 16);
        float r1 = vv[2 * j + 1] - __uint_as_float((unsigned)h1 << 16);
        u16 l0 = bf16_rne(r0);
        u16 l1 = bf16_rne(r1);
        hp[j] = (unsigned)h0 | ((unsigned)h1 << 16);
        lp[j] = (unsigned)l0 | ((unsigned)l1 << 16);
    }
    size_t dst = ((size_t)rest * 64 + lane) * 8;
    *reinterpret_cast<int4*>(hi + dst) = make_int4(hp[0], hp[1], hp[2], hp[3]);
    *reinterpret_cast<int4*>(lo + dst) = make_int4(lp[0], lp[1], lp[2], lp[3]);
}

// ---------------- MFMA GEMM: C[M,N] = A[M,K] @ B[K,N] ----------------
// 128x64 block, 4 waves (2x2), wave tile 64x32 = 2 m-frags of 32x32.
// 3-term split-bf16; packed operands; XCD-swizzled 1D grid.
// BF16OUT=1 stores C as bf16 (u16), else fp32.

template <int BF16OUT>
__global__ __launch_bounds__(256) void gemm_mfma(const u16* __restrict__ Ahi,
                                                 const u16* __restrict__ Alo,
                                                 const u16* __restrict__ Bhi,
                                                 const u16* __restrict__ Blo,
                                                 void* __restrict__ Cout,
                                                 int M, int N, int K,
                                                 int ntiles, int Rblocks) {
    int nwg = gridDim.x, b = blockIdx.x;
    int q = nwg >> 3, r = nwg & 7;
    int xcd = b & 7, idx = b >> 3;
    int t = (xcd < r) ? (xcd * (q + 1) + idx)
                      : (r * (q + 1) + (xcd - r) * q + idx);
    int bm = (t / ntiles) * 128;
    int bn = (t - (t / ntiles) * ntiles) * 64;

    int lane = threadIdx.x & 63, w = threadIdx.x >> 6;
    int wr = w >> 1, wc = w & 1;
    int l31 = lane & 31, lg = lane >> 5;
    int KC = K >> 4;

    int R0 = (bm + wr * 64) >> 5;               // m-frag0 row-block
    int R1 = R0 + 1;
    if (R0 >= Rblocks) R0 = Rblocks - 1;        // OOB tiles: load garbage, no store
    if (R1 >= Rblocks) R1 = Rblocks - 1;
    int Cb = (bn + wc * 32) >> 5;

    const u16* pa0h = Ahi + (((size_t)R0 * KC) * 64 + lane) * 8;
    const u16* pa0l = Alo + (((size_t)R0 * KC) * 64 + lane) * 8;
    const u16* pa1h = Ahi + (((size_t)R1 * KC) * 64 + lane) * 8;
    const u16* pa1l = Alo + (((size_t)R1 * KC) * 64 + lane) * 8;
    const u16* pbh  = Bhi + (((size_t)Cb * KC) * 64 + lane) * 8;
    const u16* pbl  = Blo + (((size_t)Cb * KC) * 64 + lane) * 8;

    f32x16 acc0, acc1;
    #pragma unroll
    for (int i2 = 0; i2 < 16; i2++) { acc0[i2] = 0.f; acc1[i2] = 0.f; }

    bf16x8 a0h = ldb8(pa0h), a0l = ldb8(pa0l);
    bf16x8 a1h = ldb8(pa1h), a1l = ldb8(pa1l);
    bf16x8 bh  = ldb8(pbh),  bl  = ldb8(pbl);

    for (int c = 1; c <= KC; c++) {
        size_t off = (size_t)c * 512;           // 64 lanes * 8 u16
        bf16x8 na0h = ldb8(pa0h + off), na0l = ldb8(pa0l + off);
        bf16x8 na1h = ldb8(pa1h + off), na1l = ldb8(pa1l + off);
        bf16x8 nbh  = ldb8(pbh + off),  nbl  = ldb8(pbl + off);
        acc0 = __builtin_amdgcn_mfma_f32_32x32x16_bf16(a0h, bh, acc0, 0, 0, 0);
        acc1 = __builtin_amdgcn_mfma_f32_32x32x16_bf16(a1h, bh, acc1, 0, 0, 0);
        acc0 = __builtin_amdgcn_mfma_f32_32x32x16_bf16(a0h, bl, acc0, 0, 0, 0);
        acc1 = __builtin_amdgcn_mfma_f32_32x32x16_bf16(a1h, bl, acc1, 0, 0, 0);
        acc0 = __builtin_amdgcn_mfma_f32_32x32x16_bf16(a0l, bh, acc0, 0, 0, 0);
        acc1 = __builtin_amdgcn_mfma_f32_32x32x16_bf16(a1l, bh, acc1, 0, 0, 0);
        a0h = na0h; a0l = na0l; a1h = na1h; a1l = na1l; bh = nbh; bl = nbl;
    }

    int n = bn + wc * 32 + l31;
    int base_m = bm + wr * 64;
    if (n < N) {
        #pragma unroll
        for (int rg = 0; rg < 16; rg++) {
            int mrow = (rg & 3) + 8 * (rg >> 2) + 4 * lg;
            int m0 = base_m + mrow;
            int m1 = m0 + 32;
            if (BF16OUT) {
                u16* C = (u16*)Cout;
                if (m0 < M) C[(size_t)m0 * N + n] = bf16_rne(acc0[rg]);
                if (m1 < M) C[(size_t)m1 * N + n] = bf16_rne(acc1[rg]);
            } else {
                float* C = (float*)Cout;
                if (m0 < M) C[(size_t)m0 * N + n] = acc0[rg];
                if (m1 < M) C[(size_t)m1 * N + n] = acc1[rg];
            }
        }
    }
}

// ---------------- attention scores: a_src/a_dst [N,H], xw in bf16 --------

__global__ __launch_bounds__(256) void att_scores(const u16* __restrict__ xw,
                                                  const float* __restrict__ att_s,
                                                  const float* __restrict__ att_d,
                                                  float* __restrict__ asrc,
                                                  float* __restrict__ adst,
                                                  int N, int H, int C) {
    int w = (blockIdx.x * blockDim.x + threadIdx.x) >> 6;
    int lane = threadIdx.x & 63;
    if (w >= N * H) return;
    int n = w / H, h = w - n * H;
    const u16* xp = &xw[((size_t)n * H + h) * C];
    float vs = 0.f, vd = 0.f;
    for (int c = lane; c < C; c += 64) {
        float v = bf16_to_f32(xp[c]);
        vs = fmaf(v, att_s[h * C + c], vs);
        vd = fmaf(v, att_d[h * C + c], vd);
    }
    #pragma unroll
    for (int off = 32; off; off >>= 1) {
        vs += __shfl_xor(vs, off);
        vd += __shfl_xor(vd, off);
    }
    if (lane == 0) { asrc[n * H + h] = vs; adst[n * H + h] = vd; }
}

// ---------------- phase 1: normalized edge attention ----------------

__global__ __launch_bounds__(256) void edge_alpha(const float* __restrict__ asrc,
                                                  const float* __restrict__ adst,
                                                  const int* __restrict__ row_off,
                                                  const int* __restrict__ col,
                                                  float* __restrict__ alpha,
                                                  int N, int H) {
    int w = (blockIdx.x * blockDim.x + threadIdx.x) >> 6;
    int lane = threadIdx.x & 63;
    if (w >= N * H) return;
    int n = w / H, h = w - n * H;
    int jb = row_off[n], je = row_off[n + 1];
    float adn = adst[n * H + h];

    float m = -INFINITY;
    for (int j = jb + lane; j < je; j += 64) {
        float e = asrc[col[j] * H + h] + adn;
        e = e > 0.f ? e : 0.2f * e;
        m = fmaxf(m, e);
    }
    #pragma unroll
    for (int off = 32; off; off >>= 1) m = fmaxf(m, __shfl_xor(m, off));

    float ssum = 0.f;
    for (int j = jb + lane; j < je; j += 64) {
        float e = asrc[col[j] * H + h] + adn;
        e = e > 0.f ? e : 0.2f * e;
        ssum += __expf(e - m);
    }
    #pragma unroll
    for (int off = 32; off; off >>= 1) ssum += __shfl_xor(ssum, off);
    float inv = 1.f / (ssum + 1e-16f);

    for (int j = jb + lane; j < je; j += 64) {
        float e = asrc[col[j] * H + h] + adn;
        e = e > 0.f ? e : 0.2f * e;
        alpha[(size_t)j * H + h] = __expf(e - m) * inv;
    }
}

// ---------------- phase 2: aggregation, wave per node, H=4, C=128 --------
// xw bf16: lane reads 8 bf16 (16B, one uint4). fused elu(agg+bias+skip).

__global__ __launch_bounds__(256) void agg_fused512(const u16* __restrict__ xw,
                                                    const float* __restrict__ alpha,
                                                    const int* __restrict__ row_off,
                                                    const int* __restrict__ col,
                                                    const float* __restrict__ bias,
                                                    const float* __restrict__ skip,
                                                    float* __restrict__ out,
                                                    int N) {
    int w = (blockIdx.x * blockDim.x + threadIdx.x) >> 6;  // node
    int lane = threadIdx.x & 63;
    if (w >= N) return;
    int base = lane * 8;
    int hme = lane >> 4;

    float acc[8] = {};
    int jb = row_off[w], je = row_off[w + 1];
    int s = (jb < je) ? col[jb] : 0;
    for (int j = jb; j < je; ++j) {
        int snext = (j + 1 < je) ? col[j + 1] : 0;
        float a = alpha[(size_t)j * 4 + hme];
        uint4 raw = *reinterpret_cast<const uint4*>(&xw[(size_t)s * 512 + base]);
        acc[0] = fmaf(a, __uint_as_float(raw.x << 16), acc[0]);
        acc[1] = fmaf(a, __uint_as_float(raw.x & 0xffff0000u), acc[1]);
        acc[2] = fmaf(a, __uint_as_float(raw.y << 16), acc[2]);
        acc[3] = fmaf(a, __uint_as_float(raw.y & 0xffff0000u), acc[3]);
        acc[4] = fmaf(a, __uint_as_float(raw.z << 16), acc[4]);
        acc[5] = fmaf(a, __uint_as_float(raw.z & 0xffff0000u), acc[5]);
        acc[6] = fmaf(a, __uint_as_float(raw.w << 16), acc[6]);
        acc[7] = fmaf(a, __uint_as_float(raw.w & 0xffff0000u), acc[7]);
        s = snext;
    }

    const float* bp = &bias[base];
    const float* kp = &skip[(size_t)w * 512 + base];
    float r[8];
    #pragma unroll
    for (int i = 0; i < 8; i++) {
        float v = acc[i] + bp[i] + kp[i];
        r[i] = v > 0.f ? v : expm1f(v);          // elu
    }
    float* op = &out[(size_t)w * 512 + base];
    *reinterpret_cast<float4*>(op)     = make_float4(r[0], r[1], r[2], r[3]);
    *reinterpret_cast<float4*>(op + 4) = make_float4(r[4], r[5], r[6], r[7]);
}

// ---------------- phase 2 (layer 2): H=6, C=40, head-mean + skip ---------

__global__ __launch_bounds__(256) void agg_final240(const u16* __restrict__ xw,
                                                    const float* __restrict__ alpha,
                                                    const int* __restrict__ row_off,
                                                    const int* __restrict__ col,
                                                    const float* __restrict__ b2,
                                                    const float* __restrict__ skip,
                                                    float* __restrict__ out,
                                                    int N) {
    int w = (blockIdx.x * blockDim.x + threadIdx.x) >> 6;  // node
    int lane = threadIdx.x & 63;
    if (w >= N) return;
    bool active = lane < 40;

    float acc[6] = {};
    int jb = row_off[w], je = row_off[w + 1];
    int s = (jb < je) ? col[jb] : 0;
    for (int j = jb; j < je; ++j) {
        int snext = (j + 1 < je) ? col[j + 1] : 0;
        const float* ap = &alpha[(size_t)j * 6];
        if (active) {
            const u16* sp = &xw[(size_t)s * 240 + lane];
            #pragma unroll
            for (int h = 0; h < 6; h++)
                acc[h] = fmaf(ap[h], bf16_to_f32(sp[h * 40]), acc[h]);
        }
        s = snext;
    }
    if (active) {
        float v = (acc[0] + acc[1] + acc[2] + acc[3] + acc[4] + acc[5]) * (1.f / 6.f)
                  + b2[lane] + skip[(size_t)w * 40 + lane];
        out[(size_t)w * 40 + lane] = v;
    }
}

// ---------------- orchestration ----------------

template <int BF16OUT>
static inline void launch_gemm(const u16* Ah, const u16* Al,
                               const u16* Bh, const u16* Bl, void* C,
                               int M, int N, int K, int Rblocks, hipStream_t stream) {
    int mtiles = (M + 127) / 128;
    int ntiles = (N + 63) / 64;
    gemm_mfma<BF16OUT><<<mtiles * ntiles, 256, 0, stream>>>(Ah, Al, Bh, Bl, C,
                                                            M, N, K, ntiles, Rblocks);
}

extern "C" void kernel_launch(void* const* d_in, const int* in_sizes, int n_in,
                              void* d_out, int out_size, void* d_ws, size_t ws_size,
                              hipStream_t stream) {
    const float* x        = (const float*)d_in[0];
    const int*   ei       = (const int*)  d_in[1];
    const float* W0       = (const float*)d_in[2];
    const float* a_src0   = (const float*)d_in[3];
    const float* a_dst0   = (const float*)d_in[4];
    const float* b0       = (const float*)d_in[5];
    const float* Wskip_in = (const float*)d_in[6];
    const float* W1       = (const float*)d_in[7];
    const float* a_src1   = (const float*)d_in[8];
    const float* a_dst1   = (const float*)d_in[9];
    const float* b1       = (const float*)d_in[10];
    const float* W2       = (const float*)d_in[11];
    const float* a_src2   = (const float*)d_in[12];
    const float* a_dst2   = (const float*)d_in[13];
    const float* b2       = (const float*)d_in[14];
    const float* Wskip_out= (const float*)d_in[15];

    const int N = in_sizes[0] / N_FEAT;     // 10000
    const int E = in_sizes[1] / 2;          // 160000
    float* out = (float*)d_out;

    const int Rblocks = (N + 31) / 32;      // 313

    // ---------- workspace layout ----------
    float* ws = (float*)d_ws;
    size_t o = 0;
    u16* xwb = (u16*)(ws + o); o += (size_t)N * 256;   // N*512 bf16
    float* x1    = ws + o; o += (size_t)N * HID;
    float* tmpD  = ws + o; o += (size_t)N * HID;       // skip_in (L0), then x2
    float* asrc  = ws + o; o += (size_t)N * 8;
    float* adst  = ws + o; o += (size_t)N * 8;
    float* skipo = ws + o; o += (size_t)N * 40;

    u16* up = (u16*)(ws + o);
    size_t uo = 0;
    const size_t aPack = (size_t)Rblocks * 32 * 512 + 512;  // K=512 worst case
    u16* Ah  = up + uo; uo += aPack;
    u16* Al  = up + uo; uo += aPack;
    const size_t w0sz = (size_t)16 * 16 * 512 + 512;   // Cb=16, KC=16
    u16* W0h = up + uo; uo += w0sz;  u16* W0l = up + uo; uo += w0sz;
    u16* Wih = up + uo; uo += w0sz;  u16* Wil = up + uo; uo += w0sz;
    const size_t w1sz = (size_t)16 * 32 * 512 + 512;   // Cb=16, KC=32
    u16* W1h = up + uo; uo += w1sz;  u16* W1l = up + uo; uo += w1sz;
    const size_t w2sz = (size_t)8 * 32 * 512 + 512;    // Cb=8, KC=32
    u16* W2h = up + uo; uo += w2sz;  u16* W2l = up + uo; uo += w2sz;
    const size_t wssz = (size_t)2 * 32 * 512 + 512;    // Cb=2, KC=32
    u16* Wsh = up + uo; uo += wssz;  u16* Wsl = up + uo; uo += wssz;
    int* row_off = (int*)(up + uo);
    int* cursor  = row_off + (N + 1);
    int* col     = cursor + (N + 1);
    // alpha aliases Ah: Ah dead after each layer's GEMMs; alpha dead before
    // the next layer's cvtA_pack (stream-ordered, no overlap).
    float* alpha = (float*)Ah;

    // ---- CSR by destination (includes self loops) ----
    init_counts<<<(N + 255) / 256, 256, 0, stream>>>(cursor, N);
    count_edges<<<(E + 255) / 256, 256, 0, stream>>>(ei, E, cursor);
    scan_offsets<<<1, 1024, 0, stream>>>(cursor, row_off, N);
    fill_csr<<<(E + N + 255) / 256, 256, 0, stream>>>(ei, E, N, cursor, col);

    // ---- weight packing (B^T fragment layout, hi/lo split) ----
    cvtB_pack<<<16 * 16 * 64 / 256, 256, 0, stream>>>(W0,        W0h, W0l, 256, 512, 16);
    cvtB_pack<<<16 * 16 * 64 / 256, 256, 0, stream>>>(Wskip_in,  Wih, Wil, 256, 512, 16);
    cvtB_pack<<<16 * 32 * 64 / 256, 256, 0, stream>>>(W1,        W1h, W1l, 512, 512, 16);
    cvtB_pack<<< 8 * 32 * 64 / 256, 256, 0, stream>>>(W2,        W2h, W2l, 512, 240, 8);
    cvtB_pack<<< 2 * 32 * 64 / 256, 256, 0, stream>>>(Wskip_out, Wsh, Wsl, 512, 40, 2);

    int nodeBlocks = (N * 64 + 255) / 256;

    // ---- Layer 0: in 256 -> 4x128 concat ----
    {
        cvtA_pack<<<Rblocks * 16 * 64 / 256 + 1, 256, 0, stream>>>(x, Ah, Al, N, 256, Rblocks);
        launch_gemm<1>(Ah, Al, W0h, W0l, xwb,  N, HID, 256, Rblocks, stream);
        launch_gemm<0>(Ah, Al, Wih, Wil, tmpD, N, HID, 256, Rblocks, stream);
        int waves = N * 4;
        att_scores<<<(waves * 64 + 255) / 256, 256, 0, stream>>>(
            xwb, a_src0, a_dst0, asrc, adst, N, 4, 128);
        edge_alpha<<<(waves * 64 + 255) / 256, 256, 0, stream>>>(
            asrc, adst, row_off, col, alpha, N, 4);
        agg_fused512<<<nodeBlocks, 256, 0, stream>>>(
            xwb, alpha, row_off, col, b0, tmpD, x1, N);
    }

    // ---- Layer 1: 512 -> 4x128 concat, residual x1 ----
    {
        cvtA_pack<<<Rblocks * 32 * 64 / 256 + 1, 256, 0, stream>>>(x1, Ah, Al, N, 512, Rblocks);
        launch_gemm<1>(Ah, Al, W1h, W1l, xwb, N, HID, 512, Rblocks, stream);
        int waves = N * 4;
        att_scores<<<(waves * 64 + 255) / 256, 256, 0, stream>>>(
            xwb, a_src1, a_dst1, asrc, adst, N, 4, 128);
        edge_alpha<<<(waves * 64 + 255) / 256, 256, 0, stream>>>(
            asrc, adst, row_off, col, alpha, N, 4);
        agg_fused512<<<nodeBlocks, 256, 0, stream>>>(
            xwb, alpha, row_off, col, b1, x1, tmpD, N);   // tmpD = x2
    }

    // ---- Layer 2: 512 -> 6x40 mean, + x2@Wskip_out ----
    {
        cvtA_pack<<<Rblocks * 32 * 64 / 256 + 1, 256, 0, stream>>>(tmpD, Ah, Al, N, 512, Rblocks);
        launch_gemm<1>(Ah, Al, W2h, W2l, xwb,   N, 240, 512, Rblocks, stream);
        launch_gemm<0>(Ah, Al, Wsh, Wsl, skipo, N, 40,  512, Rblocks, stream);
        int waves = N * 6;
        att_scores<<<(waves * 64 + 255) / 256, 256, 0, stream>>>(
            xwb, a_src2, a_dst2, asrc, adst, N, 6, 40);
        edge_alpha<<<(waves * 64 + 255) / 256, 256, 0, stream>>>(
            asrc, adst, row_off, col, alpha, N, 6);
        agg_final240<<<nodeBlocks, 256, 0, stream>>>(
            xwb, alpha, row_off, col, b2, skipo, out, N);
    }
}

// Round 8
// 439.672 us; speedup vs baseline: 1.6469x; 1.0810x over previous
//
#include <hip/hip_runtime.h>
#include <math.h>

// ---------------------------------------------------------------------------
// GAT (3-layer, PyG GATConv semantics) on MI355X.
// Round 8: latency-focused:
//   - edge_alpha_fused<H>: one wave per node, ALL heads in one single pass
//     (e-values in registers), contiguous asrc-row loads.
//   - agg_fused512: 4-edge unroll -> 4 gathers in flight (MLP).
//   - agg_final240: 2-edge unroll.
// GEMM path (split-bf16 MFMA, bf16 xw) unchanged from round 7.
// ---------------------------------------------------------------------------

#define N_FEAT 256
#define HID 512

using u16 = unsigned short;
using bf16x8 = __attribute__((ext_vector_type(8))) __bf16;
using f32x16 = __attribute__((ext_vector_type(16))) float;

__device__ inline u16 bf16_rne(float f) {
    unsigned u = __float_as_uint(f);
    return (u16)((u + 0x7fffu + ((u >> 16) & 1u)) >> 16);
}
__device__ inline float bf16_to_f32(u16 h) {
    return __uint_as_float((unsigned)h << 16);
}
__device__ inline bf16x8 ldb8(const u16* p) {
    return *reinterpret_cast<const bf16x8*>(p);
}

// ---------------- CSR construction ----------------

__global__ void init_counts(int* cursor, int N) {
    int i = blockIdx.x * blockDim.x + threadIdx.x;
    if (i < N) cursor[i] = 1;  // self loop contributes 1
}

__global__ void count_edges(const int* __restrict__ ei, int E, int* cursor) {
    int e = blockIdx.x * blockDim.x + threadIdx.x;
    if (e < E) atomicAdd(&cursor[ei[E + e]], 1);
}

__global__ __launch_bounds__(1024) void scan_offsets(int* cursor, int* row_off, int N) {
    __shared__ int sdata[1024];
    int tid = threadIdx.x;
    int chunk = (N + 1023) >> 10;
    int base = tid * chunk;
    int lsum = 0;
    for (int i = 0; i < chunk; i++) {
        int idx = base + i;
        if (idx < N) lsum += cursor[idx];
    }
    sdata[tid] = lsum;
    __syncthreads();
    for (int off = 1; off < 1024; off <<= 1) {
        int t = (tid >= off) ? sdata[tid - off] : 0;
        __syncthreads();
        sdata[tid] += t;
        __syncthreads();
    }
    int run = sdata[tid] - lsum;
    if (tid == 0) row_off[0] = 0;
    for (int i = 0; i < chunk; i++) {
        int idx = base + i;
        if (idx < N) {
            int c = cursor[idx];
            cursor[idx] = run;
            run += c;
            row_off[idx + 1] = run;
        }
    }
}

__global__ void fill_csr(const int* __restrict__ ei, int E, int N,
                         int* cursor, int* __restrict__ col) {
    int i = blockIdx.x * blockDim.x + threadIdx.x;
    int tot = E + N;
    if (i >= tot) return;
    int s, d;
    if (i < E) { s = ei[i]; d = ei[E + i]; }
    else       { s = i - E; d = s; }
    int pos = atomicAdd(&cursor[d], 1);
    col[pos] = s;
}

// ---------------- split-bf16 packing ----------------

__global__ __launch_bounds__(256) void cvtA_pack(const float* __restrict__ X,
                                                 u16* __restrict__ hi, u16* __restrict__ lo,
                                                 int M, int K, int Rblocks) {
    int gid = blockIdx.x * blockDim.x + threadIdx.x;
    int lane = gid & 63;
    int rest = gid >> 6;                 // R * KC + c
    int KC = K >> 4;
    int R = rest / KC;
    int c = rest - R * KC;
    if (R >= Rblocks) return;
    int row = R * 32 + (lane & 31);
    if (row >= M) row = M - 1;           // clamp: clamped rows never stored
    const float* src = X + (size_t)row * K + c * 16 + (lane >> 5) * 8;
    float4 v0 = *reinterpret_cast<const float4*>(src);
    float4 v1 = *reinterpret_cast<const float4*>(src + 4);
    float vv[8] = {v0.x, v0.y, v0.z, v0.w, v1.x, v1.y, v1.z, v1.w};
    unsigned hp[4], lp[4];
    #pragma unroll
    for (int j = 0; j < 4; j++) {
        u16 h0 = bf16_rne(vv[2 * j]);
        u16 h1 = bf16_rne(vv[2 * j + 1]);
        float r0 = vv[2 * j]     - __uint_as_float((unsigned)h0 << 16);
        float r1 = vv[2 * j + 1] - __uint_as_float((unsigned)h1 << 16);
        u16 l0 = bf16_rne(r0);
        u16 l1 = bf16_rne(r1);
        hp[j] = (unsigned)h0 | ((unsigned)h1 << 16);
        lp[j] = (unsigned)l0 | ((unsigned)l1 << 16);
    }
    size_t dst = ((size_t)rest * 64 + lane) * 8;
    *reinterpret_cast<int4*>(hi + dst) = make_int4(hp[0], hp[1], hp[2], hp[3]);
    *reinterpret_cast<int4*>(lo + dst) = make_int4(lp[0], lp[1], lp[2], lp[3]);
}

__global__ __launch_bounds__(256) void cvtB_pack(const float* __restrict__ B,
                                                 u16* __restrict__ hi, u16* __restrict__ lo,
                                                 int K, int N, int Cblocks) {
    int gid = blockIdx.x * blockDim.x + threadIdx.x;
    int lane = gid & 63;
    int rest = gid >> 6;                 // Cb * KC + c
    int KC = K >> 4;
    int Cb = rest / KC;
    int c = rest - Cb * KC;
    if (Cb >= Cblocks) return;
    int n = Cb * 32 + (lane & 31);
    int kbase = c * 16 + (lane >> 5) * 8;
    float vv[8];
    #pragma unroll
    for (int j = 0; j < 8; j++)
        vv[j] = (n < N) ? B[(size_t)(kbase + j) * N + n] : 0.f;
    unsigned hp[4], lp[4];
    #pragma unroll
    for (int j = 0; j < 4; j++) {
        u16 h0 = bf16_rne(vv[2 * j]);
        u16 h1 = bf16_rne(vv[2 * j + 1]);
        float r0 = vv[2 * j]     - __uint_as_float((unsigned)h0 << 16);
        float r1 = vv[2 * j + 1] - __uint_as_float((unsigned)h1 << 16);
        u16 l0 = bf16_rne(r0);
        u16 l1 = bf16_rne(r1);
        hp[j] = (unsigned)h0 | ((unsigned)h1 << 16);
        lp[j] = (unsigned)l0 | ((unsigned)l1 << 16);
    }
    size_t dst = ((size_t)rest * 64 + lane) * 8;
    *reinterpret_cast<int4*>(hi + dst) = make_int4(hp[0], hp[1], hp[2], hp[3]);
    *reinterpret_cast<int4*>(lo + dst) = make_int4(lp[0], lp[1], lp[2], lp[3]);
}

// ---------------- MFMA GEMM (unchanged from round 7) ----------------

template <int BF16OUT>
__global__ __launch_bounds__(256) void gemm_mfma(const u16* __restrict__ Ahi,
                                                 const u16* __restrict__ Alo,
                                                 const u16* __restrict__ Bhi,
                                                 const u16* __restrict__ Blo,
                                                 void* __restrict__ Cout,
                                                 int M, int N, int K,
                                                 int ntiles, int Rblocks) {
    int nwg = gridDim.x, b = blockIdx.x;
    int q = nwg >> 3, r = nwg & 7;
    int xcd = b & 7, idx = b >> 3;
    int t = (xcd < r) ? (xcd * (q + 1) + idx)
                      : (r * (q + 1) + (xcd - r) * q + idx);
    int bm = (t / ntiles) * 128;
    int bn = (t - (t / ntiles) * ntiles) * 64;

    int lane = threadIdx.x & 63, w = threadIdx.x >> 6;
    int wr = w >> 1, wc = w & 1;
    int l31 = lane & 31, lg = lane >> 5;
    int KC = K >> 4;

    int R0 = (bm + wr * 64) >> 5;
    int R1 = R0 + 1;
    if (R0 >= Rblocks) R0 = Rblocks - 1;
    if (R1 >= Rblocks) R1 = Rblocks - 1;
    int Cb = (bn + wc * 32) >> 5;

    const u16* pa0h = Ahi + (((size_t)R0 * KC) * 64 + lane) * 8;
    const u16* pa0l = Alo + (((size_t)R0 * KC) * 64 + lane) * 8;
    const u16* pa1h = Ahi + (((size_t)R1 * KC) * 64 + lane) * 8;
    const u16* pa1l = Alo + (((size_t)R1 * KC) * 64 + lane) * 8;
    const u16* pbh  = Bhi + (((size_t)Cb * KC) * 64 + lane) * 8;
    const u16* pbl  = Blo + (((size_t)Cb * KC) * 64 + lane) * 8;

    f32x16 acc0, acc1;
    #pragma unroll
    for (int i2 = 0; i2 < 16; i2++) { acc0[i2] = 0.f; acc1[i2] = 0.f; }

    bf16x8 a0h = ldb8(pa0h), a0l = ldb8(pa0l);
    bf16x8 a1h = ldb8(pa1h), a1l = ldb8(pa1l);
    bf16x8 bh  = ldb8(pbh),  bl  = ldb8(pbl);

    for (int c = 1; c <= KC; c++) {
        size_t off = (size_t)c * 512;
        bf16x8 na0h = ldb8(pa0h + off), na0l = ldb8(pa0l + off);
        bf16x8 na1h = ldb8(pa1h + off), na1l = ldb8(pa1l + off);
        bf16x8 nbh  = ldb8(pbh + off),  nbl  = ldb8(pbl + off);
        acc0 = __builtin_amdgcn_mfma_f32_32x32x16_bf16(a0h, bh, acc0, 0, 0, 0);
        acc1 = __builtin_amdgcn_mfma_f32_32x32x16_bf16(a1h, bh, acc1, 0, 0, 0);
        acc0 = __builtin_amdgcn_mfma_f32_32x32x16_bf16(a0h, bl, acc0, 0, 0, 0);
        acc1 = __builtin_amdgcn_mfma_f32_32x32x16_bf16(a1h, bl, acc1, 0, 0, 0);
        acc0 = __builtin_amdgcn_mfma_f32_32x32x16_bf16(a0l, bh, acc0, 0, 0, 0);
        acc1 = __builtin_amdgcn_mfma_f32_32x32x16_bf16(a1l, bh, acc1, 0, 0, 0);
        a0h = na0h; a0l = na0l; a1h = na1h; a1l = na1l; bh = nbh; bl = nbl;
    }

    int n = bn + wc * 32 + l31;
    int base_m = bm + wr * 64;
    if (n < N) {
        #pragma unroll
        for (int rg = 0; rg < 16; rg++) {
            int mrow = (rg & 3) + 8 * (rg >> 2) + 4 * lg;
            int m0 = base_m + mrow;
            int m1 = m0 + 32;
            if (BF16OUT) {
                u16* C = (u16*)Cout;
                if (m0 < M) C[(size_t)m0 * N + n] = bf16_rne(acc0[rg]);
                if (m1 < M) C[(size_t)m1 * N + n] = bf16_rne(acc1[rg]);
            } else {
                float* C = (float*)Cout;
                if (m0 < M) C[(size_t)m0 * N + n] = acc0[rg];
                if (m1 < M) C[(size_t)m1 * N + n] = acc1[rg];
            }
        }
    }
}

// ---------------- attention scores: a_src/a_dst [N,H], xw in bf16 --------

__global__ __launch_bounds__(256) void att_scores(const u16* __restrict__ xw,
                                                  const float* __restrict__ att_s,
                                                  const float* __restrict__ att_d,
                                                  float* __restrict__ asrc,
                                                  float* __restrict__ adst,
                                                  int N, int H, int C) {
    int w = (blockIdx.x * blockDim.x + threadIdx.x) >> 6;
    int lane = threadIdx.x & 63;
    if (w >= N * H) return;
    int n = w / H, h = w - n * H;
    const u16* xp = &xw[((size_t)n * H + h) * C];
    float vs = 0.f, vd = 0.f;
    for (int c = lane; c < C; c += 64) {
        float v = bf16_to_f32(xp[c]);
        vs = fmaf(v, att_s[h * C + c], vs);
        vd = fmaf(v, att_d[h * C + c], vd);
    }
    #pragma unroll
    for (int off = 32; off; off >>= 1) {
        vs += __shfl_xor(vs, off);
        vd += __shfl_xor(vd, off);
    }
    if (lane == 0) { asrc[n * H + h] = vs; adst[n * H + h] = vd; }
}

// ---------------- phase 1: fused all-heads single-pass edge softmax -------
// one wave per node; lane j holds edge jb+c*64+j's e-values (all H heads) in
// registers. CHUNKS*64 edges fast-path; correct (recompute) fallback beyond.

template <int H, int CHUNKS>
__global__ __launch_bounds__(256) void edge_alpha_fused(const float* __restrict__ asrc,
                                                        const float* __restrict__ adst,
                                                        const int* __restrict__ row_off,
                                                        const int* __restrict__ col,
                                                        float* __restrict__ alpha,
                                                        int N) {
    int w = (blockIdx.x * blockDim.x + threadIdx.x) >> 6;  // node
    int lane = threadIdx.x & 63;
    if (w >= N) return;
    int jb = row_off[w], je = row_off[w + 1];

    float adn[H];
    #pragma unroll
    for (int h = 0; h < H; h++) adn[h] = adst[(size_t)w * H + h];

    float ev[CHUNKS][H];
    float m[H];
    #pragma unroll
    for (int h = 0; h < H; h++) m[h] = -INFINITY;

    #pragma unroll
    for (int c = 0; c < CHUNKS; c++) {
        int j = jb + c * 64 + lane;
        if (j < je) {
            int s = col[j];
            const float* ap = &asrc[(size_t)s * H];
            #pragma unroll
            for (int h = 0; h < H; h++) {
                float e = ap[h] + adn[h];
                e = e > 0.f ? e : 0.2f * e;
                ev[c][h] = e;
                m[h] = fmaxf(m[h], e);
            }
        } else {
            #pragma unroll
            for (int h = 0; h < H; h++) ev[c][h] = -INFINITY;
        }
    }
    // fallback (deg > CHUNKS*64; never taken at this scale, kept for safety)
    for (int j = jb + CHUNKS * 64 + lane; j < je; j += 64) {
        int s = col[j];
        const float* ap = &asrc[(size_t)s * H];
        #pragma unroll
        for (int h = 0; h < H; h++) {
            float e = ap[h] + adn[h];
            e = e > 0.f ? e : 0.2f * e;
            m[h] = fmaxf(m[h], e);
        }
    }

    #pragma unroll
    for (int off = 32; off; off >>= 1)
        #pragma unroll
        for (int h = 0; h < H; h++) m[h] = fmaxf(m[h], __shfl_xor(m[h], off));

    float ssum[H];
    #pragma unroll
    for (int h = 0; h < H; h++) ssum[h] = 0.f;
    #pragma unroll
    for (int c = 0; c < CHUNKS; c++)
        #pragma unroll
        for (int h = 0; h < H; h++) ssum[h] += __expf(ev[c][h] - m[h]);
    for (int j = jb + CHUNKS * 64 + lane; j < je; j += 64) {
        int s = col[j];
        const float* ap = &asrc[(size_t)s * H];
        #pragma unroll
        for (int h = 0; h < H; h++) {
            float e = ap[h] + adn[h];
            e = e > 0.f ? e : 0.2f * e;
            ssum[h] += __expf(e - m[h]);
        }
    }
    #pragma unroll
    for (int off = 32; off; off >>= 1)
        #pragma unroll
        for (int h = 0; h < H; h++) ssum[h] += __shfl_xor(ssum[h], off);

    float inv[H];
    #pragma unroll
    for (int h = 0; h < H; h++) inv[h] = 1.f / (ssum[h] + 1e-16f);

    #pragma unroll
    for (int c = 0; c < CHUNKS; c++) {
        int j = jb + c * 64 + lane;
        if (j < je) {
            float* op = &alpha[(size_t)j * H];
            #pragma unroll
            for (int h = 0; h < H; h++)
                op[h] = __expf(ev[c][h] - m[h]) * inv[h];
        }
    }
    for (int j = jb + CHUNKS * 64 + lane; j < je; j += 64) {
        int s = col[j];
        const float* ap = &asrc[(size_t)s * H];
        float* op = &alpha[(size_t)j * H];
        #pragma unroll
        for (int h = 0; h < H; h++) {
            float e = ap[h] + adn[h];
            e = e > 0.f ? e : 0.2f * e;
            op[h] = __expf(e - m[h]) * inv[h];
        }
    }
}

// ---------------- phase 2: aggregation, wave per node, H=4, C=128 --------
// 4-edge unroll: 4 independent uint4 gathers in flight per iteration.

__global__ __launch_bounds__(256) void agg_fused512(const u16* __restrict__ xw,
                                                    const float* __restrict__ alpha,
                                                    const int* __restrict__ row_off,
                                                    const int* __restrict__ col,
                                                    const float* __restrict__ bias,
                                                    const float* __restrict__ skip,
                                                    float* __restrict__ out,
                                                    int N) {
    int w = (blockIdx.x * blockDim.x + threadIdx.x) >> 6;  // node
    int lane = threadIdx.x & 63;
    if (w >= N) return;
    int base = lane * 8;
    int hme = lane >> 4;

    float acc[8] = {};
    int jb = row_off[w], je = row_off[w + 1];

    int j = jb;
    for (; j + 3 < je; j += 4) {
        int s0 = col[j], s1 = col[j + 1], s2 = col[j + 2], s3 = col[j + 3];
        float a0 = alpha[(size_t)(j + 0) * 4 + hme];
        float a1 = alpha[(size_t)(j + 1) * 4 + hme];
        float a2 = alpha[(size_t)(j + 2) * 4 + hme];
        float a3 = alpha[(size_t)(j + 3) * 4 + hme];
        uint4 r0 = *reinterpret_cast<const uint4*>(&xw[(size_t)s0 * 512 + base]);
        uint4 r1 = *reinterpret_cast<const uint4*>(&xw[(size_t)s1 * 512 + base]);
        uint4 r2 = *reinterpret_cast<const uint4*>(&xw[(size_t)s2 * 512 + base]);
        uint4 r3 = *reinterpret_cast<const uint4*>(&xw[(size_t)s3 * 512 + base]);
        acc[0] = fmaf(a0, __uint_as_float(r0.x << 16), acc[0]);
        acc[1] = fmaf(a0, __uint_as_float(r0.x & 0xffff0000u), acc[1]);
        acc[2] = fmaf(a0, __uint_as_float(r0.y << 16), acc[2]);
        acc[3] = fmaf(a0, __uint_as_float(r0.y & 0xffff0000u), acc[3]);
        acc[4] = fmaf(a0, __uint_as_float(r0.z << 16), acc[4]);
        acc[5] = fmaf(a0, __uint_as_float(r0.z & 0xffff0000u), acc[5]);
        acc[6] = fmaf(a0, __uint_as_float(r0.w << 16), acc[6]);
        acc[7] = fmaf(a0, __uint_as_float(r0.w & 0xffff0000u), acc[7]);
        acc[0] = fmaf(a1, __uint_as_float(r1.x << 16), acc[0]);
        acc[1] = fmaf(a1, __uint_as_float(r1.x & 0xffff0000u), acc[1]);
        acc[2] = fmaf(a1, __uint_as_float(r1.y << 16), acc[2]);
        acc[3] = fmaf(a1, __uint_as_float(r1.y & 0xffff0000u), acc[3]);
        acc[4] = fmaf(a1, __uint_as_float(r1.z << 16), acc[4]);
        acc[5] = fmaf(a1, __uint_as_float(r1.z & 0xffff0000u), acc[5]);
        acc[6] = fmaf(a1, __uint_as_float(r1.w << 16), acc[6]);
        acc[7] = fmaf(a1, __uint_as_float(r1.w & 0xffff0000u), acc[7]);
        acc[0] = fmaf(a2, __uint_as_float(r2.x << 16), acc[0]);
        acc[1] = fmaf(a2, __uint_as_float(r2.x & 0xffff0000u), acc[1]);
        acc[2] = fmaf(a2, __uint_as_float(r2.y << 16), acc[2]);
        acc[3] = fmaf(a2, __uint_as_float(r2.y & 0xffff0000u), acc[3]);
        acc[4] = fmaf(a2, __uint_as_float(r2.z << 16), acc[4]);
        acc[5] = fmaf(a2, __uint_as_float(r2.z & 0xffff0000u), acc[5]);
        acc[6] = fmaf(a2, __uint_as_float(r2.w << 16), acc[6]);
        acc[7] = fmaf(a2, __uint_as_float(r2.w & 0xffff0000u), acc[7]);
        acc[0] = fmaf(a3, __uint_as_float(r3.x << 16), acc[0]);
        acc[1] = fmaf(a3, __uint_as_float(r3.x & 0xffff0000u), acc[1]);
        acc[2] = fmaf(a3, __uint_as_float(r3.y << 16), acc[2]);
        acc[3] = fmaf(a3, __uint_as_float(r3.y & 0xffff0000u), acc[3]);
        acc[4] = fmaf(a3, __uint_as_float(r3.z << 16), acc[4]);
        acc[5] = fmaf(a3, __uint_as_float(r3.z & 0xffff0000u), acc[5]);
        acc[6] = fmaf(a3, __uint_as_float(r3.w << 16), acc[6]);
        acc[7] = fmaf(a3, __uint_as_float(r3.w & 0xffff0000u), acc[7]);
    }
    for (; j < je; ++j) {
        int s = col[j];
        float a = alpha[(size_t)j * 4 + hme];
        uint4 raw = *reinterpret_cast<const uint4*>(&xw[(size_t)s * 512 + base]);
        acc[0] = fmaf(a, __uint_as_float(raw.x << 16), acc[0]);
        acc[1] = fmaf(a, __uint_as_float(raw.x & 0xffff0000u), acc[1]);
        acc[2] = fmaf(a, __uint_as_float(raw.y << 16), acc[2]);
        acc[3] = fmaf(a, __uint_as_float(raw.y & 0xffff0000u), acc[3]);
        acc[4] = fmaf(a, __uint_as_float(raw.z << 16), acc[4]);
        acc[5] = fmaf(a, __uint_as_float(raw.z & 0xffff0000u), acc[5]);
        acc[6] = fmaf(a, __uint_as_float(raw.w << 16), acc[6]);
        acc[7] = fmaf(a, __uint_as_float(raw.w & 0xffff0000u), acc[7]);
    }

    const float* bp = &bias[base];
    const float* kp = &skip[(size_t)w * 512 + base];
    float r[8];
    #pragma unroll
    for (int i = 0; i < 8; i++) {
        float v = acc[i] + bp[i] + kp[i];
        r[i] = v > 0.f ? v : expm1f(v);          // elu
    }
    float* op = &out[(size_t)w * 512 + base];
    *reinterpret_cast<float4*>(op)     = make_float4(r[0], r[1], r[2], r[3]);
    *reinterpret_cast<float4*>(op + 4) = make_float4(r[4], r[5], r[6], r[7]);
}

// ---------------- phase 2 (layer 2): H=6, C=40, head-mean + skip ---------

__global__ __launch_bounds__(256) void agg_final240(const u16* __restrict__ xw,
                                                    const float* __restrict__ alpha,
                                                    const int* __restrict__ row_off,
                                                    const int* __restrict__ col,
                                                    const float* __restrict__ b2,
                                                    const float* __restrict__ skip,
                                                    float* __restrict__ out,
                                                    int N) {
    int w = (blockIdx.x * blockDim.x + threadIdx.x) >> 6;  // node
    int lane = threadIdx.x & 63;
    if (w >= N) return;
    bool active = lane < 40;

    float acc[6] = {};
    int jb = row_off[w], je = row_off[w + 1];

    int j = jb;
    for (; j + 1 < je; j += 2) {
        int s0 = col[j], s1 = col[j + 1];
        const float* ap0 = &alpha[(size_t)j * 6];
        const float* ap1 = &alpha[(size_t)(j + 1) * 6];
        if (active) {
            const u16* sp0 = &xw[(size_t)s0 * 240 + lane];
            const u16* sp1 = &xw[(size_t)s1 * 240 + lane];
            #pragma unroll
            for (int h = 0; h < 6; h++) {
                acc[h] = fmaf(ap0[h], bf16_to_f32(sp0[h * 40]), acc[h]);
                acc[h] = fmaf(ap1[h], bf16_to_f32(sp1[h * 40]), acc[h]);
            }
        }
    }
    for (; j < je; ++j) {
        int s = col[j];
        const float* ap = &alpha[(size_t)j * 6];
        if (active) {
            const u16* sp = &xw[(size_t)s * 240 + lane];
            #pragma unroll
            for (int h = 0; h < 6; h++)
                acc[h] = fmaf(ap[h], bf16_to_f32(sp[h * 40]), acc[h]);
        }
    }
    if (active) {
        float v = (acc[0] + acc[1] + acc[2] + acc[3] + acc[4] + acc[5]) * (1.f / 6.f)
                  + b2[lane] + skip[(size_t)w * 40 + lane];
        out[(size_t)w * 40 + lane] = v;
    }
}

// ---------------- orchestration ----------------

template <int BF16OUT>
static inline void launch_gemm(const u16* Ah, const u16* Al,
                               const u16* Bh, const u16* Bl, void* C,
                               int M, int N, int K, int Rblocks, hipStream_t stream) {
    int mtiles = (M + 127) / 128;
    int ntiles = (N + 63) / 64;
    gemm_mfma<BF16OUT><<<mtiles * ntiles, 256, 0, stream>>>(Ah, Al, Bh, Bl, C,
                                                            M, N, K, ntiles, Rblocks);
}

extern "C" void kernel_launch(void* const* d_in, const int* in_sizes, int n_in,
                              void* d_out, int out_size, void* d_ws, size_t ws_size,
                              hipStream_t stream) {
    const float* x        = (const float*)d_in[0];
    const int*   ei       = (const int*)  d_in[1];
    const float* W0       = (const float*)d_in[2];
    const float* a_src0   = (const float*)d_in[3];
    const float* a_dst0   = (const float*)d_in[4];
    const float* b0       = (const float*)d_in[5];
    const float* Wskip_in = (const float*)d_in[6];
    const float* W1       = (const float*)d_in[7];
    const float* a_src1   = (const float*)d_in[8];
    const float* a_dst1   = (const float*)d_in[9];
    const float* b1       = (const float*)d_in[10];
    const float* W2       = (const float*)d_in[11];
    const float* a_src2   = (const float*)d_in[12];
    const float* a_dst2   = (const float*)d_in[13];
    const float* b2       = (const float*)d_in[14];
    const float* Wskip_out= (const float*)d_in[15];

    const int N = in_sizes[0] / N_FEAT;     // 10000
    const int E = in_sizes[1] / 2;          // 160000
    float* out = (float*)d_out;

    const int Rblocks = (N + 31) / 32;      // 313

    // ---------- workspace layout ----------
    float* ws = (float*)d_ws;
    size_t o = 0;
    u16* xwb = (u16*)(ws + o); o += (size_t)N * 256;   // N*512 bf16
    float* x1    = ws + o; o += (size_t)N * HID;
    float* tmpD  = ws + o; o += (size_t)N * HID;       // skip_in (L0), then x2
    float* asrc  = ws + o; o += (size_t)N * 8;
    float* adst  = ws + o; o += (size_t)N * 8;
    float* skipo = ws + o; o += (size_t)N * 40;

    u16* up = (u16*)(ws + o);
    size_t uo = 0;
    const size_t aPack = (size_t)Rblocks * 32 * 512 + 512;  // K=512 worst case
    u16* Ah  = up + uo; uo += aPack;
    u16* Al  = up + uo; uo += aPack;
    const size_t w0sz = (size_t)16 * 16 * 512 + 512;   // Cb=16, KC=16
    u16* W0h = up + uo; uo += w0sz;  u16* W0l = up + uo; uo += w0sz;
    u16* Wih = up + uo; uo += w0sz;  u16* Wil = up + uo; uo += w0sz;
    const size_t w1sz = (size_t)16 * 32 * 512 + 512;   // Cb=16, KC=32
    u16* W1h = up + uo; uo += w1sz;  u16* W1l = up + uo; uo += w1sz;
    const size_t w2sz = (size_t)8 * 32 * 512 + 512;    // Cb=8, KC=32
    u16* W2h = up + uo; uo += w2sz;  u16* W2l = up + uo; uo += w2sz;
    const size_t wssz = (size_t)2 * 32 * 512 + 512;    // Cb=2, KC=32
    u16* Wsh = up + uo; uo += wssz;  u16* Wsl = up + uo; uo += wssz;
    int* row_off = (int*)(up + uo);
    int* cursor  = row_off + (N + 1);
    int* col     = cursor + (N + 1);
    // alpha aliases Ah (disjoint live ranges, stream-ordered)
    float* alpha = (float*)Ah;

    // ---- CSR by destination (includes self loops) ----
    init_counts<<<(N + 255) / 256, 256, 0, stream>>>(cursor, N);
    count_edges<<<(E + 255) / 256, 256, 0, stream>>>(ei, E, cursor);
    scan_offsets<<<1, 1024, 0, stream>>>(cursor, row_off, N);
    fill_csr<<<(E + N + 255) / 256, 256, 0, stream>>>(ei, E, N, cursor, col);

    // ---- weight packing (B^T fragment layout, hi/lo split) ----
    cvtB_pack<<<16 * 16 * 64 / 256, 256, 0, stream>>>(W0,        W0h, W0l, 256, 512, 16);
    cvtB_pack<<<16 * 16 * 64 / 256, 256, 0, stream>>>(Wskip_in,  Wih, Wil, 256, 512, 16);
    cvtB_pack<<<16 * 32 * 64 / 256, 256, 0, stream>>>(W1,        W1h, W1l, 512, 512, 16);
    cvtB_pack<<< 8 * 32 * 64 / 256, 256, 0, stream>>>(W2,        W2h, W2l, 512, 240, 8);
    cvtB_pack<<< 2 * 32 * 64 / 256, 256, 0, stream>>>(Wskip_out, Wsh, Wsl, 512, 40, 2);

    int nodeBlocks = (N * 64 + 255) / 256;

    // ---- Layer 0: in 256 -> 4x128 concat ----
    {
        cvtA_pack<<<Rblocks * 16 * 64 / 256 + 1, 256, 0, stream>>>(x, Ah, Al, N, 256, Rblocks);
        launch_gemm<1>(Ah, Al, W0h, W0l, xwb,  N, HID, 256, Rblocks, stream);
        launch_gemm<0>(Ah, Al, Wih, Wil, tmpD, N, HID, 256, Rblocks, stream);
        int waves = N * 4;
        att_scores<<<(waves * 64 + 255) / 256, 256, 0, stream>>>(
            xwb, a_src0, a_dst0, asrc, adst, N, 4, 128);
        edge_alpha_fused<4, 4><<<nodeBlocks, 256, 0, stream>>>(
            asrc, adst, row_off, col, alpha, N);
        agg_fused512<<<nodeBlocks, 256, 0, stream>>>(
            xwb, alpha, row_off, col, b0, tmpD, x1, N);
    }

    // ---- Layer 1: 512 -> 4x128 concat, residual x1 ----
    {
        cvtA_pack<<<Rblocks * 32 * 64 / 256 + 1, 256, 0, stream>>>(x1, Ah, Al, N, 512, Rblocks);
        launch_gemm<1>(Ah, Al, W1h, W1l, xwb, N, HID, 512, Rblocks, stream);
        int waves = N * 4;
        att_scores<<<(waves * 64 + 255) / 256, 256, 0, stream>>>(
            xwb, a_src1, a_dst1, asrc, adst, N, 4, 128);
        edge_alpha_fused<4, 4><<<nodeBlocks, 256, 0, stream>>>(
            asrc, adst, row_off, col, alpha, N);
        agg_fused512<<<nodeBlocks, 256, 0, stream>>>(
            xwb, alpha, row_off, col, b1, x1, tmpD, N);   // tmpD = x2
    }

    // ---- Layer 2: 512 -> 6x40 mean, + x2@Wskip_out ----
    {
        cvtA_pack<<<Rblocks * 32 * 64 / 256 + 1, 256, 0, stream>>>(tmpD, Ah, Al, N, 512, Rblocks);
        launch_gemm<1>(Ah, Al, W2h, W2l, xwb,   N, 240, 512, Rblocks, stream);
        launch_gemm<0>(Ah, Al, Wsh, Wsl, skipo, N, 40,  512, Rblocks, stream);
        int waves = N * 6;
        att_scores<<<(waves * 64 + 255) / 256, 256, 0, stream>>>(
            xwb, a_src2, a_dst2, asrc, adst, N, 6, 40);
        edge_alpha_fused<6, 4><<<nodeBlocks, 256, 0, stream>>>(
            asrc, adst, row_off, col, alpha, N);
        agg_final240<<<nodeBlocks, 256, 0, stream>>>(
            xwb, alpha, row_off, col, b2, skipo, out, N);
    }
}

// Round 9
// 415.598 us; speedup vs baseline: 1.7423x; 1.0579x over previous
//
#include <hip/hip_runtime.h>
#include <math.h>

// ---------------------------------------------------------------------------
// GAT (3-layer, PyG GATConv semantics) on MI355X.
// Round 9: algebraic fusion.
//   - a_src/a_dst are linear in x -> combined weight cols ac[k,2H] appended
//     to each layer's fused GEMM B (att_scores kernels deleted).
//   - L0/L2 skip projections fused as more B columns (one GEMM per layer).
//   - agg epilogue writes the NEXT layer's packed A (hi/lo bf16) directly
//     (cvtA_pack deleted for layers 1,2); L1 residual skip read from pack.
// ws_size is 256 MiB (measured) -> dedicated buffers, no aliasing.
// ---------------------------------------------------------------------------

#define N_FEAT 256
#define HID 512

using u16 = unsigned short;
using bf16x8 = __attribute__((ext_vector_type(8))) __bf16;
using f32x16 = __attribute__((ext_vector_type(16))) float;

__device__ inline u16 bf16_rne(float f) {
    unsigned u = __float_as_uint(f);
    return (u16)((u + 0x7fffu + ((u >> 16) & 1u)) >> 16);
}
__device__ inline float bf16_to_f32(u16 h) {
    return __uint_as_float((unsigned)h << 16);
}
__device__ inline bf16x8 ldb8(const u16* p) {
    return *reinterpret_cast<const bf16x8*>(p);
}

// ---------------- CSR construction ----------------

__global__ void init_counts(int* cursor, int N) {
    int i = blockIdx.x * blockDim.x + threadIdx.x;
    if (i < N) cursor[i] = 1;  // self loop contributes 1
}

__global__ void count_edges(const int* __restrict__ ei, int E, int* cursor) {
    int e = blockIdx.x * blockDim.x + threadIdx.x;
    if (e < E) atomicAdd(&cursor[ei[E + e]], 1);
}

__global__ __launch_bounds__(1024) void scan_offsets(int* cursor, int* row_off, int N) {
    __shared__ int sdata[1024];
    int tid = threadIdx.x;
    int chunk = (N + 1023) >> 10;
    int base = tid * chunk;
    int lsum = 0;
    for (int i = 0; i < chunk; i++) {
        int idx = base + i;
        if (idx < N) lsum += cursor[idx];
    }
    sdata[tid] = lsum;
    __syncthreads();
    for (int off = 1; off < 1024; off <<= 1) {
        int t = (tid >= off) ? sdata[tid - off] : 0;
        __syncthreads();
        sdata[tid] += t;
        __syncthreads();
    }
    int run = sdata[tid] - lsum;
    if (tid == 0) row_off[0] = 0;
    for (int i = 0; i < chunk; i++) {
        int idx = base + i;
        if (idx < N) {
            int c = cursor[idx];
            cursor[idx] = run;
            run += c;
            row_off[idx + 1] = run;
        }
    }
}

__global__ void fill_csr(const int* __restrict__ ei, int E, int N,
                         int* cursor, int* __restrict__ col) {
    int i = blockIdx.x * blockDim.x + threadIdx.x;
    int tot = E + N;
    if (i >= tot) return;
    int s, d;
    if (i < E) { s = ei[i]; d = ei[E + i]; }
    else       { s = i - E; d = s; }
    int pos = atomicAdd(&cursor[d], 1);
    col[pos] = s;
}

// ---------------- attention col combine: ac[k][2H] ----------------
// ac[k][h] = sum_c W[k][h*C+c]*att_s[h][c];  ac[k][H+h] = ... att_d

__global__ __launch_bounds__(256) void att_combine(const float* __restrict__ W,
                                                   const float* __restrict__ as_,
                                                   const float* __restrict__ ad_,
                                                   float* __restrict__ ac,
                                                   int K, int H, int C) {
    int i = blockIdx.x * blockDim.x + threadIdx.x;
    if (i >= K * 2 * H) return;
    int k = i / (2 * H);
    int hh = i - k * 2 * H;
    int h = (hh >= H) ? hh - H : hh;
    const float* av = (hh >= H) ? &ad_[h * C] : &as_[h * C];
    const float* wp = &W[(size_t)k * H * C + (size_t)h * C];
    float sum = 0.f;
    for (int c = 0; c < C; c++) sum = fmaf(wp[c], av[c], sum);
    ac[(size_t)k * 2 * H + hh] = sum;
}

// ---------------- split-bf16 packing ----------------
// slot = ((blk*(K/16) + c)*64 + lane)*8 ; lane&31 = row/col in 32-block,
// lane>>5 = k-subgroup (8 consecutive k of the 16-chunk).

__global__ __launch_bounds__(256) void cvtA_pack(const float* __restrict__ X,
                                                 u16* __restrict__ hi, u16* __restrict__ lo,
                                                 int M, int K, int Rblocks) {
    int gid = blockIdx.x * blockDim.x + threadIdx.x;
    int lane = gid & 63;
    int rest = gid >> 6;                 // R * KC + c
    int KC = K >> 4;
    int R = rest / KC;
    int c = rest - R * KC;
    if (R >= Rblocks) return;
    int row = R * 32 + (lane & 31);
    if (row >= M) row = M - 1;           // clamp: clamped rows never stored
    const float* src = X + (size_t)row * K + c * 16 + (lane >> 5) * 8;
    float4 v0 = *reinterpret_cast<const float4*>(src);
    float4 v1 = *reinterpret_cast<const float4*>(src + 4);
    float vv[8] = {v0.x, v0.y, v0.z, v0.w, v1.x, v1.y, v1.z, v1.w};
    unsigned hp[4], lp[4];
    #pragma unroll
    for (int j = 0; j < 4; j++) {
        u16 h0 = bf16_rne(vv[2 * j]);
        u16 h1 = bf16_rne(vv[2 * j + 1]);
        float r0 = vv[2 * j]     - __uint_as_float((unsigned)h0 << 16);
        float r1 = vv[2 * j + 1] - __uint_as_float((unsigned)h1 << 16);
        u16 l0 = bf16_rne(r0);
        u16 l1 = bf16_rne(r1);
        hp[j] = (unsigned)h0 | ((unsigned)h1 << 16);
        lp[j] = (unsigned)l0 | ((unsigned)l1 << 16);
    }
    size_t dst = ((size_t)rest * 64 + lane) * 8;
    *reinterpret_cast<int4*>(hi + dst) = make_int4(hp[0], hp[1], hp[2], hp[3]);
    *reinterpret_cast<int4*>(lo + dst) = make_int4(lp[0], lp[1], lp[2], lp[3]);
}

// B [K][Nb] -> packed B^T fragments (col blocks of 32), cols >= Nb zero.
// hi/lo pointers may be pre-offset to a block boundary.
__global__ __launch_bounds__(256) void cvtB_pack(const float* __restrict__ B,
                                                 u16* __restrict__ hi, u16* __restrict__ lo,
                                                 int K, int Nb, int Cblocks) {
    int gid = blockIdx.x * blockDim.x + threadIdx.x;
    int lane = gid & 63;
    int rest = gid >> 6;                 // Cb * KC + c
    int KC = K >> 4;
    int Cb = rest / KC;
    int c = rest - Cb * KC;
    if (Cb >= Cblocks) return;
    int n = Cb * 32 + (lane & 31);
    int kbase = c * 16 + (lane >> 5) * 8;
    float vv[8];
    #pragma unroll
    for (int j = 0; j < 8; j++)
        vv[j] = (n < Nb) ? B[(size_t)(kbase + j) * Nb + n] : 0.f;
    unsigned hp[4], lp[4];
    #pragma unroll
    for (int j = 0; j < 4; j++) {
        u16 h0 = bf16_rne(vv[2 * j]);
        u16 h1 = bf16_rne(vv[2 * j + 1]);
        float r0 = vv[2 * j]     - __uint_as_float((unsigned)h0 << 16);
        float r1 = vv[2 * j + 1] - __uint_as_float((unsigned)h1 << 16);
        u16 l0 = bf16_rne(r0);
        u16 l1 = bf16_rne(r1);
        hp[j] = (unsigned)h0 | ((unsigned)h1 << 16);
        lp[j] = (unsigned)l0 | ((unsigned)l1 << 16);
    }
    size_t dst = ((size_t)rest * 64 + lane) * 8;
    *reinterpret_cast<int4*>(hi + dst) = make_int4(hp[0], hp[1], hp[2], hp[3]);
    *reinterpret_cast<int4*>(lo + dst) = make_int4(lp[0], lp[1], lp[2], lp[3]);
}

// ---------------- fused MFMA GEMM ----------------
// C cols map: [0,xwCols) -> xwb bf16 ; [skipBeg,skipEnd) -> skipP fp32 ;
// [attBeg,attBeg+H) -> asrc ; [attBeg+H,attBeg+2H) -> adst ; else discard.

__global__ __launch_bounds__(256) void gemm_fused(const u16* __restrict__ Ahi,
                                                  const u16* __restrict__ Alo,
                                                  const u16* __restrict__ Bhi,
                                                  const u16* __restrict__ Blo,
                                                  u16* __restrict__ xwb, int xwCols,
                                                  float* __restrict__ skipP,
                                                  int skipBeg, int skipEnd,
                                                  float* __restrict__ asrc,
                                                  float* __restrict__ adst,
                                                  int attBeg, int H,
                                                  int M, int K,
                                                  int ntiles, int Rblocks) {
    int nwg = gridDim.x, b = blockIdx.x;
    int q = nwg >> 3, r = nwg & 7;
    int xcd = b & 7, idx = b >> 3;
    int t = (xcd < r) ? (xcd * (q + 1) + idx)
                      : (r * (q + 1) + (xcd - r) * q + idx);
    int bm = (t / ntiles) * 128;
    int bn = (t - (t / ntiles) * ntiles) * 64;

    int lane = threadIdx.x & 63, w = threadIdx.x >> 6;
    int wr = w >> 1, wc = w & 1;
    int l31 = lane & 31, lg = lane >> 5;
    int KC = K >> 4;

    int R0 = (bm + wr * 64) >> 5;
    int R1 = R0 + 1;
    if (R0 >= Rblocks) R0 = Rblocks - 1;
    if (R1 >= Rblocks) R1 = Rblocks - 1;
    int Cb = (bn + wc * 32) >> 5;

    const u16* pa0h = Ahi + (((size_t)R0 * KC) * 64 + lane) * 8;
    const u16* pa0l = Alo + (((size_t)R0 * KC) * 64 + lane) * 8;
    const u16* pa1h = Ahi + (((size_t)R1 * KC) * 64 + lane) * 8;
    const u16* pa1l = Alo + (((size_t)R1 * KC) * 64 + lane) * 8;
    const u16* pbh  = Bhi + (((size_t)Cb * KC) * 64 + lane) * 8;
    const u16* pbl  = Blo + (((size_t)Cb * KC) * 64 + lane) * 8;

    f32x16 acc0, acc1;
    #pragma unroll
    for (int i2 = 0; i2 < 16; i2++) { acc0[i2] = 0.f; acc1[i2] = 0.f; }

    bf16x8 a0h = ldb8(pa0h), a0l = ldb8(pa0l);
    bf16x8 a1h = ldb8(pa1h), a1l = ldb8(pa1l);
    bf16x8 bh  = ldb8(pbh),  bl  = ldb8(pbl);

    for (int c = 1; c <= KC; c++) {
        size_t off = (size_t)c * 512;
        bf16x8 na0h = ldb8(pa0h + off), na0l = ldb8(pa0l + off);
        bf16x8 na1h = ldb8(pa1h + off), na1l = ldb8(pa1l + off);
        bf16x8 nbh  = ldb8(pbh + off),  nbl  = ldb8(pbl + off);
        acc0 = __builtin_amdgcn_mfma_f32_32x32x16_bf16(a0h, bh, acc0, 0, 0, 0);
        acc1 = __builtin_amdgcn_mfma_f32_32x32x16_bf16(a1h, bh, acc1, 0, 0, 0);
        acc0 = __builtin_amdgcn_mfma_f32_32x32x16_bf16(a0h, bl, acc0, 0, 0, 0);
        acc1 = __builtin_amdgcn_mfma_f32_32x32x16_bf16(a1h, bl, acc1, 0, 0, 0);
        acc0 = __builtin_amdgcn_mfma_f32_32x32x16_bf16(a0l, bh, acc0, 0, 0, 0);
        acc1 = __builtin_amdgcn_mfma_f32_32x32x16_bf16(a1l, bh, acc1, 0, 0, 0);
        a0h = na0h; a0l = na0l; a1h = na1h; a1l = na1l; bh = nbh; bl = nbl;
    }

    int n = bn + wc * 32 + l31;
    int base_m = bm + wr * 64;
    #pragma unroll
    for (int rg = 0; rg < 16; rg++) {
        int mrow = (rg & 3) + 8 * (rg >> 2) + 4 * lg;
        int m0 = base_m + mrow;
        int m1 = m0 + 32;
        float v0 = acc0[rg], v1 = acc1[rg];
        if (n < xwCols) {
            if (m0 < M) xwb[(size_t)m0 * xwCols + n] = bf16_rne(v0);
            if (m1 < M) xwb[(size_t)m1 * xwCols + n] = bf16_rne(v1);
        } else if (n >= skipBeg && n < skipEnd) {
            int cc = n - skipBeg, st = skipEnd - skipBeg;
            if (m0 < M) skipP[(size_t)m0 * st + cc] = v0;
            if (m1 < M) skipP[(size_t)m1 * st + cc] = v1;
        } else if (n >= attBeg && n < attBeg + H) {
            int h = n - attBeg;
            if (m0 < M) asrc[(size_t)m0 * H + h] = v0;
            if (m1 < M) asrc[(size_t)m1 * H + h] = v1;
        } else if (n >= attBeg + H && n < attBeg + 2 * H) {
            int h = n - attBeg - H;
            if (m0 < M) adst[(size_t)m0 * H + h] = v0;
            if (m1 < M) adst[(size_t)m1 * H + h] = v1;
        }
    }
}

// ---------------- phase 1: fused all-heads single-pass edge softmax -------

template <int H, int CHUNKS>
__global__ __launch_bounds__(256) void edge_alpha_fused(const float* __restrict__ asrc,
                                                        const float* __restrict__ adst,
                                                        const int* __restrict__ row_off,
                                                        const int* __restrict__ col,
                                                        float* __restrict__ alpha,
                                                        int N) {
    int w = (blockIdx.x * blockDim.x + threadIdx.x) >> 6;  // node
    int lane = threadIdx.x & 63;
    if (w >= N) return;
    int jb = row_off[w], je = row_off[w + 1];

    float adn[H];
    #pragma unroll
    for (int h = 0; h < H; h++) adn[h] = adst[(size_t)w * H + h];

    float ev[CHUNKS][H];
    float m[H];
    #pragma unroll
    for (int h = 0; h < H; h++) m[h] = -INFINITY;

    #pragma unroll
    for (int c = 0; c < CHUNKS; c++) {
        int j = jb + c * 64 + lane;
        if (j < je) {
            int s = col[j];
            const float* ap = &asrc[(size_t)s * H];
            #pragma unroll
            for (int h = 0; h < H; h++) {
                float e = ap[h] + adn[h];
                e = e > 0.f ? e : 0.2f * e;
                ev[c][h] = e;
                m[h] = fmaxf(m[h], e);
            }
        } else {
            #pragma unroll
            for (int h = 0; h < H; h++) ev[c][h] = -INFINITY;
        }
    }
    for (int j = jb + CHUNKS * 64 + lane; j < je; j += 64) {
        int s = col[j];
        const float* ap = &asrc[(size_t)s * H];
        #pragma unroll
        for (int h = 0; h < H; h++) {
            float e = ap[h] + adn[h];
            e = e > 0.f ? e : 0.2f * e;
            m[h] = fmaxf(m[h], e);
        }
    }

    #pragma unroll
    for (int off = 32; off; off >>= 1)
        #pragma unroll
        for (int h = 0; h < H; h++) m[h] = fmaxf(m[h], __shfl_xor(m[h], off));

    float ssum[H];
    #pragma unroll
    for (int h = 0; h < H; h++) ssum[h] = 0.f;
    #pragma unroll
    for (int c = 0; c < CHUNKS; c++)
        #pragma unroll
        for (int h = 0; h < H; h++) ssum[h] += __expf(ev[c][h] - m[h]);
    for (int j = jb + CHUNKS * 64 + lane; j < je; j += 64) {
        int s = col[j];
        const float* ap = &asrc[(size_t)s * H];
        #pragma unroll
        for (int h = 0; h < H; h++) {
            float e = ap[h] + adn[h];
            e = e > 0.f ? e : 0.2f * e;
            ssum[h] += __expf(e - m[h]);
        }
    }
    #pragma unroll
    for (int off = 32; off; off >>= 1)
        #pragma unroll
        for (int h = 0; h < H; h++) ssum[h] += __shfl_xor(ssum[h], off);

    float inv[H];
    #pragma unroll
    for (int h = 0; h < H; h++) inv[h] = 1.f / (ssum[h] + 1e-16f);

    #pragma unroll
    for (int c = 0; c < CHUNKS; c++) {
        int j = jb + c * 64 + lane;
        if (j < je) {
            float* op = &alpha[(size_t)j * H];
            #pragma unroll
            for (int h = 0; h < H; h++)
                op[h] = __expf(ev[c][h] - m[h]) * inv[h];
        }
    }
    for (int j = jb + CHUNKS * 64 + lane; j < je; j += 64) {
        int s = col[j];
        const float* ap = &asrc[(size_t)s * H];
        float* op = &alpha[(size_t)j * H];
        #pragma unroll
        for (int h = 0; h < H; h++) {
            float e = ap[h] + adn[h];
            e = e > 0.f ? e : 0.2f * e;
            op[h] = __expf(e - m[h]) * inv[h];
        }
    }
}

// ---------------- phase 2: aggregation, wave per node, H=4, C=128 --------
// SKIPPK: 0 = skip from fp32 array, 1 = skip from packed hi/lo (x = hi+lo).
// Output: elu(acc+bias+skip) written as packed hi/lo A-fragments (K=512).

template <int SKIPPK>
__global__ __launch_bounds__(256) void agg_fused512(const u16* __restrict__ xw,
                                                    const float* __restrict__ alpha,
                                                    const int* __restrict__ row_off,
                                                    const int* __restrict__ col,
                                                    const float* __restrict__ bias,
                                                    const float* __restrict__ skipF,
                                                    const u16* __restrict__ skipHi,
                                                    const u16* __restrict__ skipLo,
                                                    u16* __restrict__ outHi,
                                                    u16* __restrict__ outLo,
                                                    int N) {
    int w = (blockIdx.x * blockDim.x + threadIdx.x) >> 6;  // node
    int lane = threadIdx.x & 63;
    if (w >= N) return;
    int base = lane * 8;
    int hme = lane >> 4;

    float acc[8] = {};
    int jb = row_off[w], je = row_off[w + 1];

    int j = jb;
    for (; j + 3 < je; j += 4) {
        int s0 = col[j], s1 = col[j + 1], s2 = col[j + 2], s3 = col[j + 3];
        float a0 = alpha[(size_t)(j + 0) * 4 + hme];
        float a1 = alpha[(size_t)(j + 1) * 4 + hme];
        float a2 = alpha[(size_t)(j + 2) * 4 + hme];
        float a3 = alpha[(size_t)(j + 3) * 4 + hme];
        uint4 r0 = *reinterpret_cast<const uint4*>(&xw[(size_t)s0 * 512 + base]);
        uint4 r1 = *reinterpret_cast<const uint4*>(&xw[(size_t)s1 * 512 + base]);
        uint4 r2 = *reinterpret_cast<const uint4*>(&xw[(size_t)s2 * 512 + base]);
        uint4 r3 = *reinterpret_cast<const uint4*>(&xw[(size_t)s3 * 512 + base]);
        acc[0] = fmaf(a0, __uint_as_float(r0.x << 16), acc[0]);
        acc[1] = fmaf(a0, __uint_as_float(r0.x & 0xffff0000u), acc[1]);
        acc[2] = fmaf(a0, __uint_as_float(r0.y << 16), acc[2]);
        acc[3] = fmaf(a0, __uint_as_float(r0.y & 0xffff0000u), acc[3]);
        acc[4] = fmaf(a0, __uint_as_float(r0.z << 16), acc[4]);
        acc[5] = fmaf(a0, __uint_as_float(r0.z & 0xffff0000u), acc[5]);
        acc[6] = fmaf(a0, __uint_as_float(r0.w << 16), acc[6]);
        acc[7] = fmaf(a0, __uint_as_float(r0.w & 0xffff0000u), acc[7]);
        acc[0] = fmaf(a1, __uint_as_float(r1.x << 16), acc[0]);
        acc[1] = fmaf(a1, __uint_as_float(r1.x & 0xffff0000u), acc[1]);
        acc[2] = fmaf(a1, __uint_as_float(r1.y << 16), acc[2]);
        acc[3] = fmaf(a1, __uint_as_float(r1.y & 0xffff0000u), acc[3]);
        acc[4] = fmaf(a1, __uint_as_float(r1.z << 16), acc[4]);
        acc[5] = fmaf(a1, __uint_as_float(r1.z & 0xffff0000u), acc[5]);
        acc[6] = fmaf(a1, __uint_as_float(r1.w << 16), acc[6]);
        acc[7] = fmaf(a1, __uint_as_float(r1.w & 0xffff0000u), acc[7]);
        acc[0] = fmaf(a2, __uint_as_float(r2.x << 16), acc[0]);
        acc[1] = fmaf(a2, __uint_as_float(r2.x & 0xffff0000u), acc[1]);
        acc[2] = fmaf(a2, __uint_as_float(r2.y << 16), acc[2]);
        acc[3] = fmaf(a2, __uint_as_float(r2.y & 0xffff0000u), acc[3]);
        acc[4] = fmaf(a2, __uint_as_float(r2.z << 16), acc[4]);
        acc[5] = fmaf(a2, __uint_as_float(r2.z & 0xffff0000u), acc[5]);
        acc[6] = fmaf(a2, __uint_as_float(r2.w << 16), acc[6]);
        acc[7] = fmaf(a2, __uint_as_float(r2.w & 0xffff0000u), acc[7]);
        acc[0] = fmaf(a3, __uint_as_float(r3.x << 16), acc[0]);
        acc[1] = fmaf(a3, __uint_as_float(r3.x & 0xffff0000u), acc[1]);
        acc[2] = fmaf(a3, __uint_as_float(r3.y << 16), acc[2]);
        acc[3] = fmaf(a3, __uint_as_float(r3.y & 0xffff0000u), acc[3]);
        acc[4] = fmaf(a3, __uint_as_float(r3.z << 16), acc[4]);
        acc[5] = fmaf(a3, __uint_as_float(r3.z & 0xffff0000u), acc[5]);
        acc[6] = fmaf(a3, __uint_as_float(r3.w << 16), acc[6]);
        acc[7] = fmaf(a3, __uint_as_float(r3.w & 0xffff0000u), acc[7]);
    }
    for (; j < je; ++j) {
        int s = col[j];
        float a = alpha[(size_t)j * 4 + hme];
        uint4 raw = *reinterpret_cast<const uint4*>(&xw[(size_t)s * 512 + base]);
        acc[0] = fmaf(a, __uint_as_float(raw.x << 16), acc[0]);
        acc[1] = fmaf(a, __uint_as_float(raw.x & 0xffff0000u), acc[1]);
        acc[2] = fmaf(a, __uint_as_float(raw.y << 16), acc[2]);
        acc[3] = fmaf(a, __uint_as_float(raw.y & 0xffff0000u), acc[3]);
        acc[4] = fmaf(a, __uint_as_float(raw.z << 16), acc[4]);
        acc[5] = fmaf(a, __uint_as_float(raw.z & 0xffff0000u), acc[5]);
        acc[6] = fmaf(a, __uint_as_float(raw.w << 16), acc[6]);
        acc[7] = fmaf(a, __uint_as_float(raw.w & 0xffff0000u), acc[7]);
    }

    // pack-slot address for node w, channels [base, base+8), K=512 (KC=32)
    int R = w >> 5, r31 = w & 31, cc = lane >> 1, sub = lane & 1;
    int lp = r31 | (sub << 5);
    size_t slot = (((size_t)R * 32 + cc) * 64 + lp) * 8;

    float sk[8];
    if (SKIPPK) {
        int4 h4 = *reinterpret_cast<const int4*>(skipHi + slot);
        int4 l4 = *reinterpret_cast<const int4*>(skipLo + slot);
        unsigned hu[4] = {(unsigned)h4.x, (unsigned)h4.y, (unsigned)h4.z, (unsigned)h4.w};
        unsigned lu[4] = {(unsigned)l4.x, (unsigned)l4.y, (unsigned)l4.z, (unsigned)l4.w};
        #pragma unroll
        for (int i = 0; i < 4; i++) {
            sk[2 * i]     = __uint_as_float(hu[i] << 16) + __uint_as_float(lu[i] << 16);
            sk[2 * i + 1] = __uint_as_float(hu[i] & 0xffff0000u)
                          + __uint_as_float(lu[i] & 0xffff0000u);
        }
    } else {
        const float* kp = &skipF[(size_t)w * 512 + base];
        float4 s0 = *reinterpret_cast<const float4*>(kp);
        float4 s1 = *reinterpret_cast<const float4*>(kp + 4);
        sk[0] = s0.x; sk[1] = s0.y; sk[2] = s0.z; sk[3] = s0.w;
        sk[4] = s1.x; sk[5] = s1.y; sk[6] = s1.z; sk[7] = s1.w;
    }

    const float* bp = &bias[base];
    float r[8];
    #pragma unroll
    for (int i = 0; i < 8; i++) {
        float v = acc[i] + bp[i] + sk[i];
        r[i] = v > 0.f ? v : expm1f(v);          // elu
    }

    unsigned hp[4], lpk[4];
    #pragma unroll
    for (int i = 0; i < 4; i++) {
        u16 h0 = bf16_rne(r[2 * i]);
        u16 h1 = bf16_rne(r[2 * i + 1]);
        float q0 = r[2 * i]     - __uint_as_float((unsigned)h0 << 16);
        float q1 = r[2 * i + 1] - __uint_as_float((unsigned)h1 << 16);
        u16 l0 = bf16_rne(q0);
        u16 l1 = bf16_rne(q1);
        hp[i]  = (unsigned)h0 | ((unsigned)h1 << 16);
        lpk[i] = (unsigned)l0 | ((unsigned)l1 << 16);
    }
    *reinterpret_cast<int4*>(outHi + slot) = make_int4(hp[0], hp[1], hp[2], hp[3]);
    *reinterpret_cast<int4*>(outLo + slot) = make_int4(lpk[0], lpk[1], lpk[2], lpk[3]);
}

// ---------------- phase 2 (layer 2): H=6, C=40, head-mean + skip ---------

__global__ __launch_bounds__(256) void agg_final240(const u16* __restrict__ xw,
                                                    const float* __restrict__ alpha,
                                                    const int* __restrict__ row_off,
                                                    const int* __restrict__ col,
                                                    const float* __restrict__ b2,
                                                    const float* __restrict__ skip,
                                                    float* __restrict__ out,
                                                    int N) {
    int w = (blockIdx.x * blockDim.x + threadIdx.x) >> 6;  // node
    int lane = threadIdx.x & 63;
    if (w >= N) return;
    bool active = lane < 40;

    float acc[6] = {};
    int jb = row_off[w], je = row_off[w + 1];

    int j = jb;
    for (; j + 1 < je; j += 2) {
        int s0 = col[j], s1 = col[j + 1];
        const float* ap0 = &alpha[(size_t)j * 6];
        const float* ap1 = &alpha[(size_t)(j + 1) * 6];
        if (active) {
            const u16* sp0 = &xw[(size_t)s0 * 240 + lane];
            const u16* sp1 = &xw[(size_t)s1 * 240 + lane];
            #pragma unroll
            for (int h = 0; h < 6; h++) {
                acc[h] = fmaf(ap0[h], bf16_to_f32(sp0[h * 40]), acc[h]);
                acc[h] = fmaf(ap1[h], bf16_to_f32(sp1[h * 40]), acc[h]);
            }
        }
    }
    for (; j < je; ++j) {
        int s = col[j];
        const float* ap = &alpha[(size_t)j * 6];
        if (active) {
            const u16* sp = &xw[(size_t)s * 240 + lane];
            #pragma unroll
            for (int h = 0; h < 6; h++)
                acc[h] = fmaf(ap[h], bf16_to_f32(sp[h * 40]), acc[h]);
        }
    }
    if (active) {
        float v = (acc[0] + acc[1] + acc[2] + acc[3] + acc[4] + acc[5]) * (1.f / 6.f)
                  + b2[lane] + skip[(size_t)w * 40 + lane];
        out[(size_t)w * 40 + lane] = v;
    }
}

// ---------------- orchestration ----------------

extern "C" void kernel_launch(void* const* d_in, const int* in_sizes, int n_in,
                              void* d_out, int out_size, void* d_ws, size_t ws_size,
                              hipStream_t stream) {
    const float* x        = (const float*)d_in[0];
    const int*   ei       = (const int*)  d_in[1];
    const float* W0       = (const float*)d_in[2];
    const float* a_src0   = (const float*)d_in[3];
    const float* a_dst0   = (const float*)d_in[4];
    const float* b0       = (const float*)d_in[5];
    const float* Wskip_in = (const float*)d_in[6];
    const float* W1       = (const float*)d_in[7];
    const float* a_src1   = (const float*)d_in[8];
    const float* a_dst1   = (const float*)d_in[9];
    const float* b1       = (const float*)d_in[10];
    const float* W2       = (const float*)d_in[11];
    const float* a_src2   = (const float*)d_in[12];
    const float* a_dst2   = (const float*)d_in[13];
    const float* b2       = (const float*)d_in[14];
    const float* Wskip_out= (const float*)d_in[15];

    const int N = in_sizes[0] / N_FEAT;     // 10000
    const int E = in_sizes[1] / 2;          // 160000
    float* out = (float*)d_out;

    const int Rblocks = (N + 31) / 32;      // 313
    const int mtiles = (N + 127) / 128;     // 79

    // ---------- workspace layout (ws_size = 256 MiB, ~110 MB used) ----------
    float* ws = (float*)d_ws;
    size_t o = 0;
    u16* xwb   = (u16*)(ws + o); o += (size_t)N * 256;   // N*512 bf16
    float* tmpD  = ws + o; o += (size_t)N * HID;         // L0 skip_in (fp32)
    float* asrc  = ws + o; o += (size_t)N * 8;
    float* adst  = ws + o; o += (size_t)N * 8;
    float* skipo = ws + o; o += (size_t)N * 40;
    float* alpha = ws + o; o += (size_t)(E + N) * 6;
    float* ac    = ws + o; o += (size_t)512 * 12;        // combined att cols

    u16* up = (u16*)(ws + o);
    size_t uo = 0;
    const size_t aPack = (size_t)Rblocks * 32 * 512 + 512;   // K=512 pack + guard
    u16* AhA = up + uo; uo += aPack;   u16* AlA = up + uo; uo += aPack;
    u16* AhB = up + uo; uo += aPack;   u16* AlB = up + uo; uo += aPack;
    const size_t b0sz = (size_t)34 * 16 * 512 + 512;   // L0: 34 blocks, KC=16
    u16* B0h = up + uo; uo += b0sz;  u16* B0l = up + uo; uo += b0sz;
    const size_t b1sz = (size_t)18 * 32 * 512 + 512;   // L1: 18 blocks, KC=32
    u16* B1h = up + uo; uo += b1sz;  u16* B1l = up + uo; uo += b1sz;
    const size_t b2sz = (size_t)12 * 32 * 512 + 512;   // L2: 12 blocks, KC=32
    u16* B2h = up + uo; uo += b2sz;  u16* B2l = up + uo; uo += b2sz;
    int* row_off = (int*)(up + uo);
    int* cursor  = row_off + (N + 1);
    int* col     = cursor + (N + 1);

    // ---- CSR by destination (includes self loops) ----
    init_counts<<<(N + 255) / 256, 256, 0, stream>>>(cursor, N);
    count_edges<<<(E + 255) / 256, 256, 0, stream>>>(ei, E, cursor);
    scan_offsets<<<1, 1024, 0, stream>>>(cursor, row_off, N);
    fill_csr<<<(E + N + 255) / 256, 256, 0, stream>>>(ei, E, N, cursor, col);

    // ---- B packs: weights + combined attention columns ----
    // L0 (K=256, KC=16): blocks 0-15 W0 | 16-31 Wskip_in | 32 ac0 | 33 zero
    cvtB_pack<<<(16 * 16 * 64 + 255) / 256, 256, 0, stream>>>(W0, B0h, B0l, 256, 512, 16);
    cvtB_pack<<<(16 * 16 * 64 + 255) / 256, 256, 0, stream>>>(
        Wskip_in, B0h + (size_t)16 * 16 * 512, B0l + (size_t)16 * 16 * 512, 256, 512, 16);
    att_combine<<<(256 * 8 + 255) / 256, 256, 0, stream>>>(W0, a_src0, a_dst0, ac, 256, 4, 128);
    cvtB_pack<<<(2 * 16 * 64 + 255) / 256, 256, 0, stream>>>(
        ac, B0h + (size_t)32 * 16 * 512, B0l + (size_t)32 * 16 * 512, 256, 8, 2);
    // L1 (K=512, KC=32): blocks 0-15 W1 | 16 ac1 | 17 zero
    cvtB_pack<<<(16 * 32 * 64 + 255) / 256, 256, 0, stream>>>(W1, B1h, B1l, 512, 512, 16);
    att_combine<<<(512 * 8 + 255) / 256, 256, 0, stream>>>(W1, a_src1, a_dst1, ac, 512, 4, 128);
    cvtB_pack<<<(2 * 32 * 64 + 255) / 256, 256, 0, stream>>>(
        ac, B1h + (size_t)16 * 32 * 512, B1l + (size_t)16 * 32 * 512, 512, 8, 2);
    // L2 (K=512, KC=32): blocks 0-7 W2(240) | 8-9 Wskip_out(40) | 10 ac2 | 11 zero
    cvtB_pack<<<(8 * 32 * 64 + 255) / 256, 256, 0, stream>>>(W2, B2h, B2l, 512, 240, 8);
    cvtB_pack<<<(2 * 32 * 64 + 255) / 256, 256, 0, stream>>>(
        Wskip_out, B2h + (size_t)8 * 32 * 512, B2l + (size_t)8 * 32 * 512, 512, 40, 2);
    att_combine<<<(512 * 12 + 255) / 256, 256, 0, stream>>>(W2, a_src2, a_dst2, ac, 512, 6, 40);
    cvtB_pack<<<(2 * 32 * 64 + 255) / 256, 256, 0, stream>>>(
        ac, B2h + (size_t)10 * 32 * 512, B2l + (size_t)10 * 32 * 512, 512, 12, 2);

    int nodeBlocks = (N * 64 + 255) / 256;
    const int BIG = 1 << 30;

    // ---- Layer 0: x(fp32) -> pack -> fused GEMM (1088 cols) ----
    cvtA_pack<<<(Rblocks * 16 * 64 + 255) / 256, 256, 0, stream>>>(x, AhA, AlA, N, 256, Rblocks);
    gemm_fused<<<mtiles * 17, 256, 0, stream>>>(
        AhA, AlA, B0h, B0l, xwb, 512, tmpD, 512, 1024, asrc, adst, 1024, 4,
        N, 256, 17, Rblocks);
    edge_alpha_fused<4, 4><<<nodeBlocks, 256, 0, stream>>>(asrc, adst, row_off, col, alpha, N);
    agg_fused512<0><<<nodeBlocks, 256, 0, stream>>>(
        xwb, alpha, row_off, col, b0, tmpD, nullptr, nullptr, AhB, AlB, N);  // x1 -> pair B

    // ---- Layer 1: fused GEMM (576 cols), skip = x1 packs ----
    gemm_fused<<<mtiles * 9, 256, 0, stream>>>(
        AhB, AlB, B1h, B1l, xwb, 512, nullptr, BIG, BIG, asrc, adst, 512, 4,
        N, 512, 9, Rblocks);
    edge_alpha_fused<4, 4><<<nodeBlocks, 256, 0, stream>>>(asrc, adst, row_off, col, alpha, N);
    agg_fused512<1><<<nodeBlocks, 256, 0, stream>>>(
        xwb, alpha, row_off, col, b1, nullptr, AhB, AlB, AhA, AlA, N);       // x2 -> pair A

    // ---- Layer 2: fused GEMM (384 cols): xwb240 | skipo | att ----
    gemm_fused<<<mtiles * 6, 256, 0, stream>>>(
        AhA, AlA, B2h, B2l, xwb, 240, skipo, 256, 296, asrc, adst, 320, 6,
        N, 512, 6, Rblocks);
    edge_alpha_fused<6, 4><<<nodeBlocks, 256, 0, stream>>>(asrc, adst, row_off, col, alpha, N);
    agg_final240<<<nodeBlocks, 256, 0, stream>>>(
        xwb, alpha, row_off, col, b2, skipo, out, N);
}

// Round 10
// 343.418 us; speedup vs baseline: 2.1085x; 1.2102x over previous
//
#include <hip/hip_runtime.h>
#include <math.h>

// ---------------------------------------------------------------------------
// GAT (3-layer, PyG GATConv semantics) on MI355X.
// Round 10: dispatch collapse 26 -> 13.
//   - agg_sm512 / agg_final240_sm: edge-softmax fused into aggregation
//     (phase A: lane-parallel softmax -> alpha,col in LDS; phase B: gather).
//   - att_combine_all: one launch for all 3 layers' combined attention cols.
//   - pack_all_B: one launch packs all weight/ac B-fragments (hardcoded segs).
// GEMM path (split-bf16 MFMA, fused epilogue) unchanged from round 9.
// ---------------------------------------------------------------------------

#define N_FEAT 256
#define HID 512

using u16 = unsigned short;
using bf16x8 = __attribute__((ext_vector_type(8))) __bf16;
using f32x16 = __attribute__((ext_vector_type(16))) float;

__device__ inline u16 bf16_rne(float f) {
    unsigned u = __float_as_uint(f);
    return (u16)((u + 0x7fffu + ((u >> 16) & 1u)) >> 16);
}
__device__ inline float bf16_to_f32(u16 h) {
    return __uint_as_float((unsigned)h << 16);
}
__device__ inline bf16x8 ldb8(const u16* p) {
    return *reinterpret_cast<const bf16x8*>(p);
}

// ---------------- CSR construction ----------------

__global__ void init_counts(int* cursor, int N) {
    int i = blockIdx.x * blockDim.x + threadIdx.x;
    if (i < N) cursor[i] = 1;  // self loop contributes 1
}

__global__ void count_edges(const int* __restrict__ ei, int E, int* cursor) {
    int e = blockIdx.x * blockDim.x + threadIdx.x;
    if (e < E) atomicAdd(&cursor[ei[E + e]], 1);
}

__global__ __launch_bounds__(1024) void scan_offsets(int* cursor, int* row_off, int N) {
    __shared__ int sdata[1024];
    int tid = threadIdx.x;
    int chunk = (N + 1023) >> 10;
    int base = tid * chunk;
    int lsum = 0;
    for (int i = 0; i < chunk; i++) {
        int idx = base + i;
        if (idx < N) lsum += cursor[idx];
    }
    sdata[tid] = lsum;
    __syncthreads();
    for (int off = 1; off < 1024; off <<= 1) {
        int t = (tid >= off) ? sdata[tid - off] : 0;
        __syncthreads();
        sdata[tid] += t;
        __syncthreads();
    }
    int run = sdata[tid] - lsum;
    if (tid == 0) row_off[0] = 0;
    for (int i = 0; i < chunk; i++) {
        int idx = base + i;
        if (idx < N) {
            int c = cursor[idx];
            cursor[idx] = run;
            run += c;
            row_off[idx + 1] = run;
        }
    }
}

__global__ void fill_csr(const int* __restrict__ ei, int E, int N,
                         int* cursor, int* __restrict__ col) {
    int i = blockIdx.x * blockDim.x + threadIdx.x;
    int tot = E + N;
    if (i >= tot) return;
    int s, d;
    if (i < E) { s = ei[i]; d = ei[E + i]; }
    else       { s = i - E; d = s; }
    int pos = atomicAdd(&cursor[d], 1);
    col[pos] = s;
}

// ---------------- attention col combine (all 3 layers, one launch) -------
// ac[k][h] = sum_c W[k][h*C+c]*att_s[h][c];  ac[k][H+h] = ... att_d

__global__ __launch_bounds__(256) void att_combine_all(
        const float* __restrict__ W0, const float* __restrict__ as0, const float* __restrict__ ad0,
        const float* __restrict__ W1, const float* __restrict__ as1, const float* __restrict__ ad1,
        const float* __restrict__ W2, const float* __restrict__ as2, const float* __restrict__ ad2,
        float* __restrict__ ac0, float* __restrict__ ac1, float* __restrict__ ac2) {
    int i = blockIdx.x * blockDim.x + threadIdx.x;
    const float *W, *as_, *ad_;
    float* ac;
    int K, H, C, li;
    if (i < 2048)       { W = W0; as_ = as0; ad_ = ad0; ac = ac0; K = 256; H = 4; C = 128; li = i; }
    else if (i < 6144)  { W = W1; as_ = as1; ad_ = ad1; ac = ac1; K = 512; H = 4; C = 128; li = i - 2048; }
    else if (i < 12288) { W = W2; as_ = as2; ad_ = ad2; ac = ac2; K = 512; H = 6; C = 40;  li = i - 6144; }
    else return;
    int k = li / (2 * H);
    int hh = li - k * 2 * H;
    int h = (hh >= H) ? hh - H : hh;
    const float* av = ((hh >= H) ? ad_ : as_) + h * C;
    const float* wp = W + (size_t)k * H * C + (size_t)h * C;
    float sum = 0.f;
    for (int c = 0; c < C; c++) sum = fmaf(wp[c], av[c], sum);
    ac[(size_t)k * 2 * H + hh] = sum;
}

// ---------------- split-bf16 packing ----------------
// slot = ((blk*(K/16) + c)*64 + lane)*8 ; lane&31 = row/col in 32-block,
// lane>>5 = k-subgroup (8 consecutive k of the 16-chunk).

__global__ __launch_bounds__(256) void cvtA_pack(const float* __restrict__ X,
                                                 u16* __restrict__ hi, u16* __restrict__ lo,
                                                 int M, int K, int Rblocks) {
    int gid = blockIdx.x * blockDim.x + threadIdx.x;
    int lane = gid & 63;
    int rest = gid >> 6;                 // R * KC + c
    int KC = K >> 4;
    int R = rest / KC;
    int c = rest - R * KC;
    if (R >= Rblocks) return;
    int row = R * 32 + (lane & 31);
    if (row >= M) row = M - 1;           // clamp: clamped rows never stored
    const float* src = X + (size_t)row * K + c * 16 + (lane >> 5) * 8;
    float4 v0 = *reinterpret_cast<const float4*>(src);
    float4 v1 = *reinterpret_cast<const float4*>(src + 4);
    float vv[8] = {v0.x, v0.y, v0.z, v0.w, v1.x, v1.y, v1.z, v1.w};
    unsigned hp[4], lp[4];
    #pragma unroll
    for (int j = 0; j < 4; j++) {
        u16 h0 = bf16_rne(vv[2 * j]);
        u16 h1 = bf16_rne(vv[2 * j + 1]);
        float r0 = vv[2 * j]     - __uint_as_float((unsigned)h0 << 16);
        float r1 = vv[2 * j + 1] - __uint_as_float((unsigned)h1 << 16);
        u16 l0 = bf16_rne(r0);
        u16 l1 = bf16_rne(r1);
        hp[j] = (unsigned)h0 | ((unsigned)h1 << 16);
        lp[j] = (unsigned)l0 | ((unsigned)l1 << 16);
    }
    size_t dst = ((size_t)rest * 64 + lane) * 8;
    *reinterpret_cast<int4*>(hi + dst) = make_int4(hp[0], hp[1], hp[2], hp[3]);
    *reinterpret_cast<int4*>(lo + dst) = make_int4(lp[0], lp[1], lp[2], lp[3]);
}

// B [K][Nb] -> packed B^T fragments; helper shared by pack_all_B segments.
__device__ inline void cvtB_body(const float* __restrict__ B,
                                 u16* __restrict__ hi, u16* __restrict__ lo,
                                 int K, int Nb, int gid) {
    int lane = gid & 63;
    int rest = gid >> 6;                 // Cb * KC + c
    int KC = K >> 4;
    int Cb = rest / KC;
    int c = rest - Cb * KC;
    int n = Cb * 32 + (lane & 31);
    int kbase = c * 16 + (lane >> 5) * 8;
    float vv[8];
    #pragma unroll
    for (int j = 0; j < 8; j++)
        vv[j] = (n < Nb) ? B[(size_t)(kbase + j) * Nb + n] : 0.f;
    unsigned hp[4], lp[4];
    #pragma unroll
    for (int j = 0; j < 4; j++) {
        u16 h0 = bf16_rne(vv[2 * j]);
        u16 h1 = bf16_rne(vv[2 * j + 1]);
        float r0 = vv[2 * j]     - __uint_as_float((unsigned)h0 << 16);
        float r1 = vv[2 * j + 1] - __uint_as_float((unsigned)h1 << 16);
        u16 l0 = bf16_rne(r0);
        u16 l1 = bf16_rne(r1);
        hp[j] = (unsigned)h0 | ((unsigned)h1 << 16);
        lp[j] = (unsigned)l0 | ((unsigned)l1 << 16);
    }
    size_t dst = ((size_t)rest * 64 + lane) * 8;
    *reinterpret_cast<int4*>(hi + dst) = make_int4(hp[0], hp[1], hp[2], hp[3]);
    *reinterpret_cast<int4*>(lo + dst) = make_int4(lp[0], lp[1], lp[2], lp[3]);
}

// All B packs in ONE launch. Segment geometry hardcoded (problem constants).
// L0 B (KC=16): blk 0-15 W0 | 16-31 Wskip_in | 32 ac0 | 33 zero
// L1 B (KC=32): blk 0-15 W1 | 16 ac1 | 17 zero
// L2 B (KC=32): blk 0-7 W2 | 8-9 Wskip_out | 10 ac2 | 11 zero
__global__ __launch_bounds__(256) void pack_all_B(
        const float* __restrict__ W0, const float* __restrict__ Wsi, const float* __restrict__ ac0,
        const float* __restrict__ W1, const float* __restrict__ ac1,
        const float* __restrict__ W2, const float* __restrict__ Wso, const float* __restrict__ ac2,
        u16* __restrict__ B0h, u16* __restrict__ B0l,
        u16* __restrict__ B1h, u16* __restrict__ B1l,
        u16* __restrict__ B2h, u16* __restrict__ B2l) {
    int g = blockIdx.x * blockDim.x + threadIdx.x;
    if (g < 16384)      cvtB_body(W0,  B0h, B0l, 256, 512, g);
    else if (g < 32768) cvtB_body(Wsi, B0h + (size_t)16 * 16 * 512, B0l + (size_t)16 * 16 * 512, 256, 512, g - 16384);
    else if (g < 34816) cvtB_body(ac0, B0h + (size_t)32 * 16 * 512, B0l + (size_t)32 * 16 * 512, 256, 8,   g - 32768);
    else if (g < 67584) cvtB_body(W1,  B1h, B1l, 512, 512, g - 34816);
    else if (g < 71680) cvtB_body(ac1, B1h + (size_t)16 * 32 * 512, B1l + (size_t)16 * 32 * 512, 512, 8,   g - 67584);
    else if (g < 88064) cvtB_body(W2,  B2h, B2l, 512, 240, g - 71680);
    else if (g < 92160) cvtB_body(Wso, B2h + (size_t)8 * 32 * 512,  B2l + (size_t)8 * 32 * 512,  512, 40,  g - 88064);
    else if (g < 96256) cvtB_body(ac2, B2h + (size_t)10 * 32 * 512, B2l + (size_t)10 * 32 * 512, 512, 12,  g - 92160);
}

// ---------------- fused MFMA GEMM (round 9, validated) ----------------
// C cols: [0,xwCols)->xwb bf16 ; [skipBeg,skipEnd)->skipP fp32 ;
// [attBeg,attBeg+H)->asrc ; [attBeg+H,attBeg+2H)->adst ; else discard.

__global__ __launch_bounds__(256) void gemm_fused(const u16* __restrict__ Ahi,
                                                  const u16* __restrict__ Alo,
                                                  const u16* __restrict__ Bhi,
                                                  const u16* __restrict__ Blo,
                                                  u16* __restrict__ xwb, int xwCols,
                                                  float* __restrict__ skipP,
                                                  int skipBeg, int skipEnd,
                                                  float* __restrict__ asrc,
                                                  float* __restrict__ adst,
                                                  int attBeg, int H,
                                                  int M, int K,
                                                  int ntiles, int Rblocks) {
    int nwg = gridDim.x, b = blockIdx.x;
    int q = nwg >> 3, r = nwg & 7;
    int xcd = b & 7, idx = b >> 3;
    int t = (xcd < r) ? (xcd * (q + 1) + idx)
                      : (r * (q + 1) + (xcd - r) * q + idx);
    int bm = (t / ntiles) * 128;
    int bn = (t - (t / ntiles) * ntiles) * 64;

    int lane = threadIdx.x & 63, w = threadIdx.x >> 6;
    int wr = w >> 1, wc = w & 1;
    int l31 = lane & 31, lg = lane >> 5;
    int KC = K >> 4;

    int R0 = (bm + wr * 64) >> 5;
    int R1 = R0 + 1;
    if (R0 >= Rblocks) R0 = Rblocks - 1;
    if (R1 >= Rblocks) R1 = Rblocks - 1;
    int Cb = (bn + wc * 32) >> 5;

    const u16* pa0h = Ahi + (((size_t)R0 * KC) * 64 + lane) * 8;
    const u16* pa0l = Alo + (((size_t)R0 * KC) * 64 + lane) * 8;
    const u16* pa1h = Ahi + (((size_t)R1 * KC) * 64 + lane) * 8;
    const u16* pa1l = Alo + (((size_t)R1 * KC) * 64 + lane) * 8;
    const u16* pbh  = Bhi + (((size_t)Cb * KC) * 64 + lane) * 8;
    const u16* pbl  = Blo + (((size_t)Cb * KC) * 64 + lane) * 8;

    f32x16 acc0, acc1;
    #pragma unroll
    for (int i2 = 0; i2 < 16; i2++) { acc0[i2] = 0.f; acc1[i2] = 0.f; }

    bf16x8 a0h = ldb8(pa0h), a0l = ldb8(pa0l);
    bf16x8 a1h = ldb8(pa1h), a1l = ldb8(pa1l);
    bf16x8 bh  = ldb8(pbh),  bl  = ldb8(pbl);

    for (int c = 1; c <= KC; c++) {
        size_t off = (size_t)c * 512;
        bf16x8 na0h = ldb8(pa0h + off), na0l = ldb8(pa0l + off);
        bf16x8 na1h = ldb8(pa1h + off), na1l = ldb8(pa1l + off);
        bf16x8 nbh  = ldb8(pbh + off),  nbl  = ldb8(pbl + off);
        acc0 = __builtin_amdgcn_mfma_f32_32x32x16_bf16(a0h, bh, acc0, 0, 0, 0);
        acc1 = __builtin_amdgcn_mfma_f32_32x32x16_bf16(a1h, bh, acc1, 0, 0, 0);
        acc0 = __builtin_amdgcn_mfma_f32_32x32x16_bf16(a0h, bl, acc0, 0, 0, 0);
        acc1 = __builtin_amdgcn_mfma_f32_32x32x16_bf16(a1h, bl, acc1, 0, 0, 0);
        acc0 = __builtin_amdgcn_mfma_f32_32x32x16_bf16(a0l, bh, acc0, 0, 0, 0);
        acc1 = __builtin_amdgcn_mfma_f32_32x32x16_bf16(a1l, bh, acc1, 0, 0, 0);
        a0h = na0h; a0l = na0l; a1h = na1h; a1l = na1l; bh = nbh; bl = nbl;
    }

    int n = bn + wc * 32 + l31;
    int base_m = bm + wr * 64;
    #pragma unroll
    for (int rg = 0; rg < 16; rg++) {
        int mrow = (rg & 3) + 8 * (rg >> 2) + 4 * lg;
        int m0 = base_m + mrow;
        int m1 = m0 + 32;
        float v0 = acc0[rg], v1 = acc1[rg];
        if (n < xwCols) {
            if (m0 < M) xwb[(size_t)m0 * xwCols + n] = bf16_rne(v0);
            if (m1 < M) xwb[(size_t)m1 * xwCols + n] = bf16_rne(v1);
        } else if (n >= skipBeg && n < skipEnd) {
            int cc = n - skipBeg, st = skipEnd - skipBeg;
            if (m0 < M) skipP[(size_t)m0 * st + cc] = v0;
            if (m1 < M) skipP[(size_t)m1 * st + cc] = v1;
        } else if (n >= attBeg && n < attBeg + H) {
            int h = n - attBeg;
            if (m0 < M) asrc[(size_t)m0 * H + h] = v0;
            if (m1 < M) asrc[(size_t)m1 * H + h] = v1;
        } else if (n >= attBeg + H && n < attBeg + 2 * H) {
            int h = n - attBeg - H;
            if (m0 < M) adst[(size_t)m0 * H + h] = v0;
            if (m1 < M) adst[(size_t)m1 * H + h] = v1;
        }
    }
}

// ---------------- fused softmax + aggregation, H=4, C=128 ----------------
// Phase A: lane-parallel softmax over incoming edges (alpha,col -> LDS).
// Phase B: serial gather with 4-edge unroll; epilogue elu(+bias+skip) and
// write as packed hi/lo A-fragments (K=512) for the next layer's GEMM.
// SKIPPK: 0 = skip from fp32 array, 1 = skip from packed hi/lo.

template <int SKIPPK>
__global__ __launch_bounds__(256) void agg_sm512(const u16* __restrict__ xw,
                                                 const float* __restrict__ asrc,
                                                 const float* __restrict__ adst,
                                                 const int* __restrict__ row_off,
                                                 const int* __restrict__ col,
                                                 const float* __restrict__ bias,
                                                 const float* __restrict__ skipF,
                                                 const u16* __restrict__ skipHi,
                                                 const u16* __restrict__ skipLo,
                                                 u16* __restrict__ outHi,
                                                 u16* __restrict__ outLo,
                                                 int N) {
    __shared__ float lalpha[4][256 * 4];
    __shared__ int   lcol[4][256];
    int w = (blockIdx.x * blockDim.x + threadIdx.x) >> 6;   // node
    int lane = threadIdx.x & 63;
    int wid = (threadIdx.x >> 6) & 3;
    bool valid = w < N;
    int jb = 0, je = 0;
    float adn[4], m[4], inv[4];

    if (valid) {
        jb = row_off[w]; je = row_off[w + 1];
        float4 ad4 = *reinterpret_cast<const float4*>(&adst[(size_t)w * 4]);
        adn[0] = ad4.x; adn[1] = ad4.y; adn[2] = ad4.z; adn[3] = ad4.w;

        float ev[4][4];
        int scol[4];
        #pragma unroll
        for (int h = 0; h < 4; h++) m[h] = -INFINITY;

        #pragma unroll
        for (int c = 0; c < 4; c++) {
            int j = jb + c * 64 + lane;
            if (j < je) {
                int s = col[j]; scol[c] = s;
                float4 as4 = *reinterpret_cast<const float4*>(&asrc[(size_t)s * 4]);
                float e0 = as4.x + adn[0]; e0 = e0 > 0.f ? e0 : 0.2f * e0;
                float e1 = as4.y + adn[1]; e1 = e1 > 0.f ? e1 : 0.2f * e1;
                float e2 = as4.z + adn[2]; e2 = e2 > 0.f ? e2 : 0.2f * e2;
                float e3 = as4.w + adn[3]; e3 = e3 > 0.f ? e3 : 0.2f * e3;
                ev[c][0] = e0; ev[c][1] = e1; ev[c][2] = e2; ev[c][3] = e3;
                m[0] = fmaxf(m[0], e0); m[1] = fmaxf(m[1], e1);
                m[2] = fmaxf(m[2], e2); m[3] = fmaxf(m[3], e3);
            } else {
                scol[c] = -1;
                #pragma unroll
                for (int h = 0; h < 4; h++) ev[c][h] = -INFINITY;
            }
        }
        for (int j = jb + 256 + lane; j < je; j += 64) {   // deg>256 fallback
            int s = col[j];
            #pragma unroll
            for (int h = 0; h < 4; h++) {
                float e = asrc[(size_t)s * 4 + h] + adn[h];
                e = e > 0.f ? e : 0.2f * e;
                m[h] = fmaxf(m[h], e);
            }
        }
        #pragma unroll
        for (int off = 32; off; off >>= 1)
            #pragma unroll
            for (int h = 0; h < 4; h++) m[h] = fmaxf(m[h], __shfl_xor(m[h], off));

        float ssum[4] = {0.f, 0.f, 0.f, 0.f};
        #pragma unroll
        for (int c = 0; c < 4; c++)
            #pragma unroll
            for (int h = 0; h < 4; h++) ssum[h] += __expf(ev[c][h] - m[h]);
        for (int j = jb + 256 + lane; j < je; j += 64) {
            int s = col[j];
            #pragma unroll
            for (int h = 0; h < 4; h++) {
                float e = asrc[(size_t)s * 4 + h] + adn[h];
                e = e > 0.f ? e : 0.2f * e;
                ssum[h] += __expf(e - m[h]);
            }
        }
        #pragma unroll
        for (int off = 32; off; off >>= 1)
            #pragma unroll
            for (int h = 0; h < 4; h++) ssum[h] += __shfl_xor(ssum[h], off);
        #pragma unroll
        for (int h = 0; h < 4; h++) inv[h] = 1.f / (ssum[h] + 1e-16f);

        #pragma unroll
        for (int c = 0; c < 4; c++) {
            int rel = c * 64 + lane;
            if (jb + rel < je) {
                lcol[wid][rel] = scol[c];
                *reinterpret_cast<float4*>(&lalpha[wid][rel * 4]) = make_float4(
                    __expf(ev[c][0] - m[0]) * inv[0],
                    __expf(ev[c][1] - m[1]) * inv[1],
                    __expf(ev[c][2] - m[2]) * inv[2],
                    __expf(ev[c][3] - m[3]) * inv[3]);
            }
        }
    }
    __syncthreads();
    if (!valid) return;

    int base = lane * 8;
    int hme = lane >> 4;
    float acc[8] = {};
    int deg = je - jb;
    int fast = deg < 256 ? deg : 256;

    int j = 0;
    for (; j + 3 < fast; j += 4) {
        int4 cs = *reinterpret_cast<const int4*>(&lcol[wid][j]);
        float a0 = lalpha[wid][(j + 0) * 4 + hme];
        float a1 = lalpha[wid][(j + 1) * 4 + hme];
        float a2 = lalpha[wid][(j + 2) * 4 + hme];
        float a3 = lalpha[wid][(j + 3) * 4 + hme];
        uint4 r0 = *reinterpret_cast<const uint4*>(&xw[(size_t)cs.x * 512 + base]);
        uint4 r1 = *reinterpret_cast<const uint4*>(&xw[(size_t)cs.y * 512 + base]);
        uint4 r2 = *reinterpret_cast<const uint4*>(&xw[(size_t)cs.z * 512 + base]);
        uint4 r3 = *reinterpret_cast<const uint4*>(&xw[(size_t)cs.w * 512 + base]);
        acc[0] = fmaf(a0, __uint_as_float(r0.x << 16), acc[0]);
        acc[1] = fmaf(a0, __uint_as_float(r0.x & 0xffff0000u), acc[1]);
        acc[2] = fmaf(a0, __uint_as_float(r0.y << 16), acc[2]);
        acc[3] = fmaf(a0, __uint_as_float(r0.y & 0xffff0000u), acc[3]);
        acc[4] = fmaf(a0, __uint_as_float(r0.z << 16), acc[4]);
        acc[5] = fmaf(a0, __uint_as_float(r0.z & 0xffff0000u), acc[5]);
        acc[6] = fmaf(a0, __uint_as_float(r0.w << 16), acc[6]);
        acc[7] = fmaf(a0, __uint_as_float(r0.w & 0xffff0000u), acc[7]);
        acc[0] = fmaf(a1, __uint_as_float(r1.x << 16), acc[0]);
        acc[1] = fmaf(a1, __uint_as_float(r1.x & 0xffff0000u), acc[1]);
        acc[2] = fmaf(a1, __uint_as_float(r1.y << 16), acc[2]);
        acc[3] = fmaf(a1, __uint_as_float(r1.y & 0xffff0000u), acc[3]);
        acc[4] = fmaf(a1, __uint_as_float(r1.z << 16), acc[4]);
        acc[5] = fmaf(a1, __uint_as_float(r1.z & 0xffff0000u), acc[5]);
        acc[6] = fmaf(a1, __uint_as_float(r1.w << 16), acc[6]);
        acc[7] = fmaf(a1, __uint_as_float(r1.w & 0xffff0000u), acc[7]);
        acc[0] = fmaf(a2, __uint_as_float(r2.x << 16), acc[0]);
        acc[1] = fmaf(a2, __uint_as_float(r2.x & 0xffff0000u), acc[1]);
        acc[2] = fmaf(a2, __uint_as_float(r2.y << 16), acc[2]);
        acc[3] = fmaf(a2, __uint_as_float(r2.y & 0xffff0000u), acc[3]);
        acc[4] = fmaf(a2, __uint_as_float(r2.z << 16), acc[4]);
        acc[5] = fmaf(a2, __uint_as_float(r2.z & 0xffff0000u), acc[5]);
        acc[6] = fmaf(a2, __uint_as_float(r2.w << 16), acc[6]);
        acc[7] = fmaf(a2, __uint_as_float(r2.w & 0xffff0000u), acc[7]);
        acc[0] = fmaf(a3, __uint_as_float(r3.x << 16), acc[0]);
        acc[1] = fmaf(a3, __uint_as_float(r3.x & 0xffff0000u), acc[1]);
        acc[2] = fmaf(a3, __uint_as_float(r3.y << 16), acc[2]);
        acc[3] = fmaf(a3, __uint_as_float(r3.y & 0xffff0000u), acc[3]);
        acc[4] = fmaf(a3, __uint_as_float(r3.z << 16), acc[4]);
        acc[5] = fmaf(a3, __uint_as_float(r3.z & 0xffff0000u), acc[5]);
        acc[6] = fmaf(a3, __uint_as_float(r3.w << 16), acc[6]);
        acc[7] = fmaf(a3, __uint_as_float(r3.w & 0xffff0000u), acc[7]);
    }
    for (; j < fast; ++j) {
        int s = lcol[wid][j];
        float a = lalpha[wid][j * 4 + hme];
        uint4 raw = *reinterpret_cast<const uint4*>(&xw[(size_t)s * 512 + base]);
        acc[0] = fmaf(a, __uint_as_float(raw.x << 16), acc[0]);
        acc[1] = fmaf(a, __uint_as_float(raw.x & 0xffff0000u), acc[1]);
        acc[2] = fmaf(a, __uint_as_float(raw.y << 16), acc[2]);
        acc[3] = fmaf(a, __uint_as_float(raw.y & 0xffff0000u), acc[3]);
        acc[4] = fmaf(a, __uint_as_float(raw.z << 16), acc[4]);
        acc[5] = fmaf(a, __uint_as_float(raw.z & 0xffff0000u), acc[5]);
        acc[6] = fmaf(a, __uint_as_float(raw.w << 16), acc[6]);
        acc[7] = fmaf(a, __uint_as_float(raw.w & 0xffff0000u), acc[7]);
    }
    if (deg > 256) {   // slow correct fallback, never taken at this scale
        float adn_h = hme == 0 ? adn[0] : hme == 1 ? adn[1] : hme == 2 ? adn[2] : adn[3];
        float m_h   = hme == 0 ? m[0]   : hme == 1 ? m[1]   : hme == 2 ? m[2]   : m[3];
        float inv_h = hme == 0 ? inv[0] : hme == 1 ? inv[1] : hme == 2 ? inv[2] : inv[3];
        for (int jj = jb + 256; jj < je; ++jj) {
            int s = col[jj];
            float e = asrc[(size_t)s * 4 + hme] + adn_h;
            e = e > 0.f ? e : 0.2f * e;
            float a = __expf(e - m_h) * inv_h;
            uint4 raw = *reinterpret_cast<const uint4*>(&xw[(size_t)s * 512 + base]);
            acc[0] = fmaf(a, __uint_as_float(raw.x << 16), acc[0]);
            acc[1] = fmaf(a, __uint_as_float(raw.x & 0xffff0000u), acc[1]);
            acc[2] = fmaf(a, __uint_as_float(raw.y << 16), acc[2]);
            acc[3] = fmaf(a, __uint_as_float(raw.y & 0xffff0000u), acc[3]);
            acc[4] = fmaf(a, __uint_as_float(raw.z << 16), acc[4]);
            acc[5] = fmaf(a, __uint_as_float(raw.z & 0xffff0000u), acc[5]);
            acc[6] = fmaf(a, __uint_as_float(raw.w << 16), acc[6]);
            acc[7] = fmaf(a, __uint_as_float(raw.w & 0xffff0000u), acc[7]);
        }
    }

    // pack-slot address for node w, channels [base, base+8), K=512 (KC=32)
    int R = w >> 5, r31 = w & 31, cc = lane >> 1, sub = lane & 1;
    int lp = r31 | (sub << 5);
    size_t slot = (((size_t)R * 32 + cc) * 64 + lp) * 8;

    float sk[8];
    if (SKIPPK) {
        int4 h4 = *reinterpret_cast<const int4*>(skipHi + slot);
        int4 l4 = *reinterpret_cast<const int4*>(skipLo + slot);
        unsigned hu[4] = {(unsigned)h4.x, (unsigned)h4.y, (unsigned)h4.z, (unsigned)h4.w};
        unsigned lu[4] = {(unsigned)l4.x, (unsigned)l4.y, (unsigned)l4.z, (unsigned)l4.w};
        #pragma unroll
        for (int i = 0; i < 4; i++) {
            sk[2 * i]     = __uint_as_float(hu[i] << 16) + __uint_as_float(lu[i] << 16);
            sk[2 * i + 1] = __uint_as_float(hu[i] & 0xffff0000u)
                          + __uint_as_float(lu[i] & 0xffff0000u);
        }
    } else {
        const float* kp = &skipF[(size_t)w * 512 + base];
        float4 s0 = *reinterpret_cast<const float4*>(kp);
        float4 s1 = *reinterpret_cast<const float4*>(kp + 4);
        sk[0] = s0.x; sk[1] = s0.y; sk[2] = s0.z; sk[3] = s0.w;
        sk[4] = s1.x; sk[5] = s1.y; sk[6] = s1.z; sk[7] = s1.w;
    }

    const float* bp = &bias[base];
    float r[8];
    #pragma unroll
    for (int i = 0; i < 8; i++) {
        float v = acc[i] + bp[i] + sk[i];
        r[i] = v > 0.f ? v : expm1f(v);          // elu
    }

    unsigned hp[4], lpk[4];
    #pragma unroll
    for (int i = 0; i < 4; i++) {
        u16 h0 = bf16_rne(r[2 * i]);
        u16 h1 = bf16_rne(r[2 * i + 1]);
        float q0 = r[2 * i]     - __uint_as_float((unsigned)h0 << 16);
        float q1 = r[2 * i + 1] - __uint_as_float((unsigned)h1 << 16);
        u16 l0 = bf16_rne(q0);
        u16 l1 = bf16_rne(q1);
        hp[i]  = (unsigned)h0 | ((unsigned)h1 << 16);
        lpk[i] = (unsigned)l0 | ((unsigned)l1 << 16);
    }
    *reinterpret_cast<int4*>(outHi + slot) = make_int4(hp[0], hp[1], hp[2], hp[3]);
    *reinterpret_cast<int4*>(outLo + slot) = make_int4(lpk[0], lpk[1], lpk[2], lpk[3]);
}

// ---------------- fused softmax + aggregation, layer 2 (H=6, C=40) -------

__global__ __launch_bounds__(256) void agg_final240_sm(const u16* __restrict__ xw,
                                                       const float* __restrict__ asrc,
                                                       const float* __restrict__ adst,
                                                       const int* __restrict__ row_off,
                                                       const int* __restrict__ col,
                                                       const float* __restrict__ b2,
                                                       const float* __restrict__ skip,
                                                       float* __restrict__ out,
                                                       int N) {
    __shared__ float lalpha[4][256 * 6];
    __shared__ int   lcol[4][256];
    int w = (blockIdx.x * blockDim.x + threadIdx.x) >> 6;
    int lane = threadIdx.x & 63;
    int wid = (threadIdx.x >> 6) & 3;
    bool valid = w < N;
    int jb = 0, je = 0;
    float adn[6], m[6], inv[6];

    if (valid) {
        jb = row_off[w]; je = row_off[w + 1];
        #pragma unroll
        for (int h = 0; h < 6; h++) adn[h] = adst[(size_t)w * 6 + h];

        float ev[4][6];
        int scol[4];
        #pragma unroll
        for (int h = 0; h < 6; h++) m[h] = -INFINITY;

        #pragma unroll
        for (int c = 0; c < 4; c++) {
            int j = jb + c * 64 + lane;
            if (j < je) {
                int s = col[j]; scol[c] = s;
                #pragma unroll
                for (int h = 0; h < 6; h++) {
                    float e = asrc[(size_t)s * 6 + h] + adn[h];
                    e = e > 0.f ? e : 0.2f * e;
                    ev[c][h] = e;
                    m[h] = fmaxf(m[h], e);
                }
            } else {
                scol[c] = -1;
                #pragma unroll
                for (int h = 0; h < 6; h++) ev[c][h] = -INFINITY;
            }
        }
        for (int j = jb + 256 + lane; j < je; j += 64) {
            int s = col[j];
            #pragma unroll
            for (int h = 0; h < 6; h++) {
                float e = asrc[(size_t)s * 6 + h] + adn[h];
                e = e > 0.f ? e : 0.2f * e;
                m[h] = fmaxf(m[h], e);
            }
        }
        #pragma unroll
        for (int off = 32; off; off >>= 1)
            #pragma unroll
            for (int h = 0; h < 6; h++) m[h] = fmaxf(m[h], __shfl_xor(m[h], off));

        float ssum[6] = {0.f, 0.f, 0.f, 0.f, 0.f, 0.f};
        #pragma unroll
        for (int c = 0; c < 4; c++)
            #pragma unroll
            for (int h = 0; h < 6; h++) ssum[h] += __expf(ev[c][h] - m[h]);
        for (int j = jb + 256 + lane; j < je; j += 64) {
            int s = col[j];
            #pragma unroll
            for (int h = 0; h < 6; h++) {
                float e = asrc[(size_t)s * 6 + h] + adn[h];
                e = e > 0.f ? e : 0.2f * e;
                ssum[h] += __expf(e - m[h]);
            }
        }
        #pragma unroll
        for (int off = 32; off; off >>= 1)
            #pragma unroll
            for (int h = 0; h < 6; h++) ssum[h] += __shfl_xor(ssum[h], off);
        #pragma unroll
        for (int h = 0; h < 6; h++) inv[h] = 1.f / (ssum[h] + 1e-16f);

        #pragma unroll
        for (int c = 0; c < 4; c++) {
            int rel = c * 64 + lane;
            if (jb + rel < je) {
                lcol[wid][rel] = scol[c];
                #pragma unroll
                for (int h = 0; h < 6; h++)
                    lalpha[wid][rel * 6 + h] = __expf(ev[c][h] - m[h]) * inv[h];
            }
        }
    }
    __syncthreads();
    if (!valid) return;

    bool active = lane < 40;
    float acc[6] = {};
    int deg = je - jb;
    int fast = deg < 256 ? deg : 256;

    int j = 0;
    for (; j + 1 < fast; j += 2) {
        int s0 = lcol[wid][j], s1 = lcol[wid][j + 1];
        const float* ap0 = &lalpha[wid][j * 6];
        const float* ap1 = &lalpha[wid][(j + 1) * 6];
        if (active) {
            const u16* sp0 = &xw[(size_t)s0 * 240 + lane];
            const u16* sp1 = &xw[(size_t)s1 * 240 + lane];
            #pragma unroll
            for (int h = 0; h < 6; h++) {
                acc[h] = fmaf(ap0[h], bf16_to_f32(sp0[h * 40]), acc[h]);
                acc[h] = fmaf(ap1[h], bf16_to_f32(sp1[h * 40]), acc[h]);
            }
        }
    }
    for (; j < fast; ++j) {
        int s = lcol[wid][j];
        const float* ap = &lalpha[wid][j * 6];
        if (active) {
            const u16* sp = &xw[(size_t)s * 240 + lane];
            #pragma unroll
            for (int h = 0; h < 6; h++)
                acc[h] = fmaf(ap[h], bf16_to_f32(sp[h * 40]), acc[h]);
        }
    }
    if (deg > 256) {
        for (int jj = jb + 256; jj < je; ++jj) {
            int s = col[jj];
            if (active) {
                const u16* sp = &xw[(size_t)s * 240 + lane];
                #pragma unroll
                for (int h = 0; h < 6; h++) {
                    float e = asrc[(size_t)s * 6 + h] + adn[h];
                    e = e > 0.f ? e : 0.2f * e;
                    float a = __expf(e - m[h]) * inv[h];
                    acc[h] = fmaf(a, bf16_to_f32(sp[h * 40]), acc[h]);
                }
            }
        }
    }
    if (active) {
        float v = (acc[0] + acc[1] + acc[2] + acc[3] + acc[4] + acc[5]) * (1.f / 6.f)
                  + b2[lane] + skip[(size_t)w * 40 + lane];
        out[(size_t)w * 40 + lane] = v;
    }
}

// ---------------- orchestration ----------------

extern "C" void kernel_launch(void* const* d_in, const int* in_sizes, int n_in,
                              void* d_out, int out_size, void* d_ws, size_t ws_size,
                              hipStream_t stream) {
    const float* x        = (const float*)d_in[0];
    const int*   ei       = (const int*)  d_in[1];
    const float* W0       = (const float*)d_in[2];
    const float* a_src0   = (const float*)d_in[3];
    const float* a_dst0   = (const float*)d_in[4];
    const float* b0       = (const float*)d_in[5];
    const float* Wskip_in = (const float*)d_in[6];
    const float* W1       = (const float*)d_in[7];
    const float* a_src1   = (const float*)d_in[8];
    const float* a_dst1   = (const float*)d_in[9];
    const float* b1       = (const float*)d_in[10];
    const float* W2       = (const float*)d_in[11];
    const float* a_src2   = (const float*)d_in[12];
    const float* a_dst2   = (const float*)d_in[13];
    const float* b2       = (const float*)d_in[14];
    const float* Wskip_out= (const float*)d_in[15];

    const int N = in_sizes[0] / N_FEAT;     // 10000
    const int E = in_sizes[1] / 2;          // 160000
    float* out = (float*)d_out;

    const int Rblocks = (N + 31) / 32;      // 313
    const int mtiles = (N + 127) / 128;     // 79

    // ---------- workspace layout (ws_size = 256 MiB measured) ----------
    float* ws = (float*)d_ws;
    size_t o = 0;
    u16* xwb   = (u16*)(ws + o); o += (size_t)N * 256;   // N*512 bf16
    float* tmpD  = ws + o; o += (size_t)N * HID;         // L0 skip_in (fp32)
    float* asrc  = ws + o; o += (size_t)N * 8;
    float* adst  = ws + o; o += (size_t)N * 8;
    float* skipo = ws + o; o += (size_t)N * 40;
    float* ac0   = ws + o; o += 256 * 8;
    float* ac1   = ws + o; o += 512 * 8;
    float* ac2   = ws + o; o += 512 * 12;

    u16* up = (u16*)(ws + o);
    size_t uo = 0;
    const size_t aPack = (size_t)Rblocks * 32 * 512 + 512;   // K=512 pack + guard
    u16* AhA = up + uo; uo += aPack;   u16* AlA = up + uo; uo += aPack;
    u16* AhB = up + uo; uo += aPack;   u16* AlB = up + uo; uo += aPack;
    const size_t b0sz = (size_t)34 * 16 * 512 + 512;   // L0: 34 blocks, KC=16
    u16* B0h = up + uo; uo += b0sz;  u16* B0l = up + uo; uo += b0sz;
    const size_t b1sz = (size_t)18 * 32 * 512 + 512;   // L1: 18 blocks, KC=32
    u16* B1h = up + uo; uo += b1sz;  u16* B1l = up + uo; uo += b1sz;
    const size_t b2sz = (size_t)12 * 32 * 512 + 512;   // L2: 12 blocks, KC=32
    u16* B2h = up + uo; uo += b2sz;  u16* B2l = up + uo; uo += b2sz;
    int* row_off = (int*)(up + uo);
    int* cursor  = row_off + (N + 1);
    int* col     = cursor + (N + 1);

    // ---- CSR by destination (includes self loops) ----
    init_counts<<<(N + 255) / 256, 256, 0, stream>>>(cursor, N);
    count_edges<<<(E + 255) / 256, 256, 0, stream>>>(ei, E, cursor);
    scan_offsets<<<1, 1024, 0, stream>>>(cursor, row_off, N);
    fill_csr<<<(E + N + 255) / 256, 256, 0, stream>>>(ei, E, N, cursor, col);

    // ---- combined attention columns (1 launch), then all B packs (1) ----
    att_combine_all<<<48, 256, 0, stream>>>(W0, a_src0, a_dst0,
                                            W1, a_src1, a_dst1,
                                            W2, a_src2, a_dst2, ac0, ac1, ac2);
    pack_all_B<<<376, 256, 0, stream>>>(W0, Wskip_in, ac0, W1, ac1,
                                        W2, Wskip_out, ac2,
                                        B0h, B0l, B1h, B1l, B2h, B2l);

    int nodeBlocks = (N * 64 + 255) / 256;
    const int BIG = 1 << 30;

    // ---- Layer 0: x(fp32) -> pack -> fused GEMM (1088 cols) ----
    cvtA_pack<<<(Rblocks * 16 * 64 + 255) / 256, 256, 0, stream>>>(x, AhA, AlA, N, 256, Rblocks);
    gemm_fused<<<mtiles * 17, 256, 0, stream>>>(
        AhA, AlA, B0h, B0l, xwb, 512, tmpD, 512, 1024, asrc, adst, 1024, 4,
        N, 256, 17, Rblocks);
    agg_sm512<0><<<nodeBlocks, 256, 0, stream>>>(
        xwb, asrc, adst, row_off, col, b0, tmpD, nullptr, nullptr, AhB, AlB, N);

    // ---- Layer 1: fused GEMM (576 cols), skip = x1 packs ----
    gemm_fused<<<mtiles * 9, 256, 0, stream>>>(
        AhB, AlB, B1h, B1l, xwb, 512, nullptr, BIG, BIG, asrc, adst, 512, 4,
        N, 512, 9, Rblocks);
    agg_sm512<1><<<nodeBlocks, 256, 0, stream>>>(
        xwb, asrc, adst, row_off, col, b1, nullptr, AhB, AlB, AhA, AlA, N);

    // ---- Layer 2: fused GEMM (384 cols): xwb240 | skipo | att ----
    gemm_fused<<<mtiles * 6, 256, 0, stream>>>(
        AhA, AlA, B2h, B2l, xwb, 240, skipo, 256, 296, asrc, adst, 320, 6,
        N, 512, 6, Rblocks);
    agg_final240_sm<<<nodeBlocks, 256, 0, stream>>>(
        xwb, asrc, adst, row_off, col, b2, skipo, out, N);
}